// Round 1
// 883.216 us; speedup vs baseline: 1.4140x; 1.4140x over previous
//
#include <hip/hip_runtime.h>
#include <hip/hip_bf16.h>

#define DEV __device__ __forceinline__

constexpr int Bc = 2, Nc = 2048, Mc = 2048, DIMc = 512, Hc = 8, FFc = 2048, Ec = 64;
constexpr int CT = 64;            // causal chunk length (tokens)
constexpr int NCc = Nc / CT;      // 32 chunks per sequence
constexpr float LN_EPS = 1e-5f, ATTN_EPS = 1e-6f;

typedef __bf16 bfrag8 __attribute__((ext_vector_type(8)));
typedef float ffrag4 __attribute__((ext_vector_type(4)));
typedef unsigned short u16;

// ---------------- helpers ----------------
DEV u16 f2bf(float v) {
  __hip_bfloat16 h = __float2bfloat16(v);   // RTN-even
  return __builtin_bit_cast(unsigned short, h);
}
DEV float bf2f(u16 u) { return __uint_as_float(((unsigned)u) << 16); }

DEV void gload16(const void* g, void* l) {
  __builtin_amdgcn_global_load_lds(
      (const __attribute__((address_space(1))) void*)g,
      (__attribute__((address_space(3))) void*)l, 16, 0, 0);
}

// ---------------- dtype detection + ingest to canonical fp32 ----------------
__global__ __launch_bounds__(64) void detect_kernel(const void* x, int* flag) {
  const unsigned short* u = (const unsigned short*)x;
  int tid = threadIdx.x;
  int bad = 0;
#pragma unroll
  for (int i = 0; i < 8; ++i) {
    float v = __uint_as_float(((unsigned)u[tid * 8 + i]) << 16);
    if (!(fabsf(v) <= 1e4f)) bad = 1;   // catches NaN, Inf, garbage
  }
  unsigned long long m = __ballot(bad);
  if (tid == 0) *flag = (m == 0ull) ? 1 : 0;  // 1 = inputs are bf16
}

struct ConvJob { const void* src; float* dst; int n; };
struct ConvJobs { ConvJob j[18]; };

__global__ __launch_bounds__(256) void ingest_kernel(ConvJobs jobs, const int* flag) {
  int bf = *flag;
  ConvJob jb = jobs.j[blockIdx.y];
  int stride = gridDim.x * 256;
  for (int i = blockIdx.x * 256 + threadIdx.x; i < jb.n; i += stride) {
    float v;
    if (bf) v = __uint_as_float(((unsigned)((const unsigned short*)jb.src)[i]) << 16);
    else    v = ((const float*)jb.src)[i];
    jb.dst[i] = v;
  }
}

// ---------------- fp32 -> 3-term bf16 split (activations) ----------------
// out layout: row-major M x 3K bf16: [hi | hi | lo]
__global__ __launch_bounds__(256) void split_act(const float* __restrict__ in,
    u16* __restrict__ out, int kshift, int total)
{
  const int K = 1 << kshift;
  int stride = gridDim.x * 256 * 4;
  for (int i = (blockIdx.x * 256 + threadIdx.x) * 4; i < total; i += stride) {
    float4 a = *(const float4*)&in[i];
    int row = i >> kshift;
    int k = i & (K - 1);
    u16 h[4], l[4];
    float v[4] = {a.x, a.y, a.z, a.w};
#pragma unroll
    for (int j = 0; j < 4; ++j) {
      h[j] = f2bf(v[j]);
      l[j] = f2bf(v[j] - bf2f(h[j]));
    }
    uint2 hv, lv;
    hv.x = (unsigned)h[0] | ((unsigned)h[1] << 16);
    hv.y = (unsigned)h[2] | ((unsigned)h[3] << 16);
    lv.x = (unsigned)l[0] | ((unsigned)l[1] << 16);
    lv.y = (unsigned)l[2] | ((unsigned)l[3] << 16);
    size_t rb = (size_t)row * 3 * K + k;
    *(uint2*)&out[rb]         = hv;
    *(uint2*)&out[rb + K]     = hv;
    *(uint2*)&out[rb + 2 * K] = lv;
  }
}

// ---------------- W (KxN fp32) -> B3t (N x 3K bf16) transpose+split ----------------
// B3t[n][k] = hi(W[k][n]); B3t[n][K+k] = lo; B3t[n][2K+k] = hi.
// Pairs with A3 = [hi|hi|lo]: terms hi*hi + hi*lo + lo*hi.
__global__ __launch_bounds__(256) void wsplit_kernel(const float* __restrict__ W,
    u16* __restrict__ B3t, int K, int N)
{
  __shared__ float T[64][65];
  int n0 = blockIdx.x * 64, k0 = blockIdx.y * 64;
  int tid = threadIdx.x;
#pragma unroll
  for (int j = 0; j < 16; ++j) {
    int idx = tid + 256 * j;
    int kl = idx >> 6, nl = idx & 63;
    T[kl][nl] = W[(size_t)(k0 + kl) * N + n0 + nl];
  }
  __syncthreads();
#pragma unroll
  for (int j = 0; j < 16; ++j) {
    int idx = tid + 256 * j;
    int nl = idx >> 6, kl = idx & 63;
    float v = T[kl][nl];
    u16 hi = f2bf(v);
    u16 lo = f2bf(v - bf2f(hi));
    size_t rb = (size_t)(n0 + nl) * 3 * K + k0 + kl;
    B3t[rb]         = hi;
    B3t[rb + K]     = lo;
    B3t[rb + 2 * K] = hi;
  }
}

// ---------------- MFMA GEMM: C[M,N] = A3[M,K3] @ B3t[N,K3]^T (+bias)(+res)(relu) ----
// m97-style structure: 128-row tile, BK=32, 4 waves in 2x2, each wave 64x(BN/2),
// global_load_lds width-16 staging, 16x16x32 bf16 MFMA, fp32 accumulate.
// OUTMODE 0: write fp32 C. OUTMODE 1: write split-A3 bf16 [hi|hi|lo] (row len 3N).
template<int BM, int BN, int OUTMODE, bool RELU, bool ADD_RES>
__global__ __launch_bounds__(256) void gemm_mfma(
    const u16* __restrict__ A3, const u16* __restrict__ B3t,
    const float* __restrict__ bias, const float* __restrict__ res,
    float* __restrict__ Cf, u16* __restrict__ C3,
    int N, int K3)
{
  constexpr int WM = BM / 2, WN = BN / 2, FM = WM / 16, FN = WN / 16;
  __shared__ u16 As[BM][32];
  __shared__ u16 Bs[BN][32];
  const int tid = threadIdx.x;
  const int lane = tid & 63, wid = tid >> 6;
  const int wr = wid >> 1, wc = wid & 1;
  const int row0 = blockIdx.y * BM, col0 = blockIdx.x * BN;
  const int sr = lane >> 2, sk = (lane & 3) * 8;     // staging coords (16B/lane)
  const int ar = lane & 15, kb = (lane >> 4) * 8;    // fragment coords

  ffrag4 acc[FM][FN];
#pragma unroll
  for (int m = 0; m < FM; ++m)
#pragma unroll
    for (int n = 0; n < FN; ++n) acc[m][n] = ffrag4{0.f, 0.f, 0.f, 0.f};

  for (int k0 = 0; k0 < K3; k0 += 32) {
    // stage A tile: BM x 32 bf16, 16-row chunks of 1KB per wave-instruction
    for (int r = wid; r < BM / 16; r += 4)
      gload16(&A3[(size_t)(row0 + r * 16 + sr) * K3 + k0 + sk], &As[r * 16][0]);
    // stage B^T tile: BN x 32 bf16
    for (int r = wid; r < BN / 16; r += 4)
      gload16(&B3t[(size_t)(col0 + r * 16 + sr) * K3 + k0 + sk], &Bs[r * 16][0]);
    __syncthreads();   // drains vmcnt(0): LDS tiles ready

    bfrag8 af[FM], bw[FN];
#pragma unroll
    for (int m = 0; m < FM; ++m)
      af[m] = *(const bfrag8*)&As[wr * WM + m * 16 + ar][kb];
#pragma unroll
    for (int n = 0; n < FN; ++n)
      bw[n] = *(const bfrag8*)&Bs[wc * WN + n * 16 + ar][kb];
#pragma unroll
    for (int m = 0; m < FM; ++m)
#pragma unroll
      for (int n = 0; n < FN; ++n)
        acc[m][n] = __builtin_amdgcn_mfma_f32_16x16x32_bf16(af[m], bw[n], acc[m][n], 0, 0, 0);
    __syncthreads();   // protect tiles before next-iteration overwrite
  }

  // epilogue: D[row][col], col = lane&15, row = (lane>>4)*4 + u  [m89-verified]
#pragma unroll
  for (int m = 0; m < FM; ++m) {
    int rbase = row0 + wr * WM + m * 16 + (lane >> 4) * 4;
#pragma unroll
    for (int n = 0; n < FN; ++n) {
      int col = col0 + wc * WN + n * 16 + ar;
      float bi = bias[col];
#pragma unroll
      for (int u = 0; u < 4; ++u) {
        int row = rbase + u;
        float v = acc[m][n][u] + bi;
        if (ADD_RES) v += res[(size_t)row * N + col];
        if (RELU) v = fmaxf(v, 0.f);
        if constexpr (OUTMODE == 0) {
          Cf[(size_t)row * N + col] = v;
        } else {
          u16 hi = f2bf(v);
          u16 lo = f2bf(v - bf2f(hi));
          size_t rb = (size_t)row * 3 * N;
          C3[rb + col]         = hi;
          C3[rb + N + col]     = hi;
          C3[rb + 2 * N + col] = lo;
        }
      }
    }
  }
}

// ---------------- layernorm over last dim (512), optional residual ----------------
template<bool HAS_RES, bool FINAL>
__global__ __launch_bounds__(256) void ln_kernel(
    const float* __restrict__ in, const float* __restrict__ res,
    const float* __restrict__ g, const float* __restrict__ b,
    void* __restrict__ out, const int* __restrict__ flag)
{
  int row = blockIdx.x, tid = threadIdx.x;
  size_t base = (size_t)row * DIMc;
  float x0 = in[base + tid], x1 = in[base + tid + 256];
  if (HAS_RES) { x0 += res[base + tid]; x1 += res[base + tid + 256]; }
  float s1 = x0 + x1, s2 = x0 * x0 + x1 * x1;
#pragma unroll
  for (int off = 1; off < 64; off <<= 1) { s1 += __shfl_xor(s1, off); s2 += __shfl_xor(s2, off); }
  __shared__ float p1[4], p2[4], stat[2];
  if ((tid & 63) == 0) { p1[tid >> 6] = s1; p2[tid >> 6] = s2; }
  __syncthreads();
  if (tid == 0) {
    float t1 = p1[0] + p1[1] + p1[2] + p1[3];
    float t2 = p2[0] + p2[1] + p2[2] + p2[3];
    float mu = t1 / DIMc;
    float var = t2 / DIMc - mu * mu;
    stat[0] = mu; stat[1] = rsqrtf(var + LN_EPS);
  }
  __syncthreads();
  float mu = stat[0], rv = stat[1];
  float y0 = (x0 - mu) * rv * g[tid] + b[tid];
  float y1 = (x1 - mu) * rv * g[tid + 256] + b[tid + 256];
  if (FINAL) {
    if (*flag) {
      __hip_bfloat16* o = (__hip_bfloat16*)out;
      o[base + tid] = __float2bfloat16(y0);
      o[base + tid + 256] = __float2bfloat16(y1);
    } else {
      float* o = (float*)out;
      o[base + tid] = y0;
      o[base + tid + 256] = y1;
    }
  } else {
    float* o = (float*)out;
    o[base + tid] = y0;
    o[base + tid + 256] = y1;
  }
}

// ---------------- causal linear attention, pass A: per-chunk KV sums ----------------
__global__ __launch_bounds__(256) void causalA(const float* __restrict__ qvk,
    float* __restrict__ chunkKV, float* __restrict__ chunkKs)
{
  int c = blockIdx.x, bh = blockIdx.y;
  int b = bh >> 3, h = bh & 7;
  __shared__ float ks[CT][Ec];
  __shared__ float vs[CT][Ec];
  int tid = threadIdx.x;
#pragma unroll
  for (int j = 0; j < 16; ++j) {
    int i = tid + 256 * j;
    int t = i >> 6, d = i & 63;
    size_t rowbase = ((size_t)b * Nc + c * CT + t) * (3 * DIMc);
    ks[t][d] = __expf(qvk[rowbase + 2 * DIMc + h * Ec + d]);
    vs[t][d] = qvk[rowbase + DIMc + h * Ec + d];
  }
  __syncthreads();
  int e = tid & 63, d0 = tid >> 6;
  float acc[16] = {};
  for (int t = 0; t < CT; ++t) {
    float ve = vs[t][e];
#pragma unroll
    for (int j = 0; j < 16; ++j) acc[j] += ks[t][d0 + 4 * j] * ve;
  }
  size_t obase = ((size_t)bh * NCc + c) * (Ec * Ec);
#pragma unroll
  for (int j = 0; j < 16; ++j) chunkKV[obase + (size_t)(d0 + 4 * j) * Ec + e] = acc[j];
  if (tid < Ec) {
    float s = 0;
    for (int t = 0; t < CT; ++t) s += ks[t][tid];
    chunkKs[((size_t)bh * NCc + c) * Ec + tid] = s;
  }
}

// ---------------- pass B: in-place exclusive prefix over chunks ----------------
__global__ __launch_bounds__(256) void causalB(float* __restrict__ chunkKV,
                                               float* __restrict__ chunkKs)
{
  int bh = blockIdx.x, tid = threadIdx.x;
  for (int idx = tid; idx < Ec * Ec; idx += 256) {
    float run = 0;
    size_t base = (size_t)bh * NCc * Ec * Ec + idx;
    for (int c = 0; c < NCc; ++c) {
      float t = chunkKV[base + (size_t)c * Ec * Ec];
      chunkKV[base + (size_t)c * Ec * Ec] = run;
      run += t;
    }
  }
  if (tid < Ec) {
    float run = 0;
    size_t base = (size_t)bh * NCc * Ec + tid;
    for (int c = 0; c < NCc; ++c) {
      float t = chunkKs[base + (size_t)c * Ec];
      chunkKs[base + (size_t)c * Ec] = run;
      run += t;
    }
  }
}

// ---------------- pass C: per-token outputs ----------------
__global__ __launch_bounds__(256) void causalC(const float* __restrict__ qvk,
    const float* __restrict__ chunkKV, const float* __restrict__ chunkKs,
    float* __restrict__ attn_out)
{
  int c = blockIdx.x, bh = blockIdx.y;
  int b = bh >> 3, h = bh & 7;
  __shared__ float S[Ec][Ec];        // exclusive KV prefix
  __shared__ float ks[CT][Ec + 1];
  __shared__ float vs[CT][Ec];
  __shared__ float kpre[Ec];
  int tid = threadIdx.x;
  size_t kvb = (size_t)bh * NCc + c;
#pragma unroll
  for (int j = 0; j < 16; ++j) {
    int i = tid + 256 * j;
    int t = i >> 6, d = i & 63;
    S[t][d] = chunkKV[kvb * (Ec * Ec) + i];
    size_t rowbase = ((size_t)b * Nc + c * CT + t) * (3 * DIMc);
    ks[t][d] = __expf(qvk[rowbase + 2 * DIMc + h * Ec + d]);
    vs[t][d] = qvk[rowbase + DIMc + h * Ec + d];
  }
  if (tid < Ec) kpre[tid] = chunkKs[kvb * Ec + tid] + ATTN_EPS;
  __syncthreads();
  int w = tid >> 6, lane = tid & 63;
  for (int ti = 0; ti < 16; ++ti) {
    int t = w * 16 + ti;  // token index within chunk (uniform per wave)
    size_t rowbase = ((size_t)b * Nc + c * CT + t) * (3 * DIMc);
    float qv = qvk[rowbase + h * Ec + lane];
    float mx = qv;
#pragma unroll
    for (int off = 1; off < 64; off <<= 1) mx = fmaxf(mx, __shfl_xor(mx, off));
    float ex = __expf(qv - mx);
    float ssum = ex;
#pragma unroll
    for (int off = 1; off < 64; off <<= 1) ssum += __shfl_xor(ssum, off);
    float qs = ex / ssum * 0.125f;     // softmax(q)[lane] * E^-0.5
    // intra-chunk score for tau = lane
    float a = 0;
    for (int d = 0; d < Ec; ++d) a += __shfl(qs, d) * ks[lane][d];
    float am = (lane <= t) ? a : 0.f;
    // denominator
    float r = am + qs * kpre[lane];
#pragma unroll
    for (int off = 1; off < 64; off <<= 1) r += __shfl_xor(r, off);
    float dinv = 1.f / r;
    // output element e = lane
    float acc = 0;
    for (int d = 0; d < Ec; ++d) acc += __shfl(qs, d) * S[d][lane];
    for (int tau = 0; tau <= t; ++tau) acc += __shfl(am, tau) * vs[tau][lane];
    attn_out[((size_t)b * Nc + c * CT + t) * DIMc + h * Ec + lane] = acc * dinv;
  }
}

// ---------------- cross-attn: column softmax sums of exp(k2) over m ----------------
__global__ __launch_bounds__(256) void colsum_kernel(const float* __restrict__ kvbuf,
                                                     float* __restrict__ colsum)
{
  int bh = blockIdx.x;
  int b = bh >> 3, h = bh & 7;
  int tid = threadIdx.x, w = tid >> 6, lane = tid & 63;
  float s = 0;
  for (int m = w; m < Mc; m += 4)
    s += __expf(kvbuf[((size_t)b * Mc + m) * (2 * DIMc) + h * Ec + lane]);
  __shared__ float p[4][Ec];
  p[w][lane] = s;
  __syncthreads();
  if (tid < Ec) colsum[(size_t)bh * Ec + tid] = p[0][tid] + p[1][tid] + p[2][tid] + p[3][tid];
}

// ---------------- cross-attn: ctx[d,e] = sum_m softmax_col(k2)[m,d] * v2[m,e] --------
__global__ __launch_bounds__(256) void ctx_kernel(const float* __restrict__ kvbuf,
    const float* __restrict__ colsum, float* __restrict__ ctx)
{
  int slab = blockIdx.x, bh = blockIdx.y;
  int b = bh >> 3, h = bh & 7;
  __shared__ float ks[64][Ec];
  __shared__ float vs[64][Ec];
  int tid = threadIdx.x;
#pragma unroll
  for (int j = 0; j < 16; ++j) {
    int i = tid + 256 * j;
    int m = i >> 6, d = i & 63;
    size_t rowbase = ((size_t)b * Mc + slab * 64 + m) * (2 * DIMc);
    ks[m][d] = __expf(kvbuf[rowbase + h * Ec + d]) / colsum[(size_t)bh * Ec + d];
    vs[m][d] = kvbuf[rowbase + DIMc + h * Ec + d];
  }
  __syncthreads();
  int e = tid & 63, d0 = tid >> 6;
  float acc[16] = {};
  for (int m = 0; m < 64; ++m) {
    float ve = vs[m][e];
#pragma unroll
    for (int j = 0; j < 16; ++j) acc[j] += ks[m][d0 + 4 * j] * ve;
  }
  size_t obase = (size_t)bh * Ec * Ec;
#pragma unroll
  for (int j = 0; j < 16; ++j) atomicAdd(&ctx[obase + (size_t)(d0 + 4 * j) * Ec + e], acc[j]);
}

// ---------------- cross-attn: out[t,e] = softmax(q2[t])*E^-.5 @ ctx ----------------
__global__ __launch_bounds__(256) void attn2_kernel(const float* __restrict__ q2,
    const float* __restrict__ ctx, float* __restrict__ out)
{
  int bh = blockIdx.y;
  int b = bh >> 3, h = bh & 7;
  __shared__ float cs[Ec][Ec];
  int tid = threadIdx.x;
#pragma unroll
  for (int j = 0; j < 16; ++j) {
    int i = tid + 256 * j;
    cs[i >> 6][i & 63] = ctx[(size_t)bh * Ec * Ec + i];
  }
  __syncthreads();
  int w = tid >> 6, lane = tid & 63;
  int t = blockIdx.x * 4 + w;
  float qv = q2[((size_t)b * Nc + t) * DIMc + h * Ec + lane];
  float mx = qv;
#pragma unroll
  for (int off = 1; off < 64; off <<= 1) mx = fmaxf(mx, __shfl_xor(mx, off));
  float ex = __expf(qv - mx);
  float ssum = ex;
#pragma unroll
  for (int off = 1; off < 64; off <<= 1) ssum += __shfl_xor(ssum, off);
  float qs = ex / ssum * 0.125f;
  float acc = 0;
  for (int d = 0; d < Ec; ++d) acc += __shfl(qs, d) * cs[d][lane];
  out[((size_t)b * Nc + t) * DIMc + h * Ec + lane] = acc;
}

extern "C" void kernel_launch(void* const* d_in, const int* in_sizes, int n_in,
                              void* d_out, int out_size, void* d_ws, size_t ws_size,
                              hipStream_t stream)
{
  // ---- workspace layout (fp32-equivalent elements) ----
  // [0,64): flag
  // conv: fp32 copies of all 18 inputs (7,873,024 floats)
  // region0 (12,582,912 f-eq): qvk fp32 (6.29M) -> kvbuf+q2 fp32 (6.29M)
  //                            -> O3ff bf16 split (25.17M u16 = 12.58M f-eq)
  // out1 (2.10M), attn_o/ybuf (2.10M), r3: chunkKV->pre3 (2.10M), smalls
  // B3 region: 5 transposed+split weight matrices (11.01M u16 = 5.51M f-eq)
  // A3a scratch: one 4096x1536 u16 activation-split slot, reused 4x (3.15M f-eq)
  float* ws = (float*)d_ws;
  int* flag = (int*)ws;
  float* conv = ws + 64;

  float* cin[18];
  size_t off = 0;
  for (int i = 0; i < 18; ++i) { cin[i] = conv + off; off += (size_t)in_sizes[i]; }
  float* pipe = conv + off;

  const size_t SZ_ROW = (size_t)Bc * Nc * DIMc;            // 2,097,152
  const size_t SZ_KV  = (size_t)Bc * Mc * 2 * DIMc;        // 4,194,304
  const size_t SZ_R0  = (size_t)Bc * Nc * 3 * FFc / 2;     // 12,582,912 f-eq (O3ff)

  float* region0 = pipe;
  float* qvk     = region0;                   // live: gemm1 .. causalC
  float* kvbuf   = region0;                   // live: kvGEMM .. ctx_kernel
  float* q2      = region0 + SZ_KV;           // live: q2GEMM .. attn2
  u16*   O3ff    = (u16*)region0;             // live: ff1 .. ff2 (split format)
  float* out1    = region0 + SZ_R0;           // live: LN1 .. LN2
  float* attn_o  = out1 + SZ_ROW;             // attn_o -> attn2_o -> ybuf
  float* r3      = attn_o + SZ_ROW;           // chunkKV -> pre3
  float* chunkKV = r3;
  float* pre3    = r3;
  float* chunkKs = r3 + SZ_ROW;                                   // 32768
  float* colsum  = chunkKs + (size_t)Bc * Hc * NCc * Ec;          // 1024
  float* ctx2    = colsum + (size_t)Bc * Hc * Ec;                 // 65536
  float* ybuf    = attn_o;
  float* attn2_o = attn_o;

  u16* B3_qvk = (u16*)(ctx2 + (size_t)Bc * Hc * Ec * Ec);
  u16* B3_kv  = B3_qvk + (size_t)(3 * DIMc) * (3 * DIMc);   // 1536*1536
  u16* B3_q   = B3_kv  + (size_t)(2 * DIMc) * (3 * DIMc);   // 1024*1536
  u16* B3_ff1 = B3_q   + (size_t)DIMc * (3 * DIMc);         // 512*1536
  u16* B3_ff2 = B3_ff1 + (size_t)FFc  * (3 * DIMc);         // 2048*1536
  u16* A3a    = B3_ff2 + (size_t)DIMc * (3 * FFc);          // 512*6144
  (void)ws_size; (void)n_in; (void)out_size;

  dim3 blk(256);
  const int MR = Bc * Nc;  // 4096 rows

  // 0. detect input dtype, convert everything to fp32
  detect_kernel<<<dim3(1), dim3(64), 0, stream>>>(d_in[0], flag);
  ConvJobs jobs;
  for (int i = 0; i < 18; ++i) { jobs.j[i].src = d_in[i]; jobs.j[i].dst = cin[i]; jobs.j[i].n = in_sizes[i]; }
  ingest_kernel<<<dim3(64, 18), blk, 0, stream>>>(jobs, flag);

  const float *x = cin[0], *memory = cin[1], *W_qvk = cin[2], *b_qvk = cin[3],
              *W_kv = cin[4], *b_kv = cin[5], *W_q = cin[6], *b_q = cin[7],
              *W_ff1 = cin[8], *b_ff1 = cin[9], *W_ff2 = cin[10], *b_ff2 = cin[11],
              *ln1_g = cin[12], *ln1_b = cin[13], *ln2_g = cin[14], *ln2_b = cin[15],
              *ln3_g = cin[16], *ln3_b = cin[17];

  // 0b. weight transpose+split (once)
  wsplit_kernel<<<dim3(24, 8), blk, 0, stream>>>(W_qvk, B3_qvk, DIMc, 3 * DIMc);
  wsplit_kernel<<<dim3(16, 8), blk, 0, stream>>>(W_kv,  B3_kv,  DIMc, 2 * DIMc);
  wsplit_kernel<<<dim3(8, 8),  blk, 0, stream>>>(W_q,   B3_q,   DIMc, DIMc);
  wsplit_kernel<<<dim3(32, 8), blk, 0, stream>>>(W_ff1, B3_ff1, DIMc, FFc);
  wsplit_kernel<<<dim3(8, 32), blk, 0, stream>>>(W_ff2, B3_ff2, FFc,  DIMc);

  // 1. qvk = x @ W_qvk + b   (MFMA, 3-term split)
  split_act<<<dim3(1024), blk, 0, stream>>>(x, A3a, 9, (int)SZ_ROW);
  gemm_mfma<128, 128, 0, false, false><<<dim3(12, 32), blk, 0, stream>>>(
      A3a, B3_qvk, b_qvk, nullptr, qvk, nullptr, 3 * DIMc, 3 * DIMc);
  // 2. causal linear self-attention
  causalA<<<dim3(NCc, Bc * Hc), blk, 0, stream>>>(qvk, chunkKV, chunkKs);
  causalB<<<dim3(Bc * Hc), blk, 0, stream>>>(chunkKV, chunkKs);
  causalC<<<dim3(NCc, Bc * Hc), blk, 0, stream>>>(qvk, chunkKV, chunkKs, attn_o);
  // 3. LN1(attn + x)
  ln_kernel<true, false><<<dim3(MR), blk, 0, stream>>>(
      attn_o, x, ln1_g, ln1_b, out1, flag);
  // 4. kv = memory @ W_kv + b (overwrites dead qvk) ; q2 = out1 @ W_q + b
  split_act<<<dim3(1024), blk, 0, stream>>>(memory, A3a, 9, (int)SZ_ROW);
  gemm_mfma<128, 128, 0, false, false><<<dim3(8, 32), blk, 0, stream>>>(
      A3a, B3_kv, b_kv, nullptr, kvbuf, nullptr, 2 * DIMc, 3 * DIMc);
  split_act<<<dim3(1024), blk, 0, stream>>>(out1, A3a, 9, (int)SZ_ROW);
  gemm_mfma<128, 64, 0, false, false><<<dim3(8, 32), blk, 0, stream>>>(
      A3a, B3_q, b_q, nullptr, q2, nullptr, DIMc, 3 * DIMc);
  // 5. cross linear attention
  colsum_kernel<<<dim3(Bc * Hc), blk, 0, stream>>>(kvbuf, colsum);
  hipMemsetAsync(ctx2, 0, (size_t)Bc * Hc * Ec * Ec * sizeof(float), stream);
  ctx_kernel<<<dim3(Mc / 64, Bc * Hc), blk, 0, stream>>>(kvbuf, colsum, ctx2);
  attn2_kernel<<<dim3(Nc / 4, Bc * Hc), blk, 0, stream>>>(q2, ctx2, attn2_o);
  // 6. LN2(attn2 + out1) in-place
  ln_kernel<true, false><<<dim3(MR), blk, 0, stream>>>(
      attn2_o, out1, ln2_g, ln2_b, ybuf, flag);
  // 7. FF: ff1 writes split-A3 format directly (fused relu+split, overwrites dead kvbuf/q2)
  split_act<<<dim3(1024), blk, 0, stream>>>(ybuf, A3a, 9, (int)SZ_ROW);
  gemm_mfma<128, 128, 1, true, false><<<dim3(16, 32), blk, 0, stream>>>(
      A3a, B3_ff1, b_ff1, nullptr, nullptr, O3ff, FFc, 3 * DIMc);
  gemm_mfma<128, 64, 0, false, true><<<dim3(8, 32), blk, 0, stream>>>(
      O3ff, B3_ff2, b_ff2, ybuf, pre3, nullptr, DIMc, 3 * FFc);
  // 8. LN3 -> d_out (bf16 or fp32 per flag)
  ln_kernel<false, true><<<dim3(MR), blk, 0, stream>>>(
      pre3, nullptr, ln3_g, ln3_b, d_out, flag);
}

// Round 2
// 726.955 us; speedup vs baseline: 1.7179x; 1.2150x over previous
//
#include <hip/hip_runtime.h>
#include <hip/hip_bf16.h>

#define DEV __device__ __forceinline__

constexpr int Bc = 2, Nc = 2048, Mc = 2048, DIMc = 512, Hc = 8, FFc = 2048, Ec = 64;
constexpr int CT = 64;            // causal chunk length (tokens)
constexpr int NCc = Nc / CT;      // 32 chunks per sequence
constexpr float LN_EPS = 1e-5f, ATTN_EPS = 1e-6f;

typedef __bf16 bfrag8 __attribute__((ext_vector_type(8)));
typedef float ffrag4 __attribute__((ext_vector_type(4)));
typedef unsigned short u16;

// ---------------- helpers ----------------
DEV u16 f2bf(float v) {
  __hip_bfloat16 h = __float2bfloat16(v);   // RTN-even
  return __builtin_bit_cast(unsigned short, h);
}
DEV float bf2f(u16 u) { return __uint_as_float(((unsigned)u) << 16); }

DEV void gload16(const void* g, void* l) {
  __builtin_amdgcn_global_load_lds(
      (const __attribute__((address_space(1))) void*)g,
      (__attribute__((address_space(3))) void*)l, 16, 0, 0);
}

// ---------------- dtype detection + ingest to canonical fp32 ----------------
__global__ __launch_bounds__(64) void detect_kernel(const void* x, int* flag) {
  const unsigned short* u = (const unsigned short*)x;
  int tid = threadIdx.x;
  int bad = 0;
#pragma unroll
  for (int i = 0; i < 8; ++i) {
    float v = __uint_as_float(((unsigned)u[tid * 8 + i]) << 16);
    if (!(fabsf(v) <= 1e4f)) bad = 1;   // catches NaN, Inf, garbage
  }
  unsigned long long m = __ballot(bad);
  if (tid == 0) *flag = (m == 0ull) ? 1 : 0;  // 1 = inputs are bf16
}

struct ConvJob { const void* src; float* dst; int n; };
struct ConvJobs { ConvJob j[18]; };

__global__ __launch_bounds__(256) void ingest_kernel(ConvJobs jobs, const int* flag) {
  int bf = *flag;
  ConvJob jb = jobs.j[blockIdx.y];
  int stride = gridDim.x * 256;
  for (int i = blockIdx.x * 256 + threadIdx.x; i < jb.n; i += stride) {
    float v;
    if (bf) v = __uint_as_float(((unsigned)((const unsigned short*)jb.src)[i]) << 16);
    else    v = ((const float*)jb.src)[i];
    jb.dst[i] = v;
  }
}

// ---------------- fp32 -> 3-term bf16 split (activations) ----------------
// out layout: row-major M x 3K bf16: [hi | hi | lo]
__global__ __launch_bounds__(256) void split_act(const float* __restrict__ in,
    u16* __restrict__ out, int kshift, int total)
{
  const int K = 1 << kshift;
  int stride = gridDim.x * 256 * 4;
  for (int i = (blockIdx.x * 256 + threadIdx.x) * 4; i < total; i += stride) {
    float4 a = *(const float4*)&in[i];
    int row = i >> kshift;
    int k = i & (K - 1);
    u16 h[4], l[4];
    float v[4] = {a.x, a.y, a.z, a.w};
#pragma unroll
    for (int j = 0; j < 4; ++j) {
      h[j] = f2bf(v[j]);
      l[j] = f2bf(v[j] - bf2f(h[j]));
    }
    uint2 hv, lv;
    hv.x = (unsigned)h[0] | ((unsigned)h[1] << 16);
    hv.y = (unsigned)h[2] | ((unsigned)h[3] << 16);
    lv.x = (unsigned)l[0] | ((unsigned)l[1] << 16);
    lv.y = (unsigned)l[2] | ((unsigned)l[3] << 16);
    size_t rb = (size_t)row * 3 * K + k;
    *(uint2*)&out[rb]         = hv;
    *(uint2*)&out[rb + K]     = hv;
    *(uint2*)&out[rb + 2 * K] = lv;
  }
}

// ---------------- W (KxN fp32) -> B3t (N x 3K bf16) transpose+split ----------------
// B3t[n][k] = hi(W[k][n]); B3t[n][K+k] = lo; B3t[n][2K+k] = hi.
// Pairs with A3 = [hi|hi|lo]: terms hi*hi + hi*lo + lo*hi.
__global__ __launch_bounds__(256) void wsplit_kernel(const float* __restrict__ W,
    u16* __restrict__ B3t, int K, int N)
{
  __shared__ float T[64][65];
  int n0 = blockIdx.x * 64, k0 = blockIdx.y * 64;
  int tid = threadIdx.x;
#pragma unroll
  for (int j = 0; j < 16; ++j) {
    int idx = tid + 256 * j;
    int kl = idx >> 6, nl = idx & 63;
    T[kl][nl] = W[(size_t)(k0 + kl) * N + n0 + nl];
  }
  __syncthreads();
#pragma unroll
  for (int j = 0; j < 16; ++j) {
    int idx = tid + 256 * j;
    int nl = idx >> 6, kl = idx & 63;
    float v = T[kl][nl];
    u16 hi = f2bf(v);
    u16 lo = f2bf(v - bf2f(hi));
    size_t rb = (size_t)(n0 + nl) * 3 * K + k0 + kl;
    B3t[rb]         = hi;
    B3t[rb + K]     = lo;
    B3t[rb + 2 * K] = hi;
  }
}

// ---------------- MFMA GEMM: C[M,N] = A3[M,K3] @ B3t[N,K3]^T (+bias)(+res)(relu) ----
// m97-style structure: 128-row tile, BK=32, 4 waves in 2x2, each wave 64x(BN/2),
// global_load_lds width-16 staging, 16x16x32 bf16 MFMA, fp32 accumulate.
// OUTMODE 0: write fp32 C. OUTMODE 1: write split-A3 bf16 [hi|hi|lo] (row len 3N).
template<int BM, int BN, int OUTMODE, bool RELU, bool ADD_RES>
__global__ __launch_bounds__(256) void gemm_mfma(
    const u16* __restrict__ A3, const u16* __restrict__ B3t,
    const float* __restrict__ bias, const float* __restrict__ res,
    float* __restrict__ Cf, u16* __restrict__ C3,
    int N, int K3)
{
  constexpr int WM = BM / 2, WN = BN / 2, FM = WM / 16, FN = WN / 16;
  __shared__ u16 As[BM][32];
  __shared__ u16 Bs[BN][32];
  const int tid = threadIdx.x;
  const int lane = tid & 63, wid = tid >> 6;
  const int wr = wid >> 1, wc = wid & 1;
  const int row0 = blockIdx.y * BM, col0 = blockIdx.x * BN;
  const int sr = lane >> 2, sk = (lane & 3) * 8;     // staging coords (16B/lane)
  const int ar = lane & 15, kb = (lane >> 4) * 8;    // fragment coords

  ffrag4 acc[FM][FN];
#pragma unroll
  for (int m = 0; m < FM; ++m)
#pragma unroll
    for (int n = 0; n < FN; ++n) acc[m][n] = ffrag4{0.f, 0.f, 0.f, 0.f};

  for (int k0 = 0; k0 < K3; k0 += 32) {
    // stage A tile: BM x 32 bf16, 16-row chunks of 1KB per wave-instruction
    for (int r = wid; r < BM / 16; r += 4)
      gload16(&A3[(size_t)(row0 + r * 16 + sr) * K3 + k0 + sk], &As[r * 16][0]);
    // stage B^T tile: BN x 32 bf16
    for (int r = wid; r < BN / 16; r += 4)
      gload16(&B3t[(size_t)(col0 + r * 16 + sr) * K3 + k0 + sk], &Bs[r * 16][0]);
    __syncthreads();   // drains vmcnt(0): LDS tiles ready

    bfrag8 af[FM], bw[FN];
#pragma unroll
    for (int m = 0; m < FM; ++m)
      af[m] = *(const bfrag8*)&As[wr * WM + m * 16 + ar][kb];
#pragma unroll
    for (int n = 0; n < FN; ++n)
      bw[n] = *(const bfrag8*)&Bs[wc * WN + n * 16 + ar][kb];
#pragma unroll
    for (int m = 0; m < FM; ++m)
#pragma unroll
      for (int n = 0; n < FN; ++n)
        acc[m][n] = __builtin_amdgcn_mfma_f32_16x16x32_bf16(af[m], bw[n], acc[m][n], 0, 0, 0);
    __syncthreads();   // protect tiles before next-iteration overwrite
  }

  // epilogue: D[row][col], col = lane&15, row = (lane>>4)*4 + u  [m89-verified]
#pragma unroll
  for (int m = 0; m < FM; ++m) {
    int rbase = row0 + wr * WM + m * 16 + (lane >> 4) * 4;
#pragma unroll
    for (int n = 0; n < FN; ++n) {
      int col = col0 + wc * WN + n * 16 + ar;
      float bi = bias[col];
#pragma unroll
      for (int u = 0; u < 4; ++u) {
        int row = rbase + u;
        float v = acc[m][n][u] + bi;
        if (ADD_RES) v += res[(size_t)row * N + col];
        if (RELU) v = fmaxf(v, 0.f);
        if constexpr (OUTMODE == 0) {
          Cf[(size_t)row * N + col] = v;
        } else {
          u16 hi = f2bf(v);
          u16 lo = f2bf(v - bf2f(hi));
          size_t rb = (size_t)row * 3 * N;
          C3[rb + col]         = hi;
          C3[rb + N + col]     = hi;
          C3[rb + 2 * N + col] = lo;
        }
      }
    }
  }
}

// ---------------- layernorm over last dim (512), optional residual ----------------
template<bool HAS_RES, bool FINAL>
__global__ __launch_bounds__(256) void ln_kernel(
    const float* __restrict__ in, const float* __restrict__ res,
    const float* __restrict__ g, const float* __restrict__ b,
    void* __restrict__ out, const int* __restrict__ flag)
{
  int row = blockIdx.x, tid = threadIdx.x;
  size_t base = (size_t)row * DIMc;
  float x0 = in[base + tid], x1 = in[base + tid + 256];
  if (HAS_RES) { x0 += res[base + tid]; x1 += res[base + tid + 256]; }
  float s1 = x0 + x1, s2 = x0 * x0 + x1 * x1;
#pragma unroll
  for (int off = 1; off < 64; off <<= 1) { s1 += __shfl_xor(s1, off); s2 += __shfl_xor(s2, off); }
  __shared__ float p1[4], p2[4], stat[2];
  if ((tid & 63) == 0) { p1[tid >> 6] = s1; p2[tid >> 6] = s2; }
  __syncthreads();
  if (tid == 0) {
    float t1 = p1[0] + p1[1] + p1[2] + p1[3];
    float t2 = p2[0] + p2[1] + p2[2] + p2[3];
    float mu = t1 / DIMc;
    float var = t2 / DIMc - mu * mu;
    stat[0] = mu; stat[1] = rsqrtf(var + LN_EPS);
  }
  __syncthreads();
  float mu = stat[0], rv = stat[1];
  float y0 = (x0 - mu) * rv * g[tid] + b[tid];
  float y1 = (x1 - mu) * rv * g[tid + 256] + b[tid + 256];
  if (FINAL) {
    if (*flag) {
      __hip_bfloat16* o = (__hip_bfloat16*)out;
      o[base + tid] = __float2bfloat16(y0);
      o[base + tid + 256] = __float2bfloat16(y1);
    } else {
      float* o = (float*)out;
      o[base + tid] = y0;
      o[base + tid + 256] = y1;
    }
  } else {
    float* o = (float*)out;
    o[base + tid] = y0;
    o[base + tid + 256] = y1;
  }
}

// ---------------- causal linear attention, pass A: per-chunk KV sums ----------------
__global__ __launch_bounds__(256) void causalA(const float* __restrict__ qvk,
    float* __restrict__ chunkKV, float* __restrict__ chunkKs)
{
  int c = blockIdx.x, bh = blockIdx.y;
  int b = bh >> 3, h = bh & 7;
  __shared__ float ks[CT][Ec];
  __shared__ float vs[CT][Ec];
  int tid = threadIdx.x;
#pragma unroll
  for (int j = 0; j < 16; ++j) {
    int i = tid + 256 * j;
    int t = i >> 6, d = i & 63;
    size_t rowbase = ((size_t)b * Nc + c * CT + t) * (3 * DIMc);
    ks[t][d] = __expf(qvk[rowbase + 2 * DIMc + h * Ec + d]);
    vs[t][d] = qvk[rowbase + DIMc + h * Ec + d];
  }
  __syncthreads();
  int e = tid & 63, d0 = tid >> 6;
  float acc[16] = {};
  for (int t = 0; t < CT; ++t) {
    float ve = vs[t][e];
#pragma unroll
    for (int j = 0; j < 16; ++j) acc[j] += ks[t][d0 + 4 * j] * ve;
  }
  size_t obase = ((size_t)bh * NCc + c) * (Ec * Ec);
#pragma unroll
  for (int j = 0; j < 16; ++j) chunkKV[obase + (size_t)(d0 + 4 * j) * Ec + e] = acc[j];
  if (tid < Ec) {
    float s = 0;
    for (int t = 0; t < CT; ++t) s += ks[t][tid];
    chunkKs[((size_t)bh * NCc + c) * Ec + tid] = s;
  }
}

// ---------------- pass B: in-place exclusive prefix over chunks ----------------
__global__ __launch_bounds__(256) void causalB(float* __restrict__ chunkKV,
                                               float* __restrict__ chunkKs)
{
  int bh = blockIdx.x, tid = threadIdx.x;
  for (int idx = tid; idx < Ec * Ec; idx += 256) {
    float run = 0;
    size_t base = (size_t)bh * NCc * Ec * Ec + idx;
    for (int c = 0; c < NCc; ++c) {
      float t = chunkKV[base + (size_t)c * Ec * Ec];
      chunkKV[base + (size_t)c * Ec * Ec] = run;
      run += t;
    }
  }
  if (tid < Ec) {
    float run = 0;
    size_t base = (size_t)bh * NCc * Ec + tid;
    for (int c = 0; c < NCc; ++c) {
      float t = chunkKs[base + (size_t)c * Ec];
      chunkKs[base + (size_t)c * Ec] = run;
      run += t;
    }
  }
}

// ---------------- pass C: per-token outputs ----------------
__global__ __launch_bounds__(256) void causalC(const float* __restrict__ qvk,
    const float* __restrict__ chunkKV, const float* __restrict__ chunkKs,
    float* __restrict__ attn_out)
{
  int c = blockIdx.x, bh = blockIdx.y;
  int b = bh >> 3, h = bh & 7;
  __shared__ float S[Ec][Ec];        // exclusive KV prefix
  __shared__ float ks[CT][Ec + 1];
  __shared__ float vs[CT][Ec];
  __shared__ float kpre[Ec];
  int tid = threadIdx.x;
  size_t kvb = (size_t)bh * NCc + c;
#pragma unroll
  for (int j = 0; j < 16; ++j) {
    int i = tid + 256 * j;
    int t = i >> 6, d = i & 63;
    S[t][d] = chunkKV[kvb * (Ec * Ec) + i];
    size_t rowbase = ((size_t)b * Nc + c * CT + t) * (3 * DIMc);
    ks[t][d] = __expf(qvk[rowbase + 2 * DIMc + h * Ec + d]);
    vs[t][d] = qvk[rowbase + DIMc + h * Ec + d];
  }
  if (tid < Ec) kpre[tid] = chunkKs[kvb * Ec + tid] + ATTN_EPS;
  __syncthreads();
  int w = tid >> 6, lane = tid & 63;
  for (int ti = 0; ti < 16; ++ti) {
    int t = w * 16 + ti;  // token index within chunk (uniform per wave)
    size_t rowbase = ((size_t)b * Nc + c * CT + t) * (3 * DIMc);
    float qv = qvk[rowbase + h * Ec + lane];
    float mx = qv;
#pragma unroll
    for (int off = 1; off < 64; off <<= 1) mx = fmaxf(mx, __shfl_xor(mx, off));
    float ex = __expf(qv - mx);
    float ssum = ex;
#pragma unroll
    for (int off = 1; off < 64; off <<= 1) ssum += __shfl_xor(ssum, off);
    float qs = ex / ssum * 0.125f;     // softmax(q)[lane] * E^-0.5
    // intra-chunk score for tau = lane
    float a = 0;
    for (int d = 0; d < Ec; ++d) a += __shfl(qs, d) * ks[lane][d];
    float am = (lane <= t) ? a : 0.f;
    // denominator
    float r = am + qs * kpre[lane];
#pragma unroll
    for (int off = 1; off < 64; off <<= 1) r += __shfl_xor(r, off);
    float dinv = 1.f / r;
    // output element e = lane
    float acc = 0;
    for (int d = 0; d < Ec; ++d) acc += __shfl(qs, d) * S[d][lane];
    for (int tau = 0; tau <= t; ++tau) acc += __shfl(am, tau) * vs[tau][lane];
    attn_out[((size_t)b * Nc + c * CT + t) * DIMc + h * Ec + lane] = acc * dinv;
  }
}

// ---------------- cross-attn: ctxU[d,e] = sum_m exp(k2)[m,d] * v2[m,e]  (+colsum) ----
// Unnormalized; also accumulates colsum[d] = sum_m exp(k2[m,d]) from the staged tile.
__global__ __launch_bounds__(256) void ctx_kernel(const float* __restrict__ kvbuf,
    float* __restrict__ colsum, float* __restrict__ ctx)
{
  int slab = blockIdx.x, bh = blockIdx.y;
  int b = bh >> 3, h = bh & 7;
  __shared__ float ks[64][Ec];
  __shared__ float vs[64][Ec];
  int tid = threadIdx.x;
#pragma unroll
  for (int j = 0; j < 16; ++j) {
    int i = tid + 256 * j;
    int m = i >> 6, d = i & 63;
    size_t rowbase = ((size_t)b * Mc + slab * 64 + m) * (2 * DIMc);
    ks[m][d] = __expf(kvbuf[rowbase + h * Ec + d]);
    vs[m][d] = kvbuf[rowbase + DIMc + h * Ec + d];
  }
  __syncthreads();
  int e = tid & 63, d0 = tid >> 6;
  float acc[16] = {};
  for (int m = 0; m < 64; ++m) {
    float ve = vs[m][e];
#pragma unroll
    for (int j = 0; j < 16; ++j) acc[j] += ks[m][d0 + 4 * j] * ve;
  }
  size_t obase = (size_t)bh * Ec * Ec;
#pragma unroll
  for (int j = 0; j < 16; ++j) atomicAdd(&ctx[obase + (size_t)(d0 + 4 * j) * Ec + e], acc[j]);
  // partial column sums of exp(k2) from the LDS tile (was the 153us colsum_kernel)
  int w = tid >> 6, lane = tid & 63;
  float s = 0;
#pragma unroll
  for (int m = 0; m < 16; ++m) s += ks[w * 16 + m][lane];
  __shared__ float p[4][Ec];
  p[w][lane] = s;
  __syncthreads();
  if (tid < Ec)
    atomicAdd(&colsum[(size_t)bh * Ec + tid], p[0][tid] + p[1][tid] + p[2][tid] + p[3][tid]);
}

// ---------------- normalize ctx rows by colsum (tiny) ----------------
__global__ __launch_bounds__(256) void normctx(float* __restrict__ ctx,
                                               const float* __restrict__ colsum)
{
  int bh = blockIdx.x, tid = threadIdx.x;
#pragma unroll
  for (int j = 0; j < 16; ++j) {
    int i = tid + 256 * j;
    int d = i >> 6;
    ctx[(size_t)bh * Ec * Ec + i] /= colsum[(size_t)bh * Ec + d];
  }
}

// ---------------- cross-attn: out[t,e] = softmax(q2[t])*E^-.5 @ ctx ----------------
__global__ __launch_bounds__(256) void attn2_kernel(const float* __restrict__ q2,
    const float* __restrict__ ctx, float* __restrict__ out)
{
  int bh = blockIdx.y;
  int b = bh >> 3, h = bh & 7;
  __shared__ float cs[Ec][Ec];
  int tid = threadIdx.x;
#pragma unroll
  for (int j = 0; j < 16; ++j) {
    int i = tid + 256 * j;
    cs[i >> 6][i & 63] = ctx[(size_t)bh * Ec * Ec + i];
  }
  __syncthreads();
  int w = tid >> 6, lane = tid & 63;
  int t = blockIdx.x * 4 + w;
  float qv = q2[((size_t)b * Nc + t) * DIMc + h * Ec + lane];
  float mx = qv;
#pragma unroll
  for (int off = 1; off < 64; off <<= 1) mx = fmaxf(mx, __shfl_xor(mx, off));
  float ex = __expf(qv - mx);
  float ssum = ex;
#pragma unroll
  for (int off = 1; off < 64; off <<= 1) ssum += __shfl_xor(ssum, off);
  float qs = ex / ssum * 0.125f;
  float acc = 0;
  for (int d = 0; d < Ec; ++d) acc += __shfl(qs, d) * cs[d][lane];
  out[((size_t)b * Nc + t) * DIMc + h * Ec + lane] = acc;
}

extern "C" void kernel_launch(void* const* d_in, const int* in_sizes, int n_in,
                              void* d_out, int out_size, void* d_ws, size_t ws_size,
                              hipStream_t stream)
{
  // ---- workspace layout (fp32-equivalent elements) ----
  // [0,64): flag
  // conv: fp32 copies of all 18 inputs (7,873,024 floats)
  // region0 (12,582,912 f-eq): qvk fp32 (6.29M) -> kvbuf+q2 fp32 (6.29M)
  //                            -> O3ff bf16 split (25.17M u16 = 12.58M f-eq)
  // out1 (2.10M), attn_o/ybuf (2.10M), r3: chunkKV->pre3 (2.10M), smalls
  // B3 region: 5 transposed+split weight matrices (11.01M u16 = 5.51M f-eq)
  // A3a scratch: one 4096x1536 u16 activation-split slot, reused 4x (3.15M f-eq)
  float* ws = (float*)d_ws;
  int* flag = (int*)ws;
  float* conv = ws + 64;

  float* cin[18];
  size_t off = 0;
  for (int i = 0; i < 18; ++i) { cin[i] = conv + off; off += (size_t)in_sizes[i]; }
  float* pipe = conv + off;

  const size_t SZ_ROW = (size_t)Bc * Nc * DIMc;            // 2,097,152
  const size_t SZ_KV  = (size_t)Bc * Mc * 2 * DIMc;        // 4,194,304
  const size_t SZ_R0  = (size_t)Bc * Nc * 3 * FFc / 2;     // 12,582,912 f-eq (O3ff)

  float* region0 = pipe;
  float* qvk     = region0;                   // live: gemm1 .. causalC
  float* kvbuf   = region0;                   // live: kvGEMM .. ctx_kernel
  float* q2      = region0 + SZ_KV;           // live: q2GEMM .. attn2
  u16*   O3ff    = (u16*)region0;             // live: ff1 .. ff2 (split format)
  float* out1    = region0 + SZ_R0;           // live: LN1 .. LN2
  float* attn_o  = out1 + SZ_ROW;             // attn_o -> attn2_o -> ybuf
  float* r3      = attn_o + SZ_ROW;           // chunkKV -> pre3
  float* chunkKV = r3;
  float* pre3    = r3;
  float* chunkKs = r3 + SZ_ROW;                                   // 32768
  float* colsum  = chunkKs + (size_t)Bc * Hc * NCc * Ec;          // 1024
  float* ctx2    = colsum + (size_t)Bc * Hc * Ec;                 // 65536
  float* ybuf    = attn_o;
  float* attn2_o = attn_o;

  u16* B3_qvk = (u16*)(ctx2 + (size_t)Bc * Hc * Ec * Ec);
  u16* B3_kv  = B3_qvk + (size_t)(3 * DIMc) * (3 * DIMc);   // 1536*1536
  u16* B3_q   = B3_kv  + (size_t)(2 * DIMc) * (3 * DIMc);   // 1024*1536
  u16* B3_ff1 = B3_q   + (size_t)DIMc * (3 * DIMc);         // 512*1536
  u16* B3_ff2 = B3_ff1 + (size_t)FFc  * (3 * DIMc);         // 2048*1536
  u16* A3a    = B3_ff2 + (size_t)DIMc * (3 * FFc);          // 512*6144
  (void)ws_size; (void)n_in; (void)out_size;

  dim3 blk(256);
  const int MR = Bc * Nc;  // 4096 rows

  // 0. detect input dtype, convert everything to fp32
  detect_kernel<<<dim3(1), dim3(64), 0, stream>>>(d_in[0], flag);
  ConvJobs jobs;
  for (int i = 0; i < 18; ++i) { jobs.j[i].src = d_in[i]; jobs.j[i].dst = cin[i]; jobs.j[i].n = in_sizes[i]; }
  ingest_kernel<<<dim3(64, 18), blk, 0, stream>>>(jobs, flag);

  const float *x = cin[0], *memory = cin[1], *W_qvk = cin[2], *b_qvk = cin[3],
              *W_kv = cin[4], *b_kv = cin[5], *W_q = cin[6], *b_q = cin[7],
              *W_ff1 = cin[8], *b_ff1 = cin[9], *W_ff2 = cin[10], *b_ff2 = cin[11],
              *ln1_g = cin[12], *ln1_b = cin[13], *ln2_g = cin[14], *ln2_b = cin[15],
              *ln3_g = cin[16], *ln3_b = cin[17];

  // 0b. weight transpose+split (once)
  wsplit_kernel<<<dim3(24, 8), blk, 0, stream>>>(W_qvk, B3_qvk, DIMc, 3 * DIMc);
  wsplit_kernel<<<dim3(16, 8), blk, 0, stream>>>(W_kv,  B3_kv,  DIMc, 2 * DIMc);
  wsplit_kernel<<<dim3(8, 8),  blk, 0, stream>>>(W_q,   B3_q,   DIMc, DIMc);
  wsplit_kernel<<<dim3(32, 8), blk, 0, stream>>>(W_ff1, B3_ff1, DIMc, FFc);
  wsplit_kernel<<<dim3(8, 32), blk, 0, stream>>>(W_ff2, B3_ff2, FFc,  DIMc);

  // 1. qvk = x @ W_qvk + b   (MFMA, 3-term split)
  split_act<<<dim3(1024), blk, 0, stream>>>(x, A3a, 9, (int)SZ_ROW);
  gemm_mfma<128, 128, 0, false, false><<<dim3(12, 32), blk, 0, stream>>>(
      A3a, B3_qvk, b_qvk, nullptr, qvk, nullptr, 3 * DIMc, 3 * DIMc);
  // 2. causal linear self-attention
  causalA<<<dim3(NCc, Bc * Hc), blk, 0, stream>>>(qvk, chunkKV, chunkKs);
  causalB<<<dim3(Bc * Hc), blk, 0, stream>>>(chunkKV, chunkKs);
  causalC<<<dim3(NCc, Bc * Hc), blk, 0, stream>>>(qvk, chunkKV, chunkKs, attn_o);
  // 3. LN1(attn + x)
  ln_kernel<true, false><<<dim3(MR), blk, 0, stream>>>(
      attn_o, x, ln1_g, ln1_b, out1, flag);
  // 4. kv = memory @ W_kv + b (overwrites dead qvk) ; q2 = out1 @ W_q + b
  split_act<<<dim3(1024), blk, 0, stream>>>(memory, A3a, 9, (int)SZ_ROW);
  gemm_mfma<128, 128, 0, false, false><<<dim3(8, 32), blk, 0, stream>>>(
      A3a, B3_kv, b_kv, nullptr, kvbuf, nullptr, 2 * DIMc, 3 * DIMc);
  split_act<<<dim3(1024), blk, 0, stream>>>(out1, A3a, 9, (int)SZ_ROW);
  gemm_mfma<128, 64, 0, false, false><<<dim3(8, 32), blk, 0, stream>>>(
      A3a, B3_q, b_q, nullptr, q2, nullptr, DIMc, 3 * DIMc);
  // 5. cross linear attention (colsum fused into ctx_kernel; tiny normalize pass)
  hipMemsetAsync(colsum, 0,
      ((size_t)Bc * Hc * Ec + (size_t)Bc * Hc * Ec * Ec) * sizeof(float), stream);
  ctx_kernel<<<dim3(Mc / 64, Bc * Hc), blk, 0, stream>>>(kvbuf, colsum, ctx2);
  normctx<<<dim3(Bc * Hc), blk, 0, stream>>>(ctx2, colsum);
  attn2_kernel<<<dim3(Nc / 4, Bc * Hc), blk, 0, stream>>>(q2, ctx2, attn2_o);
  // 6. LN2(attn2 + out1) in-place
  ln_kernel<true, false><<<dim3(MR), blk, 0, stream>>>(
      attn2_o, out1, ln2_g, ln2_b, ybuf, flag);
  // 7. FF: ff1 writes split-A3 format directly (fused relu+split, overwrites dead kvbuf/q2)
  split_act<<<dim3(1024), blk, 0, stream>>>(ybuf, A3a, 9, (int)SZ_ROW);
  gemm_mfma<128, 128, 1, true, false><<<dim3(16, 32), blk, 0, stream>>>(
      A3a, B3_ff1, b_ff1, nullptr, nullptr, O3ff, FFc, 3 * DIMc);
  gemm_mfma<128, 64, 0, false, true><<<dim3(8, 32), blk, 0, stream>>>(
      O3ff, B3_ff2, b_ff2, ybuf, pre3, nullptr, DIMc, 3 * FFc);
  // 8. LN3 -> d_out (bf16 or fp32 per flag)
  ln_kernel<false, true><<<dim3(MR), blk, 0, stream>>>(
      pre3, nullptr, ln3_g, ln3_b, d_out, flag);
}

// Round 3
// 621.540 us; speedup vs baseline: 2.0093x; 1.1696x over previous
//
#include <hip/hip_runtime.h>
#include <hip/hip_bf16.h>

#define DEV __device__ __forceinline__

constexpr int Bc = 2, Nc = 2048, Mc = 2048, DIMc = 512, Hc = 8, FFc = 2048, Ec = 64;
constexpr int CT = 64;            // causal chunk length (tokens)
constexpr int NCc = Nc / CT;      // 32 chunks per sequence
constexpr float LN_EPS = 1e-5f, ATTN_EPS = 1e-6f;

typedef __bf16 bfrag8 __attribute__((ext_vector_type(8)));
typedef float ffrag4 __attribute__((ext_vector_type(4)));
typedef unsigned short u16;

// ---------------- helpers ----------------
DEV u16 f2bf(float v) {
  __hip_bfloat16 h = __float2bfloat16(v);   // RTN-even
  return __builtin_bit_cast(unsigned short, h);
}
DEV float bf2f(u16 u) { return __uint_as_float(((unsigned)u) << 16); }

DEV void gload16(const void* g, void* l) {
  __builtin_amdgcn_global_load_lds(
      (const __attribute__((address_space(1))) void*)g,
      (__attribute__((address_space(3))) void*)l, 16, 0, 0);
}

// XOR swizzle for [64][64] u16 LDS tiles (row stride 128B): spreads the
// 16 A/B-frag rows across banks (2-way, free). c must stay in [0,64).
DEV int SW(int r, int c) { return r * 64 + (c ^ ((r & 7) << 3)); }

// ---------------- dtype detection + ingest to canonical fp32 ----------------
__global__ __launch_bounds__(64) void detect_kernel(const void* x, int* flag) {
  const unsigned short* u = (const unsigned short*)x;
  int tid = threadIdx.x;
  int bad = 0;
#pragma unroll
  for (int i = 0; i < 8; ++i) {
    float v = __uint_as_float(((unsigned)u[tid * 8 + i]) << 16);
    if (!(fabsf(v) <= 1e4f)) bad = 1;   // catches NaN, Inf, garbage
  }
  unsigned long long m = __ballot(bad);
  if (tid == 0) *flag = (m == 0ull) ? 1 : 0;  // 1 = inputs are bf16
}

struct ConvJob { const void* src; float* dst; int n; };
struct ConvJobs { ConvJob j[18]; };

__global__ __launch_bounds__(256) void ingest_kernel(ConvJobs jobs, const int* flag) {
  int bf = *flag;
  ConvJob jb = jobs.j[blockIdx.y];
  int stride = gridDim.x * 256;
  for (int i = blockIdx.x * 256 + threadIdx.x; i < jb.n; i += stride) {
    float v;
    if (bf) v = __uint_as_float(((unsigned)((const unsigned short*)jb.src)[i]) << 16);
    else    v = ((const float*)jb.src)[i];
    jb.dst[i] = v;
  }
}

// ---------------- fp32 -> 3-term bf16 split (activations) ----------------
// out layout: row-major M x 3K bf16: [hi | hi | lo]
__global__ __launch_bounds__(256) void split_act(const float* __restrict__ in,
    u16* __restrict__ out, int kshift, int total)
{
  const int K = 1 << kshift;
  int stride = gridDim.x * 256 * 4;
  for (int i = (blockIdx.x * 256 + threadIdx.x) * 4; i < total; i += stride) {
    float4 a = *(const float4*)&in[i];
    int row = i >> kshift;
    int k = i & (K - 1);
    u16 h[4], l[4];
    float v[4] = {a.x, a.y, a.z, a.w};
#pragma unroll
    for (int j = 0; j < 4; ++j) {
      h[j] = f2bf(v[j]);
      l[j] = f2bf(v[j] - bf2f(h[j]));
    }
    uint2 hv, lv;
    hv.x = (unsigned)h[0] | ((unsigned)h[1] << 16);
    hv.y = (unsigned)h[2] | ((unsigned)h[3] << 16);
    lv.x = (unsigned)l[0] | ((unsigned)l[1] << 16);
    lv.y = (unsigned)l[2] | ((unsigned)l[3] << 16);
    size_t rb = (size_t)row * 3 * K + k;
    *(uint2*)&out[rb]         = hv;
    *(uint2*)&out[rb + K]     = hv;
    *(uint2*)&out[rb + 2 * K] = lv;
  }
}

// ---------------- W (KxN fp32) -> B3t (N x 3K bf16) transpose+split ----------------
// B3t[n][k] = hi(W[k][n]); B3t[n][K+k] = lo; B3t[n][2K+k] = hi.
// Pairs with A3 = [hi|hi|lo]: terms hi*hi + hi*lo + lo*hi.
__global__ __launch_bounds__(256) void wsplit_kernel(const float* __restrict__ W,
    u16* __restrict__ B3t, int K, int N)
{
  __shared__ float T[64][65];
  int n0 = blockIdx.x * 64, k0 = blockIdx.y * 64;
  int tid = threadIdx.x;
#pragma unroll
  for (int j = 0; j < 16; ++j) {
    int idx = tid + 256 * j;
    int kl = idx >> 6, nl = idx & 63;
    T[kl][nl] = W[(size_t)(k0 + kl) * N + n0 + nl];
  }
  __syncthreads();
#pragma unroll
  for (int j = 0; j < 16; ++j) {
    int idx = tid + 256 * j;
    int nl = idx >> 6, kl = idx & 63;
    float v = T[kl][nl];
    u16 hi = f2bf(v);
    u16 lo = f2bf(v - bf2f(hi));
    size_t rb = (size_t)(n0 + nl) * 3 * K + k0 + kl;
    B3t[rb]         = hi;
    B3t[rb + K]     = lo;
    B3t[rb + 2 * K] = hi;
  }
}

// ---------------- MFMA GEMM: C[M,N] = A3[M,K3] @ B3t[N,K3]^T (+bias)(+res)(relu) ----
// m97-style structure: 128-row tile, BK=32, 4 waves in 2x2, each wave 64x(BN/2),
// global_load_lds width-16 staging, 16x16x32 bf16 MFMA, fp32 accumulate.
// OUTMODE 0: write fp32 C. OUTMODE 1: write split-A3 bf16 [hi|hi|lo] (row len 3N).
template<int BM, int BN, int OUTMODE, bool RELU, bool ADD_RES>
__global__ __launch_bounds__(256) void gemm_mfma(
    const u16* __restrict__ A3, const u16* __restrict__ B3t,
    const float* __restrict__ bias, const float* __restrict__ res,
    float* __restrict__ Cf, u16* __restrict__ C3,
    int N, int K3)
{
  constexpr int WM = BM / 2, WN = BN / 2, FM = WM / 16, FN = WN / 16;
  __shared__ u16 As[BM][32];
  __shared__ u16 Bs[BN][32];
  const int tid = threadIdx.x;
  const int lane = tid & 63, wid = tid >> 6;
  const int wr = wid >> 1, wc = wid & 1;
  const int row0 = blockIdx.y * BM, col0 = blockIdx.x * BN;
  const int sr = lane >> 2, sk = (lane & 3) * 8;     // staging coords (16B/lane)
  const int ar = lane & 15, kb = (lane >> 4) * 8;    // fragment coords

  ffrag4 acc[FM][FN];
#pragma unroll
  for (int m = 0; m < FM; ++m)
#pragma unroll
    for (int n = 0; n < FN; ++n) acc[m][n] = ffrag4{0.f, 0.f, 0.f, 0.f};

  for (int k0 = 0; k0 < K3; k0 += 32) {
    // stage A tile: BM x 32 bf16, 16-row chunks of 1KB per wave-instruction
    for (int r = wid; r < BM / 16; r += 4)
      gload16(&A3[(size_t)(row0 + r * 16 + sr) * K3 + k0 + sk], &As[r * 16][0]);
    // stage B^T tile: BN x 32 bf16
    for (int r = wid; r < BN / 16; r += 4)
      gload16(&B3t[(size_t)(col0 + r * 16 + sr) * K3 + k0 + sk], &Bs[r * 16][0]);
    __syncthreads();   // drains vmcnt(0): LDS tiles ready

    bfrag8 af[FM], bw[FN];
#pragma unroll
    for (int m = 0; m < FM; ++m)
      af[m] = *(const bfrag8*)&As[wr * WM + m * 16 + ar][kb];
#pragma unroll
    for (int n = 0; n < FN; ++n)
      bw[n] = *(const bfrag8*)&Bs[wc * WN + n * 16 + ar][kb];
#pragma unroll
    for (int m = 0; m < FM; ++m)
#pragma unroll
      for (int n = 0; n < FN; ++n)
        acc[m][n] = __builtin_amdgcn_mfma_f32_16x16x32_bf16(af[m], bw[n], acc[m][n], 0, 0, 0);
    __syncthreads();   // protect tiles before next-iteration overwrite
  }

  // epilogue: D[row][col], col = lane&15, row = (lane>>4)*4 + u  [m89-verified]
#pragma unroll
  for (int m = 0; m < FM; ++m) {
    int rbase = row0 + wr * WM + m * 16 + (lane >> 4) * 4;
#pragma unroll
    for (int n = 0; n < FN; ++n) {
      int col = col0 + wc * WN + n * 16 + ar;
      float bi = bias[col];
#pragma unroll
      for (int u = 0; u < 4; ++u) {
        int row = rbase + u;
        float v = acc[m][n][u] + bi;
        if (ADD_RES) v += res[(size_t)row * N + col];
        if (RELU) v = fmaxf(v, 0.f);
        if constexpr (OUTMODE == 0) {
          Cf[(size_t)row * N + col] = v;
        } else {
          u16 hi = f2bf(v);
          u16 lo = f2bf(v - bf2f(hi));
          size_t rb = (size_t)row * 3 * N;
          C3[rb + col]         = hi;
          C3[rb + N + col]     = hi;
          C3[rb + 2 * N + col] = lo;
        }
      }
    }
  }
}

// ---------------- layernorm over last dim (512), optional residual ----------------
template<bool HAS_RES, bool FINAL>
__global__ __launch_bounds__(256) void ln_kernel(
    const float* __restrict__ in, const float* __restrict__ res,
    const float* __restrict__ g, const float* __restrict__ b,
    void* __restrict__ out, const int* __restrict__ flag)
{
  int row = blockIdx.x, tid = threadIdx.x;
  size_t base = (size_t)row * DIMc;
  float x0 = in[base + tid], x1 = in[base + tid + 256];
  if (HAS_RES) { x0 += res[base + tid]; x1 += res[base + tid + 256]; }
  float s1 = x0 + x1, s2 = x0 * x0 + x1 * x1;
#pragma unroll
  for (int off = 1; off < 64; off <<= 1) { s1 += __shfl_xor(s1, off); s2 += __shfl_xor(s2, off); }
  __shared__ float p1[4], p2[4], stat[2];
  if ((tid & 63) == 0) { p1[tid >> 6] = s1; p2[tid >> 6] = s2; }
  __syncthreads();
  if (tid == 0) {
    float t1 = p1[0] + p1[1] + p1[2] + p1[3];
    float t2 = p2[0] + p2[1] + p2[2] + p2[3];
    float mu = t1 / DIMc;
    float var = t2 / DIMc - mu * mu;
    stat[0] = mu; stat[1] = rsqrtf(var + LN_EPS);
  }
  __syncthreads();
  float mu = stat[0], rv = stat[1];
  float y0 = (x0 - mu) * rv * g[tid] + b[tid];
  float y1 = (x1 - mu) * rv * g[tid + 256] + b[tid + 256];
  if (FINAL) {
    if (*flag) {
      __hip_bfloat16* o = (__hip_bfloat16*)out;
      o[base + tid] = __float2bfloat16(y0);
      o[base + tid + 256] = __float2bfloat16(y1);
    } else {
      float* o = (float*)out;
      o[base + tid] = y0;
      o[base + tid + 256] = y1;
    }
  } else {
    float* o = (float*)out;
    o[base + tid] = y0;
    o[base + tid + 256] = y1;
  }
}

// ---------------- causal linear attention, pass A: per-chunk KV sums ----------------
// NOTE: now writes chunkKV TRANSPOSED: chunkKVT[e][d] = sum_t ks[t][d]*vs[t][e]
__global__ __launch_bounds__(256) void causalA(const float* __restrict__ qvk,
    float* __restrict__ chunkKVT, float* __restrict__ chunkKs)
{
  int c = blockIdx.x, bh = blockIdx.y;
  int b = bh >> 3, h = bh & 7;
  __shared__ float ks[CT][Ec];
  __shared__ float vs[CT][Ec];
  int tid = threadIdx.x;
#pragma unroll
  for (int j = 0; j < 16; ++j) {
    int i = tid + 256 * j;
    int t = i >> 6, d = i & 63;
    size_t rowbase = ((size_t)b * Nc + c * CT + t) * (3 * DIMc);
    ks[t][d] = __expf(qvk[rowbase + 2 * DIMc + h * Ec + d]);
    vs[t][d] = qvk[rowbase + DIMc + h * Ec + d];
  }
  __syncthreads();
  int e = tid & 63, d0 = tid >> 6;
  float acc[16] = {};
  for (int t = 0; t < CT; ++t) {
    float ve = vs[t][e];
#pragma unroll
    for (int j = 0; j < 16; ++j) acc[j] += ks[t][d0 + 4 * j] * ve;
  }
  size_t obase = ((size_t)bh * NCc + c) * (Ec * Ec);
#pragma unroll
  for (int j = 0; j < 16; ++j) chunkKVT[obase + (size_t)e * Ec + (d0 + 4 * j)] = acc[j];
  if (tid < Ec) {
    float s = 0;
    for (int t = 0; t < CT; ++t) s += ks[t][tid];
    chunkKs[((size_t)bh * NCc + c) * Ec + tid] = s;
  }
}

// ---------------- pass B: in-place exclusive prefix over chunks (layout-agnostic) ----
__global__ __launch_bounds__(256) void causalB(float* __restrict__ chunkKV,
                                               float* __restrict__ chunkKs)
{
  int bh = blockIdx.x, tid = threadIdx.x;
  for (int idx = tid; idx < Ec * Ec; idx += 256) {
    float run = 0;
    size_t base = (size_t)bh * NCc * Ec * Ec + idx;
    for (int c = 0; c < NCc; ++c) {
      float t = chunkKV[base + (size_t)c * Ec * Ec];
      chunkKV[base + (size_t)c * Ec * Ec] = run;
      run += t;
    }
  }
  if (tid < Ec) {
    float run = 0;
    size_t base = (size_t)bh * NCc * Ec + tid;
    for (int c = 0; c < NCc; ++c) {
      float t = chunkKs[base + (size_t)c * Ec];
      chunkKs[base + (size_t)c * Ec] = run;
      run += t;
    }
  }
}

// ---------------- pass C: per-token outputs via MFMA ----------------
// Per (chunk, head): P = QS·Ks^T (masked), O = QS·S + Pm·V, dinv from rowsum(Pm)+QS·kpre.
// All operands hi/lo bf16-split (3-term MFMA) for fp32-grade accuracy.
__global__ __launch_bounds__(256) void causalC(const float* __restrict__ qvk,
    const float* __restrict__ chunkKVT, const float* __restrict__ chunkKs,
    float* __restrict__ attn_out)
{
  int c = blockIdx.x, bh = blockIdx.y;
  int b = bh >> 3, h = bh & 7;
  __shared__ u16 qsh[64 * 64], qsl[64 * 64];   // A: qs[t][d]
  __shared__ u16 ksPh[64 * 64], ksPl[64 * 64]; // B: ks[tau][d]  ->  A: Pm[t][tau]
  __shared__ u16 STh[64 * 64], STl[64 * 64];   // B: S^T[e][d]
  __shared__ u16 VTh[64 * 72], VTl[64 * 72];   // B: V^T[e][tau], pad 72 (16B-aligned rows)
  __shared__ float kpre[Ec], r0[CT], dinv[CT];
  int tid = threadIdx.x;
  int lane = tid & 63, w = tid >> 6;
  const int ar = lane & 15, kb = (lane >> 4) * 8;
  size_t kvb = (size_t)bh * NCc + c;

  if (tid < Ec) kpre[tid] = chunkKs[kvb * Ec + tid] + ATTN_EPS;

  // --- load phase: wave w owns token band [w*16, w*16+16) ---
  float qreg[16];
#pragma unroll
  for (int j = 0; j < 16; ++j) {
    int t = w * 16 + j, d = lane;
    size_t rowbase = ((size_t)b * Nc + c * CT + t) * (3 * DIMc);
    qreg[j] = qvk[rowbase + h * Ec + d];
    float kv = __expf(qvk[rowbase + 2 * DIMc + h * Ec + d]);
    u16 hi = f2bf(kv);
    ksPh[SW(t, d)] = hi; ksPl[SW(t, d)] = f2bf(kv - bf2f(hi));
    float vv = qvk[rowbase + DIMc + h * Ec + d];
    hi = f2bf(vv);
    VTh[d * 72 + t] = hi; VTl[d * 72 + t] = f2bf(vv - bf2f(hi));
    float sv = chunkKVT[kvb * (Ec * Ec) + (size_t)t * Ec + d];  // row e=t of S^T
    hi = f2bf(sv);
    STh[SW(t, d)] = hi; STl[SW(t, d)] = f2bf(sv - bf2f(hi));
  }
  __syncthreads();   // kpre ready for softmax; ks/V/S staged

  // --- softmax per token + qk dot; write qs split ---
  for (int ti = 0; ti < 16; ++ti) {
    int t = w * 16 + ti;
    float qv = qreg[ti];
    float mx = qv;
#pragma unroll
    for (int off = 1; off < 64; off <<= 1) mx = fmaxf(mx, __shfl_xor(mx, off));
    float ex = __expf(qv - mx);
    float ssum = ex;
#pragma unroll
    for (int off = 1; off < 64; off <<= 1) ssum += __shfl_xor(ssum, off);
    float qs = ex / ssum * 0.125f;           // softmax(q)[lane] * E^-0.5
    float qk = qs * kpre[lane];
#pragma unroll
    for (int off = 1; off < 64; off <<= 1) qk += __shfl_xor(qk, off);
    if (lane == 0) r0[t] = qk;
    u16 hi = f2bf(qs);
    qsh[SW(t, lane)] = hi; qsl[SW(t, lane)] = f2bf(qs - bf2f(hi));
  }
  __syncthreads();   // all qs + ks visible

  // --- P = QS @ Ks^T : wave w computes rows [w*16, w*16+16) x all 64 cols ---
  ffrag4 pacc[4];
#pragma unroll
  for (int ct = 0; ct < 4; ++ct) pacc[ct] = ffrag4{0.f, 0.f, 0.f, 0.f};
#pragma unroll
  for (int ct = 0; ct < 4; ++ct)
#pragma unroll
    for (int k2 = 0; k2 < 64; k2 += 32) {
      bfrag8 ah = *(const bfrag8*)&qsh[SW(w * 16 + ar, k2 + kb)];
      bfrag8 al = *(const bfrag8*)&qsl[SW(w * 16 + ar, k2 + kb)];
      bfrag8 bh_ = *(const bfrag8*)&ksPh[SW(ct * 16 + ar, k2 + kb)];
      bfrag8 bl_ = *(const bfrag8*)&ksPl[SW(ct * 16 + ar, k2 + kb)];
      pacc[ct] = __builtin_amdgcn_mfma_f32_16x16x32_bf16(ah, bh_, pacc[ct], 0, 0, 0);
      pacc[ct] = __builtin_amdgcn_mfma_f32_16x16x32_bf16(ah, bl_, pacc[ct], 0, 0, 0);
      pacc[ct] = __builtin_amdgcn_mfma_f32_16x16x32_bf16(al, bh_, pacc[ct], 0, 0, 0);
    }
  __syncthreads();   // all waves done READING ks before P overwrites it

  // --- mask, rowsum -> dinv, store Pm split (aliased over ks arrays) ---
  float rs[4] = {0.f, 0.f, 0.f, 0.f};
#pragma unroll
  for (int ct = 0; ct < 4; ++ct) {
    int tau = ct * 16 + ar;
#pragma unroll
    for (int u = 0; u < 4; ++u) {
      int t = w * 16 + (lane >> 4) * 4 + u;
      float pv = (tau <= t) ? pacc[ct][u] : 0.f;
      rs[u] += pv;
      u16 hi = f2bf(pv);
      ksPh[SW(t, tau)] = hi; ksPl[SW(t, tau)] = f2bf(pv - bf2f(hi));
    }
  }
#pragma unroll
  for (int u = 0; u < 4; ++u) {
    float v = rs[u];
    v += __shfl_xor(v, 1); v += __shfl_xor(v, 2);
    v += __shfl_xor(v, 4); v += __shfl_xor(v, 8);
    if (ar == 0) {
      int t = w * 16 + (lane >> 4) * 4 + u;
      dinv[t] = 1.f / (r0[t] + v);
    }
  }
  __syncthreads();   // Pm + dinv visible

  // --- O = QS @ S + Pm @ V ---
#pragma unroll
  for (int et = 0; et < 4; ++et) {
    ffrag4 oacc = ffrag4{0.f, 0.f, 0.f, 0.f};
#pragma unroll
    for (int k2 = 0; k2 < 64; k2 += 32) {
      bfrag8 ah = *(const bfrag8*)&qsh[SW(w * 16 + ar, k2 + kb)];
      bfrag8 al = *(const bfrag8*)&qsl[SW(w * 16 + ar, k2 + kb)];
      bfrag8 bh_ = *(const bfrag8*)&STh[SW(et * 16 + ar, k2 + kb)];
      bfrag8 bl_ = *(const bfrag8*)&STl[SW(et * 16 + ar, k2 + kb)];
      oacc = __builtin_amdgcn_mfma_f32_16x16x32_bf16(ah, bh_, oacc, 0, 0, 0);
      oacc = __builtin_amdgcn_mfma_f32_16x16x32_bf16(ah, bl_, oacc, 0, 0, 0);
      oacc = __builtin_amdgcn_mfma_f32_16x16x32_bf16(al, bh_, oacc, 0, 0, 0);
      bfrag8 ph = *(const bfrag8*)&ksPh[SW(w * 16 + ar, k2 + kb)];
      bfrag8 pl = *(const bfrag8*)&ksPl[SW(w * 16 + ar, k2 + kb)];
      bfrag8 vh = *(const bfrag8*)&VTh[(et * 16 + ar) * 72 + k2 + kb];
      bfrag8 vl = *(const bfrag8*)&VTl[(et * 16 + ar) * 72 + k2 + kb];
      oacc = __builtin_amdgcn_mfma_f32_16x16x32_bf16(ph, vh, oacc, 0, 0, 0);
      oacc = __builtin_amdgcn_mfma_f32_16x16x32_bf16(ph, vl, oacc, 0, 0, 0);
      oacc = __builtin_amdgcn_mfma_f32_16x16x32_bf16(pl, vh, oacc, 0, 0, 0);
    }
    int e = et * 16 + ar;
#pragma unroll
    for (int u = 0; u < 4; ++u) {
      int t = w * 16 + (lane >> 4) * 4 + u;
      attn_out[((size_t)b * Nc + c * CT + t) * DIMc + h * Ec + e] = oacc[u] * dinv[t];
    }
  }
}

// ---------------- cross-attn: ctxU[d,e] = sum_m exp(k2)[m,d] * v2[m,e]  (+colsum) ----
// Unnormalized; also accumulates colsum[d] = sum_m exp(k2[m,d]) from the staged tile.
__global__ __launch_bounds__(256) void ctx_kernel(const float* __restrict__ kvbuf,
    float* __restrict__ colsum, float* __restrict__ ctx)
{
  int slab = blockIdx.x, bh = blockIdx.y;
  int b = bh >> 3, h = bh & 7;
  __shared__ float ks[64][Ec];
  __shared__ float vs[64][Ec];
  int tid = threadIdx.x;
#pragma unroll
  for (int j = 0; j < 16; ++j) {
    int i = tid + 256 * j;
    int m = i >> 6, d = i & 63;
    size_t rowbase = ((size_t)b * Mc + slab * 64 + m) * (2 * DIMc);
    ks[m][d] = __expf(kvbuf[rowbase + h * Ec + d]);
    vs[m][d] = kvbuf[rowbase + DIMc + h * Ec + d];
  }
  __syncthreads();
  int e = tid & 63, d0 = tid >> 6;
  float acc[16] = {};
  for (int m = 0; m < 64; ++m) {
    float ve = vs[m][e];
#pragma unroll
    for (int j = 0; j < 16; ++j) acc[j] += ks[m][d0 + 4 * j] * ve;
  }
  size_t obase = (size_t)bh * Ec * Ec;
#pragma unroll
  for (int j = 0; j < 16; ++j) atomicAdd(&ctx[obase + (size_t)(d0 + 4 * j) * Ec + e], acc[j]);
  // partial column sums of exp(k2) from the LDS tile
  int w = tid >> 6, lane = tid & 63;
  float s = 0;
#pragma unroll
  for (int m = 0; m < 16; ++m) s += ks[w * 16 + m][lane];
  __shared__ float p[4][Ec];
  p[w][lane] = s;
  __syncthreads();
  if (tid < Ec)
    atomicAdd(&colsum[(size_t)bh * Ec + tid], p[0][tid] + p[1][tid] + p[2][tid] + p[3][tid]);
}

// ---------------- normalize ctx rows by colsum (tiny) ----------------
__global__ __launch_bounds__(256) void normctx(float* __restrict__ ctx,
                                               const float* __restrict__ colsum)
{
  int bh = blockIdx.x, tid = threadIdx.x;
#pragma unroll
  for (int j = 0; j < 16; ++j) {
    int i = tid + 256 * j;
    int d = i >> 6;
    ctx[(size_t)bh * Ec * Ec + i] /= colsum[(size_t)bh * Ec + d];
  }
}

// ---------------- cross-attn: out[t,e] = softmax(q2[t])*E^-.5 @ ctx ----------------
__global__ __launch_bounds__(256) void attn2_kernel(const float* __restrict__ q2,
    const float* __restrict__ ctx, float* __restrict__ out)
{
  int bh = blockIdx.y;
  int b = bh >> 3, h = bh & 7;
  __shared__ float cs[Ec][Ec];
  int tid = threadIdx.x;
#pragma unroll
  for (int j = 0; j < 16; ++j) {
    int i = tid + 256 * j;
    cs[i >> 6][i & 63] = ctx[(size_t)bh * Ec * Ec + i];
  }
  __syncthreads();
  int w = tid >> 6, lane = tid & 63;
  int t = blockIdx.x * 4 + w;
  float qv = q2[((size_t)b * Nc + t) * DIMc + h * Ec + lane];
  float mx = qv;
#pragma unroll
  for (int off = 1; off < 64; off <<= 1) mx = fmaxf(mx, __shfl_xor(mx, off));
  float ex = __expf(qv - mx);
  float ssum = ex;
#pragma unroll
  for (int off = 1; off < 64; off <<= 1) ssum += __shfl_xor(ssum, off);
  float qs = ex / ssum * 0.125f;
  float acc = 0;
  for (int d = 0; d < Ec; ++d) acc += __shfl(qs, d) * cs[d][lane];
  out[((size_t)b * Nc + t) * DIMc + h * Ec + lane] = acc;
}

extern "C" void kernel_launch(void* const* d_in, const int* in_sizes, int n_in,
                              void* d_out, int out_size, void* d_ws, size_t ws_size,
                              hipStream_t stream)
{
  float* ws = (float*)d_ws;
  int* flag = (int*)ws;
  float* conv = ws + 64;

  float* cin[18];
  size_t off = 0;
  for (int i = 0; i < 18; ++i) { cin[i] = conv + off; off += (size_t)in_sizes[i]; }
  float* pipe = conv + off;

  const size_t SZ_ROW = (size_t)Bc * Nc * DIMc;            // 2,097,152
  const size_t SZ_KV  = (size_t)Bc * Mc * 2 * DIMc;        // 4,194,304
  const size_t SZ_R0  = (size_t)Bc * Nc * 3 * FFc / 2;     // 12,582,912 f-eq (O3ff)

  float* region0 = pipe;
  float* qvk     = region0;                   // live: gemm1 .. causalC
  float* kvbuf   = region0;                   // live: kvGEMM .. ctx_kernel
  float* q2      = region0 + SZ_KV;           // live: q2GEMM .. attn2
  u16*   O3ff    = (u16*)region0;             // live: ff1 .. ff2 (split format)
  float* out1    = region0 + SZ_R0;           // live: LN1 .. LN2
  float* attn_o  = out1 + SZ_ROW;             // attn_o -> attn2_o -> ybuf
  float* r3      = attn_o + SZ_ROW;           // chunkKV -> pre3
  float* chunkKV = r3;
  float* pre3    = r3;
  float* chunkKs = r3 + SZ_ROW;                                   // 32768
  float* colsum  = chunkKs + (size_t)Bc * Hc * NCc * Ec;          // 1024
  float* ctx2    = colsum + (size_t)Bc * Hc * Ec;                 // 65536
  float* ybuf    = attn_o;
  float* attn2_o = attn_o;

  u16* B3_qvk = (u16*)(ctx2 + (size_t)Bc * Hc * Ec * Ec);
  u16* B3_kv  = B3_qvk + (size_t)(3 * DIMc) * (3 * DIMc);   // 1536*1536
  u16* B3_q   = B3_kv  + (size_t)(2 * DIMc) * (3 * DIMc);   // 1024*1536
  u16* B3_ff1 = B3_q   + (size_t)DIMc * (3 * DIMc);         // 512*1536
  u16* B3_ff2 = B3_ff1 + (size_t)FFc  * (3 * DIMc);         // 2048*1536
  u16* A3a    = B3_ff2 + (size_t)DIMc * (3 * FFc);          // 512*6144
  (void)ws_size; (void)n_in; (void)out_size;

  dim3 blk(256);
  const int MR = Bc * Nc;  // 4096 rows

  // 0. detect input dtype, convert everything to fp32
  detect_kernel<<<dim3(1), dim3(64), 0, stream>>>(d_in[0], flag);
  ConvJobs jobs;
  for (int i = 0; i < 18; ++i) { jobs.j[i].src = d_in[i]; jobs.j[i].dst = cin[i]; jobs.j[i].n = in_sizes[i]; }
  ingest_kernel<<<dim3(64, 18), blk, 0, stream>>>(jobs, flag);

  const float *x = cin[0], *memory = cin[1], *W_qvk = cin[2], *b_qvk = cin[3],
              *W_kv = cin[4], *b_kv = cin[5], *W_q = cin[6], *b_q = cin[7],
              *W_ff1 = cin[8], *b_ff1 = cin[9], *W_ff2 = cin[10], *b_ff2 = cin[11],
              *ln1_g = cin[12], *ln1_b = cin[13], *ln2_g = cin[14], *ln2_b = cin[15],
              *ln3_g = cin[16], *ln3_b = cin[17];

  // 0b. weight transpose+split (once)
  wsplit_kernel<<<dim3(24, 8), blk, 0, stream>>>(W_qvk, B3_qvk, DIMc, 3 * DIMc);
  wsplit_kernel<<<dim3(16, 8), blk, 0, stream>>>(W_kv,  B3_kv,  DIMc, 2 * DIMc);
  wsplit_kernel<<<dim3(8, 8),  blk, 0, stream>>>(W_q,   B3_q,   DIMc, DIMc);
  wsplit_kernel<<<dim3(32, 8), blk, 0, stream>>>(W_ff1, B3_ff1, DIMc, FFc);
  wsplit_kernel<<<dim3(8, 32), blk, 0, stream>>>(W_ff2, B3_ff2, FFc,  DIMc);

  // 1. qvk = x @ W_qvk + b   (MFMA, 3-term split)
  split_act<<<dim3(1024), blk, 0, stream>>>(x, A3a, 9, (int)SZ_ROW);
  gemm_mfma<128, 128, 0, false, false><<<dim3(12, 32), blk, 0, stream>>>(
      A3a, B3_qvk, b_qvk, nullptr, qvk, nullptr, 3 * DIMc, 3 * DIMc);
  // 2. causal linear self-attention (A writes transposed KV; C is MFMA-based)
  causalA<<<dim3(NCc, Bc * Hc), blk, 0, stream>>>(qvk, chunkKV, chunkKs);
  causalB<<<dim3(Bc * Hc), blk, 0, stream>>>(chunkKV, chunkKs);
  causalC<<<dim3(NCc, Bc * Hc), blk, 0, stream>>>(qvk, chunkKV, chunkKs, attn_o);
  // 3. LN1(attn + x)
  ln_kernel<true, false><<<dim3(MR), blk, 0, stream>>>(
      attn_o, x, ln1_g, ln1_b, out1, flag);
  // 4. kv = memory @ W_kv + b (overwrites dead qvk) ; q2 = out1 @ W_q + b
  split_act<<<dim3(1024), blk, 0, stream>>>(memory, A3a, 9, (int)SZ_ROW);
  gemm_mfma<128, 128, 0, false, false><<<dim3(8, 32), blk, 0, stream>>>(
      A3a, B3_kv, b_kv, nullptr, kvbuf, nullptr, 2 * DIMc, 3 * DIMc);
  split_act<<<dim3(1024), blk, 0, stream>>>(out1, A3a, 9, (int)SZ_ROW);
  gemm_mfma<128, 64, 0, false, false><<<dim3(8, 32), blk, 0, stream>>>(
      A3a, B3_q, b_q, nullptr, q2, nullptr, DIMc, 3 * DIMc);
  // 5. cross linear attention (colsum fused into ctx_kernel; tiny normalize pass)
  hipMemsetAsync(colsum, 0,
      ((size_t)Bc * Hc * Ec + (size_t)Bc * Hc * Ec * Ec) * sizeof(float), stream);
  ctx_kernel<<<dim3(Mc / 64, Bc * Hc), blk, 0, stream>>>(kvbuf, colsum, ctx2);
  normctx<<<dim3(Bc * Hc), blk, 0, stream>>>(ctx2, colsum);
  attn2_kernel<<<dim3(Nc / 4, Bc * Hc), blk, 0, stream>>>(q2, ctx2, attn2_o);
  // 6. LN2(attn2 + out1) in-place
  ln_kernel<true, false><<<dim3(MR), blk, 0, stream>>>(
      attn2_o, out1, ln2_g, ln2_b, ybuf, flag);
  // 7. FF: ff1 writes split-A3 format directly (fused relu+split, overwrites dead kvbuf/q2)
  split_act<<<dim3(1024), blk, 0, stream>>>(ybuf, A3a, 9, (int)SZ_ROW);
  gemm_mfma<128, 128, 1, true, false><<<dim3(16, 32), blk, 0, stream>>>(
      A3a, B3_ff1, b_ff1, nullptr, nullptr, O3ff, FFc, 3 * DIMc);
  gemm_mfma<128, 64, 0, false, true><<<dim3(8, 32), blk, 0, stream>>>(
      O3ff, B3_ff2, b_ff2, ybuf, pre3, nullptr, DIMc, 3 * FFc);
  // 8. LN3 -> d_out (bf16 or fp32 per flag)
  ln_kernel<false, true><<<dim3(MR), blk, 0, stream>>>(
      pre3, nullptr, ln3_g, ln3_b, d_out, flag);
}

// Round 4
// 468.437 us; speedup vs baseline: 2.6659x; 1.3268x over previous
//
#include <hip/hip_runtime.h>
#include <hip/hip_bf16.h>

#define DEV __device__ __forceinline__

constexpr int Bc = 2, Nc = 2048, Mc = 2048, DIMc = 512, Hc = 8, FFc = 2048, Ec = 64;
constexpr int CT = 64;            // causal chunk length (tokens)
constexpr int NCc = Nc / CT;      // 32 chunks per sequence
constexpr float LN_EPS = 1e-5f, ATTN_EPS = 1e-6f;

typedef __bf16 bfrag8 __attribute__((ext_vector_type(8)));
typedef float ffrag4 __attribute__((ext_vector_type(4)));
typedef unsigned short u16;

// ---------------- helpers ----------------
DEV u16 f2bf(float v) {
  __hip_bfloat16 h = __float2bfloat16(v);   // RTN-even
  return __builtin_bit_cast(unsigned short, h);
}
DEV float bf2f(u16 u) { return __uint_as_float(((unsigned)u) << 16); }

DEV void gload16(const void* g, void* l) {
  __builtin_amdgcn_global_load_lds(
      (const __attribute__((address_space(1))) void*)g,
      (__attribute__((address_space(3))) void*)l, 16, 0, 0);
}

// XOR swizzle for [64][64] u16 LDS tiles (row stride 128B) in causalC.
DEV int SW(int r, int c) { return r * 64 + (c ^ ((r & 7) << 3)); }

// ---------------- dtype detection + ingest to canonical fp32 ----------------
__global__ __launch_bounds__(64) void detect_kernel(const void* x, int* flag) {
  const unsigned short* u = (const unsigned short*)x;
  int tid = threadIdx.x;
  int bad = 0;
#pragma unroll
  for (int i = 0; i < 8; ++i) {
    float v = __uint_as_float(((unsigned)u[tid * 8 + i]) << 16);
    if (!(fabsf(v) <= 1e4f)) bad = 1;   // catches NaN, Inf, garbage
  }
  unsigned long long m = __ballot(bad);
  if (tid == 0) *flag = (m == 0ull) ? 1 : 0;  // 1 = inputs are bf16
}

struct ConvJob { const void* src; float* dst; int n; };
struct ConvJobs { ConvJob j[18]; };

__global__ __launch_bounds__(256) void ingest_kernel(ConvJobs jobs, const int* flag) {
  int bf = *flag;
  ConvJob jb = jobs.j[blockIdx.y];
  int stride = gridDim.x * 256;
  for (int i = blockIdx.x * 256 + threadIdx.x; i < jb.n; i += stride) {
    float v;
    if (bf) v = __uint_as_float(((unsigned)((const unsigned short*)jb.src)[i]) << 16);
    else    v = ((const float*)jb.src)[i];
    jb.dst[i] = v;
  }
}

// ---------------- fp32 -> 2-term bf16 split (activations) ----------------
// out layout: row-major M x 2K bf16: [hi | lo]
__global__ __launch_bounds__(256) void split_act(const float* __restrict__ in,
    u16* __restrict__ out, int kshift, int total)
{
  const int K = 1 << kshift;
  int stride = gridDim.x * 256 * 4;
  for (int i = (blockIdx.x * 256 + threadIdx.x) * 4; i < total; i += stride) {
    float4 a = *(const float4*)&in[i];
    int row = i >> kshift;
    int k = i & (K - 1);
    u16 h[4], l[4];
    float v[4] = {a.x, a.y, a.z, a.w};
#pragma unroll
    for (int j = 0; j < 4; ++j) {
      h[j] = f2bf(v[j]);
      l[j] = f2bf(v[j] - bf2f(h[j]));
    }
    uint2 hv, lv;
    hv.x = (unsigned)h[0] | ((unsigned)h[1] << 16);
    hv.y = (unsigned)h[2] | ((unsigned)h[3] << 16);
    lv.x = (unsigned)l[0] | ((unsigned)l[1] << 16);
    lv.y = (unsigned)l[2] | ((unsigned)l[3] << 16);
    size_t rb = (size_t)row * 2 * K + k;
    *(uint2*)&out[rb]     = hv;
    *(uint2*)&out[rb + K] = lv;
  }
}

// ---------------- W (KxN fp32) -> B2t (N x 2K bf16) transpose+split ----------------
// B2t[n][k] = hi(W[k][n]); B2t[n][K+k] = lo(W[k][n]).
__global__ __launch_bounds__(256) void wsplit_kernel(const float* __restrict__ W,
    u16* __restrict__ B2t, int K, int N)
{
  __shared__ float T[64][65];
  int n0 = blockIdx.x * 64, k0 = blockIdx.y * 64;
  int tid = threadIdx.x;
#pragma unroll
  for (int j = 0; j < 16; ++j) {
    int idx = tid + 256 * j;
    int kl = idx >> 6, nl = idx & 63;
    T[kl][nl] = W[(size_t)(k0 + kl) * N + n0 + nl];
  }
  __syncthreads();
#pragma unroll
  for (int j = 0; j < 16; ++j) {
    int idx = tid + 256 * j;
    int nl = idx >> 6, kl = idx & 63;
    float v = T[kl][nl];
    u16 hi = f2bf(v);
    u16 lo = f2bf(v - bf2f(hi));
    size_t rb = (size_t)(n0 + nl) * 2 * K + k0 + kl;
    B2t[rb]     = hi;
    B2t[rb + K] = lo;
  }
}

// ---------------- MFMA GEMM: C[M,N] = A2[M,2K] @ B2t[N,2K]^T ----------------
// 2-term split operands [hi|lo]; per k-step issues Ah*Bh + Ah*Bl + Al*Bh.
// Bijective XCD swizzle: consecutive bx of one row-panel map to one XCD (L2 reuse).
// OUTMODE 0: fp32 C (+bias)(+res)(relu). OUTMODE 1: split [hi|lo] bf16 out (row 2N).
// OUTMODE 2: raw fp32 partial to Cf[bz*M*N + ...] (split-K; no bias/res/relu).
template<int BM, int BN, int SPLITK, int OUTMODE, bool RELU, bool ADD_RES>
__global__ __launch_bounds__(256) void gemm_mfma(
    const u16* __restrict__ A2, const u16* __restrict__ B2t,
    const float* __restrict__ bias, const float* __restrict__ res,
    float* __restrict__ Cf, u16* __restrict__ C2,
    int N, int K)
{
  constexpr int WM = BM / 2, WN = BN / 2, FM = WM / 16, FN = WN / 16;
  __shared__ u16 Ash[BM][32], Asl[BM][32];
  __shared__ u16 Bsh[BN][32], Bsl[BN][32];
  const int tid = threadIdx.x;
  const int lane = tid & 63, wid = tid >> 6;
  const int wr = wid >> 1, wc = wid & 1;
  // bijective XCD swizzle (nwg divisible by 8 at every call site)
  const int gx = gridDim.x, gy = gridDim.y;
  const int nwg = gx * gy * gridDim.z;
  const int flat = (blockIdx.z * gy + blockIdx.y) * gx + blockIdx.x;
  const int v = (flat & 7) * (nwg >> 3) + (flat >> 3);
  const int bx = v % gx;
  const int rest = v / gx;
  const int by = rest % gy;
  const int bz = rest / gy;
  const int row0 = by * BM, col0 = bx * BN;
  const int Mtot = gy * BM;
  const int sr = lane >> 2, sk = (lane & 3) * 8;     // staging coords (16B/lane)
  const int ar = lane & 15, kb = (lane >> 4) * 8;    // fragment coords
  const size_t strA = (size_t)2 * K;                 // row strides (elements)

  ffrag4 acc[FM][FN];
#pragma unroll
  for (int m = 0; m < FM; ++m)
#pragma unroll
    for (int n = 0; n < FN; ++n) acc[m][n] = ffrag4{0.f, 0.f, 0.f, 0.f};

  const int Kseg = K / SPLITK;
  const int kbeg = bz * Kseg;
  for (int k0 = kbeg; k0 < kbeg + Kseg; k0 += 32) {
    for (int r = wid; r < BM / 16; r += 4) {
      gload16(&A2[(size_t)(row0 + r * 16 + sr) * strA + k0 + sk],     &Ash[r * 16][0]);
      gload16(&A2[(size_t)(row0 + r * 16 + sr) * strA + K + k0 + sk], &Asl[r * 16][0]);
    }
    for (int r = wid; r < BN / 16; r += 4) {
      gload16(&B2t[(size_t)(col0 + r * 16 + sr) * strA + k0 + sk],     &Bsh[r * 16][0]);
      gload16(&B2t[(size_t)(col0 + r * 16 + sr) * strA + K + k0 + sk], &Bsl[r * 16][0]);
    }
    __syncthreads();   // drains vmcnt(0): LDS tiles ready

    bfrag8 afh[FM], afl[FM], bwh[FN], bwl[FN];
#pragma unroll
    for (int m = 0; m < FM; ++m) {
      afh[m] = *(const bfrag8*)&Ash[wr * WM + m * 16 + ar][kb];
      afl[m] = *(const bfrag8*)&Asl[wr * WM + m * 16 + ar][kb];
    }
#pragma unroll
    for (int n = 0; n < FN; ++n) {
      bwh[n] = *(const bfrag8*)&Bsh[wc * WN + n * 16 + ar][kb];
      bwl[n] = *(const bfrag8*)&Bsl[wc * WN + n * 16 + ar][kb];
    }
#pragma unroll
    for (int m = 0; m < FM; ++m)
#pragma unroll
      for (int n = 0; n < FN; ++n) {
        acc[m][n] = __builtin_amdgcn_mfma_f32_16x16x32_bf16(afh[m], bwh[n], acc[m][n], 0, 0, 0);
        acc[m][n] = __builtin_amdgcn_mfma_f32_16x16x32_bf16(afh[m], bwl[n], acc[m][n], 0, 0, 0);
        acc[m][n] = __builtin_amdgcn_mfma_f32_16x16x32_bf16(afl[m], bwh[n], acc[m][n], 0, 0, 0);
      }
    __syncthreads();   // protect tiles before next-iteration overwrite
  }

  // epilogue: D[row][col], col = lane&15, row = (lane>>4)*4 + u  [m89-verified]
#pragma unroll
  for (int m = 0; m < FM; ++m) {
    int rbase = row0 + wr * WM + m * 16 + (lane >> 4) * 4;
#pragma unroll
    for (int n = 0; n < FN; ++n) {
      int col = col0 + wc * WN + n * 16 + ar;
#pragma unroll
      for (int u = 0; u < 4; ++u) {
        int row = rbase + u;
        float val = acc[m][n][u];
        if constexpr (OUTMODE == 2) {
          Cf[((size_t)bz * Mtot + row) * N + col] = val;
        } else {
          val += bias[col];
          if (ADD_RES) val += res[(size_t)row * N + col];
          if (RELU) val = fmaxf(val, 0.f);
          if constexpr (OUTMODE == 0) {
            Cf[(size_t)row * N + col] = val;
          } else {
            u16 hi = f2bf(val);
            u16 lo = f2bf(val - bf2f(hi));
            size_t rb = (size_t)row * 2 * N;
            C2[rb + col]     = hi;
            C2[rb + N + col] = lo;
          }
        }
      }
    }
  }
}

// ---------------- split-K reduce for ff2: out = part0+part1 + bias + res ----------
__global__ __launch_bounds__(256) void reduce2(const float* __restrict__ part,
    const float* __restrict__ bias, const float* __restrict__ res,
    float* __restrict__ out)
{
  size_t i = ((size_t)blockIdx.x * 256 + threadIdx.x) * 4;
  float4 a = *(const float4*)&part[i];
  float4 b = *(const float4*)&part[(size_t)2097152 + i];   // 4096*512
  float4 r = *(const float4*)&res[i];
  int col = (int)(i & 511);
  float4 o;
  o.x = a.x + b.x + r.x + bias[col];
  o.y = a.y + b.y + r.y + bias[col + 1];
  o.z = a.z + b.z + r.z + bias[col + 2];
  o.w = a.w + b.w + r.w + bias[col + 3];
  *(float4*)&out[i] = o;
}

// ---------------- layernorm over last dim (512), optional residual ----------------
template<bool HAS_RES, bool FINAL>
__global__ __launch_bounds__(256) void ln_kernel(
    const float* __restrict__ in, const float* __restrict__ res,
    const float* __restrict__ g, const float* __restrict__ b,
    void* __restrict__ out, const int* __restrict__ flag)
{
  int row = blockIdx.x, tid = threadIdx.x;
  size_t base = (size_t)row * DIMc;
  float x0 = in[base + tid], x1 = in[base + tid + 256];
  if (HAS_RES) { x0 += res[base + tid]; x1 += res[base + tid + 256]; }
  float s1 = x0 + x1, s2 = x0 * x0 + x1 * x1;
#pragma unroll
  for (int off = 1; off < 64; off <<= 1) { s1 += __shfl_xor(s1, off); s2 += __shfl_xor(s2, off); }
  __shared__ float p1[4], p2[4], stat[2];
  if ((tid & 63) == 0) { p1[tid >> 6] = s1; p2[tid >> 6] = s2; }
  __syncthreads();
  if (tid == 0) {
    float t1 = p1[0] + p1[1] + p1[2] + p1[3];
    float t2 = p2[0] + p2[1] + p2[2] + p2[3];
    float mu = t1 / DIMc;
    float var = t2 / DIMc - mu * mu;
    stat[0] = mu; stat[1] = rsqrtf(var + LN_EPS);
  }
  __syncthreads();
  float mu = stat[0], rv = stat[1];
  float y0 = (x0 - mu) * rv * g[tid] + b[tid];
  float y1 = (x1 - mu) * rv * g[tid + 256] + b[tid + 256];
  if (FINAL) {
    if (*flag) {
      __hip_bfloat16* o = (__hip_bfloat16*)out;
      o[base + tid] = __float2bfloat16(y0);
      o[base + tid + 256] = __float2bfloat16(y1);
    } else {
      float* o = (float*)out;
      o[base + tid] = y0;
      o[base + tid + 256] = y1;
    }
  } else {
    float* o = (float*)out;
    o[base + tid] = y0;
    o[base + tid + 256] = y1;
  }
}

// ---------------- causal linear attention, pass A: per-chunk KV sums ----------------
// Writes chunkKV TRANSPOSED: chunkKVT[e][d] = sum_t ks[t][d]*vs[t][e]
__global__ __launch_bounds__(256) void causalA(const float* __restrict__ qvk,
    float* __restrict__ chunkKVT, float* __restrict__ chunkKs)
{
  int c = blockIdx.x, bh = blockIdx.y;
  int b = bh >> 3, h = bh & 7;
  __shared__ float ks[CT][Ec];
  __shared__ float vs[CT][Ec];
  int tid = threadIdx.x;
#pragma unroll
  for (int j = 0; j < 16; ++j) {
    int i = tid + 256 * j;
    int t = i >> 6, d = i & 63;
    size_t rowbase = ((size_t)b * Nc + c * CT + t) * (3 * DIMc);
    ks[t][d] = __expf(qvk[rowbase + 2 * DIMc + h * Ec + d]);
    vs[t][d] = qvk[rowbase + DIMc + h * Ec + d];
  }
  __syncthreads();
  int e = tid & 63, d0 = tid >> 6;
  float acc[16] = {};
  for (int t = 0; t < CT; ++t) {
    float ve = vs[t][e];
#pragma unroll
    for (int j = 0; j < 16; ++j) acc[j] += ks[t][d0 + 4 * j] * ve;
  }
  size_t obase = ((size_t)bh * NCc + c) * (Ec * Ec);
#pragma unroll
  for (int j = 0; j < 16; ++j) chunkKVT[obase + (size_t)e * Ec + (d0 + 4 * j)] = acc[j];
  if (tid < Ec) {
    float s = 0;
    for (int t = 0; t < CT; ++t) s += ks[t][tid];
    chunkKs[((size_t)bh * NCc + c) * Ec + tid] = s;
  }
}

// ---------------- pass B: in-place exclusive prefix over chunks (layout-agnostic) ----
__global__ __launch_bounds__(256) void causalB(float* __restrict__ chunkKV,
                                               float* __restrict__ chunkKs)
{
  int bh = blockIdx.x, tid = threadIdx.x;
  for (int idx = tid; idx < Ec * Ec; idx += 256) {
    float run = 0;
    size_t base = (size_t)bh * NCc * Ec * Ec + idx;
    for (int c = 0; c < NCc; ++c) {
      float t = chunkKV[base + (size_t)c * Ec * Ec];
      chunkKV[base + (size_t)c * Ec * Ec] = run;
      run += t;
    }
  }
  if (tid < Ec) {
    float run = 0;
    size_t base = (size_t)bh * NCc * Ec + tid;
    for (int c = 0; c < NCc; ++c) {
      float t = chunkKs[base + (size_t)c * Ec];
      chunkKs[base + (size_t)c * Ec] = run;
      run += t;
    }
  }
}

// ---------------- pass C: per-token outputs via MFMA ----------------
__global__ __launch_bounds__(256) void causalC(const float* __restrict__ qvk,
    const float* __restrict__ chunkKVT, const float* __restrict__ chunkKs,
    float* __restrict__ attn_out)
{
  int c = blockIdx.x, bh = blockIdx.y;
  int b = bh >> 3, h = bh & 7;
  __shared__ u16 qsh[64 * 64], qsl[64 * 64];   // A: qs[t][d]
  __shared__ u16 ksPh[64 * 64], ksPl[64 * 64]; // B: ks[tau][d]  ->  A: Pm[t][tau]
  __shared__ u16 STh[64 * 64], STl[64 * 64];   // B: S^T[e][d]
  __shared__ u16 VTh[64 * 72], VTl[64 * 72];   // B: V^T[e][tau], pad 72
  __shared__ float kpre[Ec], r0[CT], dinv[CT];
  int tid = threadIdx.x;
  int lane = tid & 63, w = tid >> 6;
  const int ar = lane & 15, kb = (lane >> 4) * 8;
  size_t kvb = (size_t)bh * NCc + c;

  if (tid < Ec) kpre[tid] = chunkKs[kvb * Ec + tid] + ATTN_EPS;

  float qreg[16];
#pragma unroll
  for (int j = 0; j < 16; ++j) {
    int t = w * 16 + j, d = lane;
    size_t rowbase = ((size_t)b * Nc + c * CT + t) * (3 * DIMc);
    qreg[j] = qvk[rowbase + h * Ec + d];
    float kv = __expf(qvk[rowbase + 2 * DIMc + h * Ec + d]);
    u16 hi = f2bf(kv);
    ksPh[SW(t, d)] = hi; ksPl[SW(t, d)] = f2bf(kv - bf2f(hi));
    float vv = qvk[rowbase + DIMc + h * Ec + d];
    hi = f2bf(vv);
    VTh[d * 72 + t] = hi; VTl[d * 72 + t] = f2bf(vv - bf2f(hi));
    float sv = chunkKVT[kvb * (Ec * Ec) + (size_t)t * Ec + d];  // row e=t of S^T
    hi = f2bf(sv);
    STh[SW(t, d)] = hi; STl[SW(t, d)] = f2bf(sv - bf2f(hi));
  }
  __syncthreads();

  for (int ti = 0; ti < 16; ++ti) {
    int t = w * 16 + ti;
    float qv = qreg[ti];
    float mx = qv;
#pragma unroll
    for (int off = 1; off < 64; off <<= 1) mx = fmaxf(mx, __shfl_xor(mx, off));
    float ex = __expf(qv - mx);
    float ssum = ex;
#pragma unroll
    for (int off = 1; off < 64; off <<= 1) ssum += __shfl_xor(ssum, off);
    float qs = ex / ssum * 0.125f;
    float qk = qs * kpre[lane];
#pragma unroll
    for (int off = 1; off < 64; off <<= 1) qk += __shfl_xor(qk, off);
    if (lane == 0) r0[t] = qk;
    u16 hi = f2bf(qs);
    qsh[SW(t, lane)] = hi; qsl[SW(t, lane)] = f2bf(qs - bf2f(hi));
  }
  __syncthreads();

  ffrag4 pacc[4];
#pragma unroll
  for (int ct = 0; ct < 4; ++ct) pacc[ct] = ffrag4{0.f, 0.f, 0.f, 0.f};
#pragma unroll
  for (int ct = 0; ct < 4; ++ct)
#pragma unroll
    for (int k2 = 0; k2 < 64; k2 += 32) {
      bfrag8 ah = *(const bfrag8*)&qsh[SW(w * 16 + ar, k2 + kb)];
      bfrag8 al = *(const bfrag8*)&qsl[SW(w * 16 + ar, k2 + kb)];
      bfrag8 bh_ = *(const bfrag8*)&ksPh[SW(ct * 16 + ar, k2 + kb)];
      bfrag8 bl_ = *(const bfrag8*)&ksPl[SW(ct * 16 + ar, k2 + kb)];
      pacc[ct] = __builtin_amdgcn_mfma_f32_16x16x32_bf16(ah, bh_, pacc[ct], 0, 0, 0);
      pacc[ct] = __builtin_amdgcn_mfma_f32_16x16x32_bf16(ah, bl_, pacc[ct], 0, 0, 0);
      pacc[ct] = __builtin_amdgcn_mfma_f32_16x16x32_bf16(al, bh_, pacc[ct], 0, 0, 0);
    }
  __syncthreads();

  float rs[4] = {0.f, 0.f, 0.f, 0.f};
#pragma unroll
  for (int ct = 0; ct < 4; ++ct) {
    int tau = ct * 16 + ar;
#pragma unroll
    for (int u = 0; u < 4; ++u) {
      int t = w * 16 + (lane >> 4) * 4 + u;
      float pv = (tau <= t) ? pacc[ct][u] : 0.f;
      rs[u] += pv;
      u16 hi = f2bf(pv);
      ksPh[SW(t, tau)] = hi; ksPl[SW(t, tau)] = f2bf(pv - bf2f(hi));
    }
  }
#pragma unroll
  for (int u = 0; u < 4; ++u) {
    float vv = rs[u];
    vv += __shfl_xor(vv, 1); vv += __shfl_xor(vv, 2);
    vv += __shfl_xor(vv, 4); vv += __shfl_xor(vv, 8);
    if (ar == 0) {
      int t = w * 16 + (lane >> 4) * 4 + u;
      dinv[t] = 1.f / (r0[t] + vv);
    }
  }
  __syncthreads();

#pragma unroll
  for (int et = 0; et < 4; ++et) {
    ffrag4 oacc = ffrag4{0.f, 0.f, 0.f, 0.f};
#pragma unroll
    for (int k2 = 0; k2 < 64; k2 += 32) {
      bfrag8 ah = *(const bfrag8*)&qsh[SW(w * 16 + ar, k2 + kb)];
      bfrag8 al = *(const bfrag8*)&qsl[SW(w * 16 + ar, k2 + kb)];
      bfrag8 bh_ = *(const bfrag8*)&STh[SW(et * 16 + ar, k2 + kb)];
      bfrag8 bl_ = *(const bfrag8*)&STl[SW(et * 16 + ar, k2 + kb)];
      oacc = __builtin_amdgcn_mfma_f32_16x16x32_bf16(ah, bh_, oacc, 0, 0, 0);
      oacc = __builtin_amdgcn_mfma_f32_16x16x32_bf16(ah, bl_, oacc, 0, 0, 0);
      oacc = __builtin_amdgcn_mfma_f32_16x16x32_bf16(al, bh_, oacc, 0, 0, 0);
      bfrag8 ph = *(const bfrag8*)&ksPh[SW(w * 16 + ar, k2 + kb)];
      bfrag8 pl = *(const bfrag8*)&ksPl[SW(w * 16 + ar, k2 + kb)];
      bfrag8 vh = *(const bfrag8*)&VTh[(et * 16 + ar) * 72 + k2 + kb];
      bfrag8 vl = *(const bfrag8*)&VTl[(et * 16 + ar) * 72 + k2 + kb];
      oacc = __builtin_amdgcn_mfma_f32_16x16x32_bf16(ph, vh, oacc, 0, 0, 0);
      oacc = __builtin_amdgcn_mfma_f32_16x16x32_bf16(ph, vl, oacc, 0, 0, 0);
      oacc = __builtin_amdgcn_mfma_f32_16x16x32_bf16(pl, vh, oacc, 0, 0, 0);
    }
    int e = et * 16 + ar;
#pragma unroll
    for (int u = 0; u < 4; ++u) {
      int t = w * 16 + (lane >> 4) * 4 + u;
      attn_out[((size_t)b * Nc + c * CT + t) * DIMc + h * Ec + e] = oacc[u] * dinv[t];
    }
  }
}

// ---------------- cross-attn: ctxU[d,e] = sum_m exp(k2)[m,d] * v2[m,e]  (+colsum) ----
__global__ __launch_bounds__(256) void ctx_kernel(const float* __restrict__ kvbuf,
    float* __restrict__ colsum, float* __restrict__ ctx)
{
  int slab = blockIdx.x, bh = blockIdx.y;
  int b = bh >> 3, h = bh & 7;
  __shared__ float ks[64][Ec];
  __shared__ float vs[64][Ec];
  int tid = threadIdx.x;
#pragma unroll
  for (int j = 0; j < 16; ++j) {
    int i = tid + 256 * j;
    int m = i >> 6, d = i & 63;
    size_t rowbase = ((size_t)b * Mc + slab * 64 + m) * (2 * DIMc);
    ks[m][d] = __expf(kvbuf[rowbase + h * Ec + d]);
    vs[m][d] = kvbuf[rowbase + DIMc + h * Ec + d];
  }
  __syncthreads();
  int e = tid & 63, d0 = tid >> 6;
  float acc[16] = {};
  for (int m = 0; m < 64; ++m) {
    float ve = vs[m][e];
#pragma unroll
    for (int j = 0; j < 16; ++j) acc[j] += ks[m][d0 + 4 * j] * ve;
  }
  size_t obase = (size_t)bh * Ec * Ec;
#pragma unroll
  for (int j = 0; j < 16; ++j) atomicAdd(&ctx[obase + (size_t)(d0 + 4 * j) * Ec + e], acc[j]);
  int w = tid >> 6, lane = tid & 63;
  float s = 0;
#pragma unroll
  for (int m = 0; m < 16; ++m) s += ks[w * 16 + m][lane];
  __shared__ float p[4][Ec];
  p[w][lane] = s;
  __syncthreads();
  if (tid < Ec)
    atomicAdd(&colsum[(size_t)bh * Ec + tid], p[0][tid] + p[1][tid] + p[2][tid] + p[3][tid]);
}

// ---------------- normalize ctx rows by colsum (tiny) ----------------
__global__ __launch_bounds__(256) void normctx(float* __restrict__ ctx,
                                               const float* __restrict__ colsum)
{
  int bh = blockIdx.x, tid = threadIdx.x;
#pragma unroll
  for (int j = 0; j < 16; ++j) {
    int i = tid + 256 * j;
    int d = i >> 6;
    ctx[(size_t)bh * Ec * Ec + i] /= colsum[(size_t)bh * Ec + d];
  }
}

// ---------------- cross-attn: out[t,e] = softmax(q2[t])*E^-.5 @ ctx ----------------
__global__ __launch_bounds__(256) void attn2_kernel(const float* __restrict__ q2,
    const float* __restrict__ ctx, float* __restrict__ out)
{
  int bh = blockIdx.y;
  int b = bh >> 3, h = bh & 7;
  __shared__ float cs[Ec][Ec];
  int tid = threadIdx.x;
#pragma unroll
  for (int j = 0; j < 16; ++j) {
    int i = tid + 256 * j;
    cs[i >> 6][i & 63] = ctx[(size_t)bh * Ec * Ec + i];
  }
  __syncthreads();
  int w = tid >> 6, lane = tid & 63;
  int t = blockIdx.x * 4 + w;
  float qv = q2[((size_t)b * Nc + t) * DIMc + h * Ec + lane];
  float mx = qv;
#pragma unroll
  for (int off = 1; off < 64; off <<= 1) mx = fmaxf(mx, __shfl_xor(mx, off));
  float ex = __expf(qv - mx);
  float ssum = ex;
#pragma unroll
  for (int off = 1; off < 64; off <<= 1) ssum += __shfl_xor(ssum, off);
  float qs = ex / ssum * 0.125f;
  float acc = 0;
  for (int d = 0; d < Ec; ++d) acc += __shfl(qs, d) * cs[d][lane];
  out[((size_t)b * Nc + t) * DIMc + h * Ec + lane] = acc;
}

extern "C" void kernel_launch(void* const* d_in, const int* in_sizes, int n_in,
                              void* d_out, int out_size, void* d_ws, size_t ws_size,
                              hipStream_t stream)
{
  float* ws = (float*)d_ws;
  int* flag = (int*)ws;
  float* conv = ws + 64;

  float* cin[18];
  size_t off = 0;
  for (int i = 0; i < 18; ++i) { cin[i] = conv + off; off += (size_t)in_sizes[i]; }
  float* pipe = conv + off;

  const size_t SZ_ROW = (size_t)Bc * Nc * DIMc;            // 2,097,152
  const size_t SZ_KV  = (size_t)Bc * Mc * 2 * DIMc;        // 4,194,304
  const size_t SZ_R0  = 12582912;                          // region0 span (f-eq)

  float* region0 = pipe;
  float* qvk     = region0;                   // live: gemm1 .. causalC
  float* kvbuf   = region0;                   // live: kvGEMM .. ctx_kernel
  float* q2      = region0 + SZ_KV;           // live: q2GEMM .. attn2
  u16*   O2ff    = (u16*)region0;             // live: ff1 .. ff2 ([hi|lo], 8.39M f-eq)
  float* partials= region0 + 8388608;         // ff2 split-K partials (2 x 2.10M f)
  float* out1    = region0 + SZ_R0;           // live: LN1 .. LN2
  float* attn_o  = out1 + SZ_ROW;             // attn_o -> attn2_o -> ybuf
  float* r3      = attn_o + SZ_ROW;           // chunkKV -> pre3
  float* chunkKV = r3;
  float* pre3    = r3;
  float* chunkKs = r3 + SZ_ROW;                                   // 32768
  float* colsum  = chunkKs + (size_t)Bc * Hc * NCc * Ec;          // 1024
  float* ctx2    = colsum + (size_t)Bc * Hc * Ec;                 // 65536
  float* ybuf    = attn_o;
  float* attn2_o = attn_o;

  u16* B2_qvk = (u16*)(ctx2 + (size_t)Bc * Hc * Ec * Ec);
  u16* B2_kv  = B2_qvk + (size_t)(3 * DIMc) * (2 * DIMc);   // 1536 x 1024
  u16* B2_q   = B2_kv  + (size_t)(2 * DIMc) * (2 * DIMc);   // 1024 x 1024
  u16* B2_ff1 = B2_q   + (size_t)DIMc * (2 * DIMc);         // 512 x 1024
  u16* B2_ff2 = B2_ff1 + (size_t)FFc  * (2 * DIMc);         // 2048 x 1024
  u16* A2a    = B2_ff2 + (size_t)DIMc * (2 * FFc);          // 512 x 4096 -> then A2a 4096x1024
  (void)ws_size; (void)n_in; (void)out_size;

  dim3 blk(256);
  const int MR = Bc * Nc;  // 4096 rows

  // 0. detect input dtype, convert everything to fp32
  detect_kernel<<<dim3(1), dim3(64), 0, stream>>>(d_in[0], flag);
  ConvJobs jobs;
  for (int i = 0; i < 18; ++i) { jobs.j[i].src = d_in[i]; jobs.j[i].dst = cin[i]; jobs.j[i].n = in_sizes[i]; }
  ingest_kernel<<<dim3(64, 18), blk, 0, stream>>>(jobs, flag);

  const float *x = cin[0], *memory = cin[1], *W_qvk = cin[2], *b_qvk = cin[3],
              *W_kv = cin[4], *b_kv = cin[5], *W_q = cin[6], *b_q = cin[7],
              *W_ff1 = cin[8], *b_ff1 = cin[9], *W_ff2 = cin[10], *b_ff2 = cin[11],
              *ln1_g = cin[12], *ln1_b = cin[13], *ln2_g = cin[14], *ln2_b = cin[15],
              *ln3_g = cin[16], *ln3_b = cin[17];

  // 0b. weight transpose+split (once)
  wsplit_kernel<<<dim3(24, 8), blk, 0, stream>>>(W_qvk, B2_qvk, DIMc, 3 * DIMc);
  wsplit_kernel<<<dim3(16, 8), blk, 0, stream>>>(W_kv,  B2_kv,  DIMc, 2 * DIMc);
  wsplit_kernel<<<dim3(8, 8),  blk, 0, stream>>>(W_q,   B2_q,   DIMc, DIMc);
  wsplit_kernel<<<dim3(32, 8), blk, 0, stream>>>(W_ff1, B2_ff1, DIMc, FFc);
  wsplit_kernel<<<dim3(8, 32), blk, 0, stream>>>(W_ff2, B2_ff2, FFc,  DIMc);

  // 1. qvk = x @ W_qvk + b   (MFMA, 2-term split operands, 3-product accumulate)
  split_act<<<dim3(1024), blk, 0, stream>>>(x, A2a, 9, (int)SZ_ROW);
  gemm_mfma<128, 128, 1, 0, false, false><<<dim3(12, 32), blk, 0, stream>>>(
      A2a, B2_qvk, b_qvk, nullptr, qvk, nullptr, 3 * DIMc, DIMc);
  // 2. causal linear self-attention
  causalA<<<dim3(NCc, Bc * Hc), blk, 0, stream>>>(qvk, chunkKV, chunkKs);
  causalB<<<dim3(Bc * Hc), blk, 0, stream>>>(chunkKV, chunkKs);
  causalC<<<dim3(NCc, Bc * Hc), blk, 0, stream>>>(qvk, chunkKV, chunkKs, attn_o);
  // 3. LN1(attn + x)
  ln_kernel<true, false><<<dim3(MR), blk, 0, stream>>>(
      attn_o, x, ln1_g, ln1_b, out1, flag);
  // 4. kv = memory @ W_kv + b (overwrites dead qvk) ; q2 = out1 @ W_q + b
  split_act<<<dim3(1024), blk, 0, stream>>>(memory, A2a, 9, (int)SZ_ROW);
  gemm_mfma<128, 128, 1, 0, false, false><<<dim3(8, 32), blk, 0, stream>>>(
      A2a, B2_kv, b_kv, nullptr, kvbuf, nullptr, 2 * DIMc, DIMc);
  split_act<<<dim3(1024), blk, 0, stream>>>(out1, A2a, 9, (int)SZ_ROW);
  gemm_mfma<128, 64, 1, 0, false, false><<<dim3(8, 32), blk, 0, stream>>>(
      A2a, B2_q, b_q, nullptr, q2, nullptr, DIMc, DIMc);
  // 5. cross linear attention
  hipMemsetAsync(colsum, 0,
      ((size_t)Bc * Hc * Ec + (size_t)Bc * Hc * Ec * Ec) * sizeof(float), stream);
  ctx_kernel<<<dim3(Mc / 64, Bc * Hc), blk, 0, stream>>>(kvbuf, colsum, ctx2);
  normctx<<<dim3(Bc * Hc), blk, 0, stream>>>(ctx2, colsum);
  attn2_kernel<<<dim3(Nc / 4, Bc * Hc), blk, 0, stream>>>(q2, ctx2, attn2_o);
  // 6. LN2(attn2 + out1) in-place
  ln_kernel<true, false><<<dim3(MR), blk, 0, stream>>>(
      attn2_o, out1, ln2_g, ln2_b, ybuf, flag);
  // 7. FF: ff1 writes [hi|lo] split directly; ff2 split-K=2 + reduce(bias+res)
  split_act<<<dim3(1024), blk, 0, stream>>>(ybuf, A2a, 9, (int)SZ_ROW);
  gemm_mfma<128, 128, 1, 1, true, false><<<dim3(16, 32), blk, 0, stream>>>(
      A2a, B2_ff1, b_ff1, nullptr, nullptr, O2ff, FFc, DIMc);
  gemm_mfma<128, 64, 2, 2, false, false><<<dim3(8, 32, 2), blk, 0, stream>>>(
      O2ff, B2_ff2, b_ff2, nullptr, partials, nullptr, DIMc, FFc);
  reduce2<<<dim3(2048), blk, 0, stream>>>(partials, b_ff2, ybuf, pre3);
  // 8. LN3 -> d_out (bf16 or fp32 per flag)
  ln_kernel<false, true><<<dim3(MR), blk, 0, stream>>>(
      pre3, nullptr, ln3_g, ln3_b, d_out, flag);
}

// Round 5
// 431.213 us; speedup vs baseline: 2.8961x; 1.0863x over previous
//
#include <hip/hip_runtime.h>
#include <hip/hip_bf16.h>

#define DEV __device__ __forceinline__

constexpr int Bc = 2, Nc = 2048, Mc = 2048, DIMc = 512, Hc = 8, FFc = 2048, Ec = 64;
constexpr int CT = 64;            // causal chunk length (tokens)
constexpr int NCc = Nc / CT;      // 32 chunks per sequence
constexpr float LN_EPS = 1e-5f, ATTN_EPS = 1e-6f;

typedef __bf16 bfrag8 __attribute__((ext_vector_type(8)));
typedef float ffrag4 __attribute__((ext_vector_type(4)));
typedef unsigned short u16;

// ---------------- helpers ----------------
DEV u16 f2bf(float v) {
  __hip_bfloat16 h = __float2bfloat16(v);   // RTN-even
  return __builtin_bit_cast(unsigned short, h);
}
DEV float bf2f(u16 u) { return __uint_as_float(((unsigned)u) << 16); }

DEV void gload16(const void* g, void* l) {
  __builtin_amdgcn_global_load_lds(
      (const __attribute__((address_space(1))) void*)g,
      (__attribute__((address_space(3))) void*)l, 16, 0, 0);
}

// XOR swizzle for [64][64] u16 LDS tiles (row stride 128B) in causalC.
DEV int SW(int r, int c) { return r * 64 + (c ^ ((r & 7) << 3)); }

// ---------------- dtype detection ----------------
__global__ __launch_bounds__(64) void detect_kernel(const void* x, int* flag) {
  const unsigned short* u = (const unsigned short*)x;
  int tid = threadIdx.x;
  int bad = 0;
#pragma unroll
  for (int i = 0; i < 8; ++i) {
    float v = __uint_as_float(((unsigned)u[tid * 8 + i]) << 16);
    if (!(fabsf(v) <= 1e4f)) bad = 1;   // catches NaN, Inf, garbage
  }
  unsigned long long m = __ballot(bad);
  if (tid == 0) *flag = (m == 0ull) ? 1 : 0;  // 1 = inputs are bf16
}

// ---------------- ingest (vectorized, only for arrays needed in fp32) ----------------
struct ConvJob { const void* src; float* dst; int n; };
struct ConvJobs { ConvJob j[18]; };

__global__ __launch_bounds__(256) void ingest_kernel(ConvJobs jobs, const int* flag) {
  int bf = *flag;
  ConvJob jb = jobs.j[blockIdx.y];
  int n8 = jb.n >> 3;
  int stride = gridDim.x * 256;
  for (int i = blockIdx.x * 256 + threadIdx.x; i < n8; i += stride) {
    float o[8];
    if (bf) {
      uint4 a = ((const uint4*)jb.src)[i];
      unsigned w[4] = {a.x, a.y, a.z, a.w};
#pragma unroll
      for (int j = 0; j < 4; ++j) {
        o[2 * j]     = bf2f((u16)(w[j] & 0xffff));
        o[2 * j + 1] = bf2f((u16)(w[j] >> 16));
      }
    } else {
      float4 a = ((const float4*)jb.src)[2 * i];
      float4 b = ((const float4*)jb.src)[2 * i + 1];
      o[0] = a.x; o[1] = a.y; o[2] = a.z; o[3] = a.w;
      o[4] = b.x; o[5] = b.y; o[6] = b.z; o[7] = b.w;
    }
    float4* d = (float4*)jb.dst;
    d[2 * i]     = float4{o[0], o[1], o[2], o[3]};
    d[2 * i + 1] = float4{o[4], o[5], o[6], o[7]};
  }
}

// ---------------- raw input -> 2-term bf16 split [hi|lo] (dtype-aware) ----------------
__global__ __launch_bounds__(256) void split_act_raw(const void* __restrict__ in,
    const int* __restrict__ flag, u16* __restrict__ out, int kshift, int total)
{
  int bf = *flag;
  const int K = 1 << kshift;
  int n8 = total >> 3;
  int stride = gridDim.x * 256;
  for (int ii = blockIdx.x * 256 + threadIdx.x; ii < n8; ii += stride) {
    int i = ii * 8;
    float v[8];
    if (bf) {
      uint4 a = ((const uint4*)in)[ii];
      unsigned w[4] = {a.x, a.y, a.z, a.w};
#pragma unroll
      for (int j = 0; j < 4; ++j) {
        v[2 * j]     = bf2f((u16)(w[j] & 0xffff));
        v[2 * j + 1] = bf2f((u16)(w[j] >> 16));
      }
    } else {
      float4 a = ((const float4*)in)[2 * ii];
      float4 b = ((const float4*)in)[2 * ii + 1];
      v[0] = a.x; v[1] = a.y; v[2] = a.z; v[3] = a.w;
      v[4] = b.x; v[5] = b.y; v[6] = b.z; v[7] = b.w;
    }
    unsigned hw[4], lw[4];
#pragma unroll
    for (int j = 0; j < 4; ++j) {
      u16 h0 = f2bf(v[2 * j]),     l0 = f2bf(v[2 * j]     - bf2f(f2bf(v[2 * j])));
      u16 h1 = f2bf(v[2 * j + 1]), l1 = f2bf(v[2 * j + 1] - bf2f(f2bf(v[2 * j + 1])));
      hw[j] = (unsigned)h0 | ((unsigned)h1 << 16);
      lw[j] = (unsigned)l0 | ((unsigned)l1 << 16);
    }
    int row = i >> kshift, k = i & (K - 1);
    size_t rb = (size_t)row * 2 * K + k;
    *(uint4*)&out[rb]     = uint4{hw[0], hw[1], hw[2], hw[3]};
    *(uint4*)&out[rb + K] = uint4{lw[0], lw[1], lw[2], lw[3]};
  }
}

// ---------------- W (KxN, raw dtype) -> B2t (N x 2K bf16) transpose+split ----------------
__global__ __launch_bounds__(256) void wsplit_kernel(const void* __restrict__ W,
    const int* __restrict__ flag, u16* __restrict__ B2t, int K, int N)
{
  int bf = *flag;
  __shared__ float T[64][65];
  int n0 = blockIdx.x * 64, k0 = blockIdx.y * 64;
  int tid = threadIdx.x;
#pragma unroll
  for (int j = 0; j < 16; ++j) {
    int idx = tid + 256 * j;
    int kl = idx >> 6, nl = idx & 63;
    size_t gi = (size_t)(k0 + kl) * N + n0 + nl;
    T[kl][nl] = bf ? bf2f(((const u16*)W)[gi]) : ((const float*)W)[gi];
  }
  __syncthreads();
#pragma unroll
  for (int j = 0; j < 16; ++j) {
    int idx = tid + 256 * j;
    int nl = idx >> 6, kl = idx & 63;
    float v = T[kl][nl];
    u16 hi = f2bf(v);
    u16 lo = f2bf(v - bf2f(hi));
    size_t rb = (size_t)(n0 + nl) * 2 * K + k0 + kl;
    B2t[rb]     = hi;
    B2t[rb + K] = lo;
  }
}

// ---------------- MFMA GEMM: C[M,N] = A2[M,2K] @ B2t[N,2K]^T ----------------
// 2-term split operands [hi|lo]; per k-step issues Ah*Bh + Ah*Bl + Al*Bh.
// Bijective XCD swizzle. OUTMODE 0: fp32 C (+bias)(+res)(relu). OUTMODE 1: split
// [hi|lo] bf16 out (row 2N). OUTMODE 2: raw fp32 partial (split-K).
template<int BM, int BN, int SPLITK, int OUTMODE, bool RELU, bool ADD_RES>
__global__ __launch_bounds__(256) void gemm_mfma(
    const u16* __restrict__ A2, const u16* __restrict__ B2t,
    const float* __restrict__ bias, const float* __restrict__ res,
    float* __restrict__ Cf, u16* __restrict__ C2,
    int N, int K)
{
  constexpr int WM = BM / 2, WN = BN / 2, FM = WM / 16, FN = WN / 16;
  __shared__ u16 Ash[BM][32], Asl[BM][32];
  __shared__ u16 Bsh[BN][32], Bsl[BN][32];
  const int tid = threadIdx.x;
  const int lane = tid & 63, wid = tid >> 6;
  const int wr = wid >> 1, wc = wid & 1;
  const int gx = gridDim.x, gy = gridDim.y;
  const int nwg = gx * gy * gridDim.z;
  const int flat = (blockIdx.z * gy + blockIdx.y) * gx + blockIdx.x;
  const int v = (flat & 7) * (nwg >> 3) + (flat >> 3);
  const int bx = v % gx;
  const int rest = v / gx;
  const int by = rest % gy;
  const int bz = rest / gy;
  const int row0 = by * BM, col0 = bx * BN;
  const int Mtot = gy * BM;
  const int sr = lane >> 2, sk = (lane & 3) * 8;
  const int ar = lane & 15, kb = (lane >> 4) * 8;
  const size_t strA = (size_t)2 * K;

  ffrag4 acc[FM][FN];
#pragma unroll
  for (int m = 0; m < FM; ++m)
#pragma unroll
    for (int n = 0; n < FN; ++n) acc[m][n] = ffrag4{0.f, 0.f, 0.f, 0.f};

  const int Kseg = K / SPLITK;
  const int kbeg = bz * Kseg;
  for (int k0 = kbeg; k0 < kbeg + Kseg; k0 += 32) {
    for (int r = wid; r < BM / 16; r += 4) {
      gload16(&A2[(size_t)(row0 + r * 16 + sr) * strA + k0 + sk],     &Ash[r * 16][0]);
      gload16(&A2[(size_t)(row0 + r * 16 + sr) * strA + K + k0 + sk], &Asl[r * 16][0]);
    }
    for (int r = wid; r < BN / 16; r += 4) {
      gload16(&B2t[(size_t)(col0 + r * 16 + sr) * strA + k0 + sk],     &Bsh[r * 16][0]);
      gload16(&B2t[(size_t)(col0 + r * 16 + sr) * strA + K + k0 + sk], &Bsl[r * 16][0]);
    }
    __syncthreads();

    bfrag8 afh[FM], afl[FM], bwh[FN], bwl[FN];
#pragma unroll
    for (int m = 0; m < FM; ++m) {
      afh[m] = *(const bfrag8*)&Ash[wr * WM + m * 16 + ar][kb];
      afl[m] = *(const bfrag8*)&Asl[wr * WM + m * 16 + ar][kb];
    }
#pragma unroll
    for (int n = 0; n < FN; ++n) {
      bwh[n] = *(const bfrag8*)&Bsh[wc * WN + n * 16 + ar][kb];
      bwl[n] = *(const bfrag8*)&Bsl[wc * WN + n * 16 + ar][kb];
    }
#pragma unroll
    for (int m = 0; m < FM; ++m)
#pragma unroll
      for (int n = 0; n < FN; ++n) {
        acc[m][n] = __builtin_amdgcn_mfma_f32_16x16x32_bf16(afh[m], bwh[n], acc[m][n], 0, 0, 0);
        acc[m][n] = __builtin_amdgcn_mfma_f32_16x16x32_bf16(afh[m], bwl[n], acc[m][n], 0, 0, 0);
        acc[m][n] = __builtin_amdgcn_mfma_f32_16x16x32_bf16(afl[m], bwh[n], acc[m][n], 0, 0, 0);
      }
    __syncthreads();
  }

#pragma unroll
  for (int m = 0; m < FM; ++m) {
    int rbase = row0 + wr * WM + m * 16 + (lane >> 4) * 4;
#pragma unroll
    for (int n = 0; n < FN; ++n) {
      int col = col0 + wc * WN + n * 16 + ar;
#pragma unroll
      for (int u = 0; u < 4; ++u) {
        int row = rbase + u;
        float val = acc[m][n][u];
        if constexpr (OUTMODE == 2) {
          Cf[((size_t)bz * Mtot + row) * N + col] = val;
        } else {
          val += bias[col];
          if (ADD_RES) val += res[(size_t)row * N + col];
          if (RELU) val = fmaxf(val, 0.f);
          if constexpr (OUTMODE == 0) {
            Cf[(size_t)row * N + col] = val;
          } else {
            u16 hi = f2bf(val);
            u16 lo = f2bf(val - bf2f(hi));
            size_t rb = (size_t)row * 2 * N;
            C2[rb + col]     = hi;
            C2[rb + N + col] = lo;
          }
        }
      }
    }
  }
}

// ---------------- split-K reduce for ff2: out = part0+part1 + bias + res ----------
__global__ __launch_bounds__(256) void reduce2(const float* __restrict__ part,
    const float* __restrict__ bias, const float* __restrict__ res,
    float* __restrict__ out)
{
  size_t i = ((size_t)blockIdx.x * 256 + threadIdx.x) * 4;
  float4 a = *(const float4*)&part[i];
  float4 b = *(const float4*)&part[(size_t)2097152 + i];   // 4096*512
  float4 r = *(const float4*)&res[i];
  int col = (int)(i & 511);
  float4 o;
  o.x = a.x + b.x + r.x + bias[col];
  o.y = a.y + b.y + r.y + bias[col + 1];
  o.z = a.z + b.z + r.z + bias[col + 2];
  o.w = a.w + b.w + r.w + bias[col + 3];
  *(float4*)&out[i] = o;
}

// ---------------- layernorm over last dim (512), optional residual ----------------
// OUTSPLIT: also emit [hi|lo] bf16 split rows (len 1024) for the next GEMM's A.
template<bool HAS_RES, bool FINAL, bool OUTSPLIT>
__global__ __launch_bounds__(256) void ln_kernel(
    const float* __restrict__ in, const float* __restrict__ res,
    const float* __restrict__ g, const float* __restrict__ b,
    void* __restrict__ out, u16* __restrict__ out2, const int* __restrict__ flag)
{
  int row = blockIdx.x, tid = threadIdx.x;
  size_t base = (size_t)row * DIMc;
  float x0 = in[base + tid], x1 = in[base + tid + 256];
  if (HAS_RES) { x0 += res[base + tid]; x1 += res[base + tid + 256]; }
  float s1 = x0 + x1, s2 = x0 * x0 + x1 * x1;
#pragma unroll
  for (int off = 1; off < 64; off <<= 1) { s1 += __shfl_xor(s1, off); s2 += __shfl_xor(s2, off); }
  __shared__ float p1[4], p2[4], stat[2];
  if ((tid & 63) == 0) { p1[tid >> 6] = s1; p2[tid >> 6] = s2; }
  __syncthreads();
  if (tid == 0) {
    float t1 = p1[0] + p1[1] + p1[2] + p1[3];
    float t2 = p2[0] + p2[1] + p2[2] + p2[3];
    float mu = t1 / DIMc;
    float var = t2 / DIMc - mu * mu;
    stat[0] = mu; stat[1] = rsqrtf(var + LN_EPS);
  }
  __syncthreads();
  float mu = stat[0], rv = stat[1];
  float y0 = (x0 - mu) * rv * g[tid] + b[tid];
  float y1 = (x1 - mu) * rv * g[tid + 256] + b[tid + 256];
  if (FINAL) {
    if (*flag) {
      __hip_bfloat16* o = (__hip_bfloat16*)out;
      o[base + tid] = __float2bfloat16(y0);
      o[base + tid + 256] = __float2bfloat16(y1);
    } else {
      float* o = (float*)out;
      o[base + tid] = y0;
      o[base + tid + 256] = y1;
    }
  } else {
    float* o = (float*)out;
    o[base + tid] = y0;
    o[base + tid + 256] = y1;
  }
  if (OUTSPLIT) {
    size_t rb = (size_t)row * 1024;
    u16 h0 = f2bf(y0);
    out2[rb + tid] = h0;
    out2[rb + 512 + tid] = f2bf(y0 - bf2f(h0));
    u16 h1 = f2bf(y1);
    out2[rb + tid + 256] = h1;
    out2[rb + 512 + tid + 256] = f2bf(y1 - bf2f(h1));
  }
}

// ---------------- causal linear attention, pass A: per-chunk KV sums ----------------
// Writes chunkKV TRANSPOSED: chunkKVT[e][d] = sum_t ks[t][d]*vs[t][e]
__global__ __launch_bounds__(256) void causalA(const float* __restrict__ qvk,
    float* __restrict__ chunkKVT, float* __restrict__ chunkKs)
{
  int c = blockIdx.x, bh = blockIdx.y;
  int b = bh >> 3, h = bh & 7;
  __shared__ float ks[CT][Ec];
  __shared__ float vs[CT][Ec];
  int tid = threadIdx.x;
#pragma unroll
  for (int j = 0; j < 16; ++j) {
    int i = tid + 256 * j;
    int t = i >> 6, d = i & 63;
    size_t rowbase = ((size_t)b * Nc + c * CT + t) * (3 * DIMc);
    ks[t][d] = __expf(qvk[rowbase + 2 * DIMc + h * Ec + d]);
    vs[t][d] = qvk[rowbase + DIMc + h * Ec + d];
  }
  __syncthreads();
  int e = tid & 63, d0 = tid >> 6;
  float acc[16] = {};
  for (int t = 0; t < CT; ++t) {
    float ve = vs[t][e];
#pragma unroll
    for (int j = 0; j < 16; ++j) acc[j] += ks[t][d0 + 4 * j] * ve;
  }
  size_t obase = ((size_t)bh * NCc + c) * (Ec * Ec);
#pragma unroll
  for (int j = 0; j < 16; ++j) chunkKVT[obase + (size_t)e * Ec + (d0 + 4 * j)] = acc[j];
  if (tid < Ec) {
    float s = 0;
    for (int t = 0; t < CT; ++t) s += ks[t][tid];
    chunkKs[((size_t)bh * NCc + c) * Ec + tid] = s;
  }
}

// ---------------- pass B: exclusive prefix over chunks (parallelized) ----------------
// grid (16 bh, 17): y<16 -> KV idx-group of 256; y==16 -> chunkKs scan.
__global__ __launch_bounds__(256) void causalB(float* __restrict__ chunkKV,
                                               float* __restrict__ chunkKs)
{
  int bh = blockIdx.x, grp = blockIdx.y, tid = threadIdx.x;
  if (grp < 16) {
    int idx = grp * 256 + tid;
    float run = 0;
    size_t base = (size_t)bh * NCc * Ec * Ec + idx;
#pragma unroll
    for (int c = 0; c < NCc; ++c) {
      float t = chunkKV[base + (size_t)c * Ec * Ec];
      chunkKV[base + (size_t)c * Ec * Ec] = run;
      run += t;
    }
  } else if (tid < Ec) {
    float run = 0;
    size_t base = (size_t)bh * NCc * Ec + tid;
#pragma unroll
    for (int c = 0; c < NCc; ++c) {
      float t = chunkKs[base + (size_t)c * Ec];
      chunkKs[base + (size_t)c * Ec] = run;
      run += t;
    }
  }
}

// ---------------- pass C: per-token outputs via MFMA ----------------
__global__ __launch_bounds__(256) void causalC(const float* __restrict__ qvk,
    const float* __restrict__ chunkKVT, const float* __restrict__ chunkKs,
    float* __restrict__ attn_out)
{
  int c = blockIdx.x, bh = blockIdx.y;
  int b = bh >> 3, h = bh & 7;
  __shared__ u16 qsh[64 * 64], qsl[64 * 64];   // A: qs[t][d]
  __shared__ u16 ksPh[64 * 64], ksPl[64 * 64]; // B: ks[tau][d]  ->  A: Pm[t][tau]
  __shared__ u16 STh[64 * 64], STl[64 * 64];   // B: S^T[e][d]
  __shared__ u16 VTh[64 * 72], VTl[64 * 72];   // B: V^T[e][tau], pad 72
  __shared__ float kpre[Ec], r0[CT], dinv[CT];
  int tid = threadIdx.x;
  int lane = tid & 63, w = tid >> 6;
  const int ar = lane & 15, kb = (lane >> 4) * 8;
  size_t kvb = (size_t)bh * NCc + c;

  if (tid < Ec) kpre[tid] = chunkKs[kvb * Ec + tid] + ATTN_EPS;

  float qreg[16];
#pragma unroll
  for (int j = 0; j < 16; ++j) {
    int t = w * 16 + j, d = lane;
    size_t rowbase = ((size_t)b * Nc + c * CT + t) * (3 * DIMc);
    qreg[j] = qvk[rowbase + h * Ec + d];
    float kv = __expf(qvk[rowbase + 2 * DIMc + h * Ec + d]);
    u16 hi = f2bf(kv);
    ksPh[SW(t, d)] = hi; ksPl[SW(t, d)] = f2bf(kv - bf2f(hi));
    float vv = qvk[rowbase + DIMc + h * Ec + d];
    hi = f2bf(vv);
    VTh[d * 72 + t] = hi; VTl[d * 72 + t] = f2bf(vv - bf2f(hi));
    float sv = chunkKVT[kvb * (Ec * Ec) + (size_t)t * Ec + d];  // row e=t of S^T
    hi = f2bf(sv);
    STh[SW(t, d)] = hi; STl[SW(t, d)] = f2bf(sv - bf2f(hi));
  }
  __syncthreads();

  for (int ti = 0; ti < 16; ++ti) {
    int t = w * 16 + ti;
    float qv = qreg[ti];
    float mx = qv;
#pragma unroll
    for (int off = 1; off < 64; off <<= 1) mx = fmaxf(mx, __shfl_xor(mx, off));
    float ex = __expf(qv - mx);
    float ssum = ex;
#pragma unroll
    for (int off = 1; off < 64; off <<= 1) ssum += __shfl_xor(ssum, off);
    float qs = ex / ssum * 0.125f;
    float qk = qs * kpre[lane];
#pragma unroll
    for (int off = 1; off < 64; off <<= 1) qk += __shfl_xor(qk, off);
    if (lane == 0) r0[t] = qk;
    u16 hi = f2bf(qs);
    qsh[SW(t, lane)] = hi; qsl[SW(t, lane)] = f2bf(qs - bf2f(hi));
  }
  __syncthreads();

  ffrag4 pacc[4];
#pragma unroll
  for (int ct = 0; ct < 4; ++ct) pacc[ct] = ffrag4{0.f, 0.f, 0.f, 0.f};
#pragma unroll
  for (int ct = 0; ct < 4; ++ct)
#pragma unroll
    for (int k2 = 0; k2 < 64; k2 += 32) {
      bfrag8 ah = *(const bfrag8*)&qsh[SW(w * 16 + ar, k2 + kb)];
      bfrag8 al = *(const bfrag8*)&qsl[SW(w * 16 + ar, k2 + kb)];
      bfrag8 bh_ = *(const bfrag8*)&ksPh[SW(ct * 16 + ar, k2 + kb)];
      bfrag8 bl_ = *(const bfrag8*)&ksPl[SW(ct * 16 + ar, k2 + kb)];
      pacc[ct] = __builtin_amdgcn_mfma_f32_16x16x32_bf16(ah, bh_, pacc[ct], 0, 0, 0);
      pacc[ct] = __builtin_amdgcn_mfma_f32_16x16x32_bf16(ah, bl_, pacc[ct], 0, 0, 0);
      pacc[ct] = __builtin_amdgcn_mfma_f32_16x16x32_bf16(al, bh_, pacc[ct], 0, 0, 0);
    }
  __syncthreads();

  float rs[4] = {0.f, 0.f, 0.f, 0.f};
#pragma unroll
  for (int ct = 0; ct < 4; ++ct) {
    int tau = ct * 16 + ar;
#pragma unroll
    for (int u = 0; u < 4; ++u) {
      int t = w * 16 + (lane >> 4) * 4 + u;
      float pv = (tau <= t) ? pacc[ct][u] : 0.f;
      rs[u] += pv;
      u16 hi = f2bf(pv);
      ksPh[SW(t, tau)] = hi; ksPl[SW(t, tau)] = f2bf(pv - bf2f(hi));
    }
  }
#pragma unroll
  for (int u = 0; u < 4; ++u) {
    float vv = rs[u];
    vv += __shfl_xor(vv, 1); vv += __shfl_xor(vv, 2);
    vv += __shfl_xor(vv, 4); vv += __shfl_xor(vv, 8);
    if (ar == 0) {
      int t = w * 16 + (lane >> 4) * 4 + u;
      dinv[t] = 1.f / (r0[t] + vv);
    }
  }
  __syncthreads();

#pragma unroll
  for (int et = 0; et < 4; ++et) {
    ffrag4 oacc = ffrag4{0.f, 0.f, 0.f, 0.f};
#pragma unroll
    for (int k2 = 0; k2 < 64; k2 += 32) {
      bfrag8 ah = *(const bfrag8*)&qsh[SW(w * 16 + ar, k2 + kb)];
      bfrag8 al = *(const bfrag8*)&qsl[SW(w * 16 + ar, k2 + kb)];
      bfrag8 bh_ = *(const bfrag8*)&STh[SW(et * 16 + ar, k2 + kb)];
      bfrag8 bl_ = *(const bfrag8*)&STl[SW(et * 16 + ar, k2 + kb)];
      oacc = __builtin_amdgcn_mfma_f32_16x16x32_bf16(ah, bh_, oacc, 0, 0, 0);
      oacc = __builtin_amdgcn_mfma_f32_16x16x32_bf16(ah, bl_, oacc, 0, 0, 0);
      oacc = __builtin_amdgcn_mfma_f32_16x16x32_bf16(al, bh_, oacc, 0, 0, 0);
      bfrag8 ph = *(const bfrag8*)&ksPh[SW(w * 16 + ar, k2 + kb)];
      bfrag8 pl = *(const bfrag8*)&ksPl[SW(w * 16 + ar, k2 + kb)];
      bfrag8 vh = *(const bfrag8*)&VTh[(et * 16 + ar) * 72 + k2 + kb];
      bfrag8 vl = *(const bfrag8*)&VTl[(et * 16 + ar) * 72 + k2 + kb];
      oacc = __builtin_amdgcn_mfma_f32_16x16x32_bf16(ph, vh, oacc, 0, 0, 0);
      oacc = __builtin_amdgcn_mfma_f32_16x16x32_bf16(ph, vl, oacc, 0, 0, 0);
      oacc = __builtin_amdgcn_mfma_f32_16x16x32_bf16(pl, vh, oacc, 0, 0, 0);
    }
    int e = et * 16 + ar;
#pragma unroll
    for (int u = 0; u < 4; ++u) {
      int t = w * 16 + (lane >> 4) * 4 + u;
      attn_out[((size_t)b * Nc + c * CT + t) * DIMc + h * Ec + e] = oacc[u] * dinv[t];
    }
  }
}

// ---------------- cross-attn: ctxU[d,e] = sum_m exp(k2)[m,d] * v2[m,e]  (+colsum) ----
__global__ __launch_bounds__(256) void ctx_kernel(const float* __restrict__ kvbuf,
    float* __restrict__ colsum, float* __restrict__ ctx)
{
  int slab = blockIdx.x, bh = blockIdx.y;
  int b = bh >> 3, h = bh & 7;
  __shared__ float ks[64][Ec];
  __shared__ float vs[64][Ec];
  int tid = threadIdx.x;
#pragma unroll
  for (int j = 0; j < 16; ++j) {
    int i = tid + 256 * j;
    int m = i >> 6, d = i & 63;
    size_t rowbase = ((size_t)b * Mc + slab * 64 + m) * (2 * DIMc);
    ks[m][d] = __expf(kvbuf[rowbase + h * Ec + d]);
    vs[m][d] = kvbuf[rowbase + DIMc + h * Ec + d];
  }
  __syncthreads();
  int e = tid & 63, d0 = tid >> 6;
  float acc[16] = {};
  for (int m = 0; m < 64; ++m) {
    float ve = vs[m][e];
#pragma unroll
    for (int j = 0; j < 16; ++j) acc[j] += ks[m][d0 + 4 * j] * ve;
  }
  size_t obase = (size_t)bh * Ec * Ec;
#pragma unroll
  for (int j = 0; j < 16; ++j) atomicAdd(&ctx[obase + (size_t)(d0 + 4 * j) * Ec + e], acc[j]);
  int w = tid >> 6, lane = tid & 63;
  float s = 0;
#pragma unroll
  for (int m = 0; m < 16; ++m) s += ks[w * 16 + m][lane];
  __shared__ float p[4][Ec];
  p[w][lane] = s;
  __syncthreads();
  if (tid < Ec)
    atomicAdd(&colsum[(size_t)bh * Ec + tid], p[0][tid] + p[1][tid] + p[2][tid] + p[3][tid]);
}

// ---------------- normalize ctx rows by colsum (tiny) ----------------
__global__ __launch_bounds__(256) void normctx(float* __restrict__ ctx,
                                               const float* __restrict__ colsum)
{
  int bh = blockIdx.x, tid = threadIdx.x;
#pragma unroll
  for (int j = 0; j < 16; ++j) {
    int i = tid + 256 * j;
    int d = i >> 6;
    ctx[(size_t)bh * Ec * Ec + i] /= colsum[(size_t)bh * Ec + d];
  }
}

// ---------------- cross-attn: out[t,e] = softmax(q2[t])*E^-.5 @ ctx ----------------
__global__ __launch_bounds__(256) void attn2_kernel(const float* __restrict__ q2,
    const float* __restrict__ ctx, float* __restrict__ out)
{
  int bh = blockIdx.y;
  int b = bh >> 3, h = bh & 7;
  __shared__ float cs[Ec][Ec];
  int tid = threadIdx.x;
#pragma unroll
  for (int j = 0; j < 16; ++j) {
    int i = tid + 256 * j;
    cs[i >> 6][i & 63] = ctx[(size_t)bh * Ec * Ec + i];
  }
  __syncthreads();
  int w = tid >> 6, lane = tid & 63;
  int t = blockIdx.x * 4 + w;
  float qv = q2[((size_t)b * Nc + t) * DIMc + h * Ec + lane];
  float mx = qv;
#pragma unroll
  for (int off = 1; off < 64; off <<= 1) mx = fmaxf(mx, __shfl_xor(mx, off));
  float ex = __expf(qv - mx);
  float ssum = ex;
#pragma unroll
  for (int off = 1; off < 64; off <<= 1) ssum += __shfl_xor(ssum, off);
  float qs = ex / ssum * 0.125f;
  float acc = 0;
  for (int d = 0; d < Ec; ++d) acc += __shfl(qs, d) * cs[d][lane];
  out[((size_t)b * Nc + t) * DIMc + h * Ec + lane] = acc;
}

extern "C" void kernel_launch(void* const* d_in, const int* in_sizes, int n_in,
                              void* d_out, int out_size, void* d_ws, size_t ws_size,
                              hipStream_t stream)
{
  float* ws = (float*)d_ws;
  int* flag = (int*)ws;
  float* conv = ws + 64;

  float* cin[18];
  size_t off = 0;
  for (int i = 0; i < 18; ++i) { cin[i] = conv + off; off += (size_t)in_sizes[i]; }
  float* pipe = conv + off;

  const size_t SZ_ROW = (size_t)Bc * Nc * DIMc;            // 2,097,152
  const size_t SZ_KV  = (size_t)Bc * Mc * 2 * DIMc;        // 4,194,304
  const size_t SZ_R0  = 12582912;                          // region0 span (f-eq)

  float* region0 = pipe;
  float* qvk     = region0;                   // live: gemm1 .. causalC
  float* kvbuf   = region0;                   // live: kvGEMM .. ctx_kernel
  float* q2      = region0 + SZ_KV;           // live: q2GEMM .. attn2
  u16*   O2ff    = (u16*)region0;             // live: ff1 .. ff2 ([hi|lo], 8.39M f-eq)
  float* partials= region0 + 8388608;         // ff2 split-K partials (2 x 2.10M f)
  float* out1    = region0 + SZ_R0;           // live: LN1 .. LN2
  float* attn_o  = out1 + SZ_ROW;             // attn_o -> attn2_o -> ybuf
  float* r3      = attn_o + SZ_ROW;           // chunkKV -> pre3
  float* chunkKV = r3;
  float* pre3    = r3;
  float* chunkKs = r3 + SZ_ROW;                                   // 32768
  float* colsum  = chunkKs + (size_t)Bc * Hc * NCc * Ec;          // 1024
  float* ctx2    = colsum + (size_t)Bc * Hc * Ec;                 // 65536
  float* ybuf    = attn_o;
  float* attn2_o = attn_o;

  u16* B2_qvk = (u16*)(ctx2 + (size_t)Bc * Hc * Ec * Ec);
  u16* B2_kv  = B2_qvk + (size_t)(3 * DIMc) * (2 * DIMc);   // 1536 x 1024
  u16* B2_q   = B2_kv  + (size_t)(2 * DIMc) * (2 * DIMc);   // 1024 x 1024
  u16* B2_ff1 = B2_q   + (size_t)DIMc * (2 * DIMc);         // 512 x 1024
  u16* B2_ff2 = B2_ff1 + (size_t)FFc  * (2 * DIMc);         // 2048 x 1024
  u16* A2slotA = B2_ff2 + (size_t)DIMc * (2 * FFc);         // 4096 x 1024 (x / memory / ybuf)
  u16* A2slotB = A2slotA + (size_t)4096 * 1024;             // 4096 x 1024 (out1)
  (void)ws_size; (void)n_in; (void)out_size;

  dim3 blk(256);
  const int MR = Bc * Nc;  // 4096 rows

  // 0. detect input dtype; ingest ONLY what is needed in fp32:
  //    x (LN1 residual) + biases + LN params. memory & weights are read raw.
  detect_kernel<<<dim3(1), dim3(64), 0, stream>>>(d_in[0], flag);
  ConvJobs jobs;
  for (int i = 0; i < 18; ++i) { jobs.j[i].src = d_in[i]; jobs.j[i].dst = cin[i]; jobs.j[i].n = in_sizes[i]; }
  jobs.j[1].n = 0;   // memory  -> split_act_raw reads d_in[1]
  jobs.j[2].n = 0;   // W_qvk   -> wsplit reads d_in[2]
  jobs.j[4].n = 0;   // W_kv
  jobs.j[6].n = 0;   // W_q
  jobs.j[8].n = 0;   // W_ff1
  jobs.j[10].n = 0;  // W_ff2
  ingest_kernel<<<dim3(32, 18), blk, 0, stream>>>(jobs, flag);

  const float *x = cin[0], *b_qvk = cin[3], *b_kv = cin[5], *b_q = cin[7],
              *b_ff1 = cin[9], *b_ff2 = cin[11],
              *ln1_g = cin[12], *ln1_b = cin[13], *ln2_g = cin[14], *ln2_b = cin[15],
              *ln3_g = cin[16], *ln3_b = cin[17];

  // 0b. weight transpose+split straight from d_in (dtype-aware)
  wsplit_kernel<<<dim3(24, 8), blk, 0, stream>>>(d_in[2],  flag, B2_qvk, DIMc, 3 * DIMc);
  wsplit_kernel<<<dim3(16, 8), blk, 0, stream>>>(d_in[4],  flag, B2_kv,  DIMc, 2 * DIMc);
  wsplit_kernel<<<dim3(8, 8),  blk, 0, stream>>>(d_in[6],  flag, B2_q,   DIMc, DIMc);
  wsplit_kernel<<<dim3(32, 8), blk, 0, stream>>>(d_in[8],  flag, B2_ff1, DIMc, FFc);
  wsplit_kernel<<<dim3(8, 32), blk, 0, stream>>>(d_in[10], flag, B2_ff2, FFc,  DIMc);

  // 1. qvk = x @ W_qvk + b   (x split read raw from d_in[0])
  split_act_raw<<<dim3(1024), blk, 0, stream>>>(d_in[0], flag, A2slotA, 9, (int)SZ_ROW);
  gemm_mfma<128, 128, 1, 0, false, false><<<dim3(12, 32), blk, 0, stream>>>(
      A2slotA, B2_qvk, b_qvk, nullptr, qvk, nullptr, 3 * DIMc, DIMc);
  // 2. causal linear self-attention
  causalA<<<dim3(NCc, Bc * Hc), blk, 0, stream>>>(qvk, chunkKV, chunkKs);
  causalB<<<dim3(16, 17), blk, 0, stream>>>(chunkKV, chunkKs);
  causalC<<<dim3(NCc, Bc * Hc), blk, 0, stream>>>(qvk, chunkKV, chunkKs, attn_o);
  // 3. LN1(attn + x) -> out1 fp32 + split into slotB (q2 GEMM A)
  ln_kernel<true, false, true><<<dim3(MR), blk, 0, stream>>>(
      attn_o, x, ln1_g, ln1_b, out1, A2slotB, flag);
  // 4. kv = memory @ W_kv + b (memory split read raw); q2 = out1 @ W_q + b
  split_act_raw<<<dim3(1024), blk, 0, stream>>>(d_in[1], flag, A2slotA, 9, (int)SZ_ROW);
  gemm_mfma<128, 128, 1, 0, false, false><<<dim3(8, 32), blk, 0, stream>>>(
      A2slotA, B2_kv, b_kv, nullptr, kvbuf, nullptr, 2 * DIMc, DIMc);
  gemm_mfma<128, 64, 1, 0, false, false><<<dim3(8, 32), blk, 0, stream>>>(
      A2slotB, B2_q, b_q, nullptr, q2, nullptr, DIMc, DIMc);
  // 5. cross linear attention
  hipMemsetAsync(colsum, 0,
      ((size_t)Bc * Hc * Ec + (size_t)Bc * Hc * Ec * Ec) * sizeof(float), stream);
  ctx_kernel<<<dim3(Mc / 64, Bc * Hc), blk, 0, stream>>>(kvbuf, colsum, ctx2);
  normctx<<<dim3(Bc * Hc), blk, 0, stream>>>(ctx2, colsum);
  attn2_kernel<<<dim3(Nc / 4, Bc * Hc), blk, 0, stream>>>(q2, ctx2, attn2_o);
  // 6. LN2(attn2 + out1) in-place -> ybuf fp32 + split into slotA (ff1 A)
  ln_kernel<true, false, true><<<dim3(MR), blk, 0, stream>>>(
      attn2_o, out1, ln2_g, ln2_b, ybuf, A2slotA, flag);
  // 7. FF: ff1 writes [hi|lo] split directly; ff2 split-K=2 + reduce(bias+res)
  gemm_mfma<128, 128, 1, 1, true, false><<<dim3(16, 32), blk, 0, stream>>>(
      A2slotA, B2_ff1, b_ff1, nullptr, nullptr, O2ff, FFc, DIMc);
  gemm_mfma<128, 64, 2, 2, false, false><<<dim3(8, 32, 2), blk, 0, stream>>>(
      O2ff, B2_ff2, b_ff2, nullptr, partials, nullptr, DIMc, FFc);
  reduce2<<<dim3(2048), blk, 0, stream>>>(partials, b_ff2, ybuf, pre3);
  // 8. LN3 -> d_out (bf16 or fp32 per flag)
  ln_kernel<false, true, false><<<dim3(MR), blk, 0, stream>>>(
      pre3, nullptr, ln3_g, ln3_b, d_out, nullptr, flag);
}

// Round 6
// 410.451 us; speedup vs baseline: 3.0426x; 1.0506x over previous
//
#include <hip/hip_runtime.h>
#include <hip/hip_bf16.h>

#define DEV __device__ __forceinline__

constexpr int Bc = 2, Nc = 2048, Mc = 2048, DIMc = 512, Hc = 8, FFc = 2048, Ec = 64;
constexpr int CT = 64;            // causal chunk length (tokens)
constexpr int NCc = Nc / CT;      // 32 chunks per sequence
constexpr float LN_EPS = 1e-5f, ATTN_EPS = 1e-6f;

typedef __bf16 bfrag8 __attribute__((ext_vector_type(8)));
typedef float ffrag4 __attribute__((ext_vector_type(4)));
typedef unsigned short u16;

// ---------------- helpers ----------------
DEV u16 f2bf(float v) {
  __hip_bfloat16 h = __float2bfloat16(v);   // RTN-even
  return __builtin_bit_cast(unsigned short, h);
}
DEV float bf2f(u16 u) { return __uint_as_float(((unsigned)u) << 16); }

DEV void gload16(const void* g, void* l) {
  __builtin_amdgcn_global_load_lds(
      (const __attribute__((address_space(1))) void*)g,
      (__attribute__((address_space(3))) void*)l, 16, 0, 0);
}

// XOR swizzle for [64][64] u16 LDS tiles (row stride 128B).
DEV int SW(int r, int c) { return r * 64 + (c ^ ((r & 7) << 3)); }

// ---------------- dtype detection ----------------
__global__ __launch_bounds__(64) void detect_kernel(const void* x, int* flag) {
  const unsigned short* u = (const unsigned short*)x;
  int tid = threadIdx.x;
  int bad = 0;
#pragma unroll
  for (int i = 0; i < 8; ++i) {
    float v = __uint_as_float(((unsigned)u[tid * 8 + i]) << 16);
    if (!(fabsf(v) <= 1e4f)) bad = 1;   // catches NaN, Inf, garbage
  }
  unsigned long long m = __ballot(bad);
  if (tid == 0) *flag = (m == 0ull) ? 1 : 0;  // 1 = inputs are bf16
}

// ---------------- ingest (vectorized, only for arrays needed in fp32) ----------------
struct ConvJob { const void* src; float* dst; int n; };
struct ConvJobs { ConvJob j[18]; };

__global__ __launch_bounds__(256) void ingest_kernel(ConvJobs jobs, const int* flag) {
  int bf = *flag;
  ConvJob jb = jobs.j[blockIdx.y];
  int n8 = jb.n >> 3;
  int stride = gridDim.x * 256;
  for (int i = blockIdx.x * 256 + threadIdx.x; i < n8; i += stride) {
    float o[8];
    if (bf) {
      uint4 a = ((const uint4*)jb.src)[i];
      unsigned w[4] = {a.x, a.y, a.z, a.w};
#pragma unroll
      for (int j = 0; j < 4; ++j) {
        o[2 * j]     = bf2f((u16)(w[j] & 0xffff));
        o[2 * j + 1] = bf2f((u16)(w[j] >> 16));
      }
    } else {
      float4 a = ((const float4*)jb.src)[2 * i];
      float4 b = ((const float4*)jb.src)[2 * i + 1];
      o[0] = a.x; o[1] = a.y; o[2] = a.z; o[3] = a.w;
      o[4] = b.x; o[5] = b.y; o[6] = b.z; o[7] = b.w;
    }
    float4* d = (float4*)jb.dst;
    d[2 * i]     = float4{o[0], o[1], o[2], o[3]};
    d[2 * i + 1] = float4{o[4], o[5], o[6], o[7]};
  }
}

// ---------------- raw input -> 2-term bf16 split [hi|lo] (dtype-aware) ----------------
__global__ __launch_bounds__(256) void split_act_raw(const void* __restrict__ in,
    const int* __restrict__ flag, u16* __restrict__ out, int kshift, int total)
{
  int bf = *flag;
  const int K = 1 << kshift;
  int n8 = total >> 3;
  int stride = gridDim.x * 256;
  for (int ii = blockIdx.x * 256 + threadIdx.x; ii < n8; ii += stride) {
    int i = ii * 8;
    float v[8];
    if (bf) {
      uint4 a = ((const uint4*)in)[ii];
      unsigned w[4] = {a.x, a.y, a.z, a.w};
#pragma unroll
      for (int j = 0; j < 4; ++j) {
        v[2 * j]     = bf2f((u16)(w[j] & 0xffff));
        v[2 * j + 1] = bf2f((u16)(w[j] >> 16));
      }
    } else {
      float4 a = ((const float4*)in)[2 * ii];
      float4 b = ((const float4*)in)[2 * ii + 1];
      v[0] = a.x; v[1] = a.y; v[2] = a.z; v[3] = a.w;
      v[4] = b.x; v[5] = b.y; v[6] = b.z; v[7] = b.w;
    }
    unsigned hw[4], lw[4];
#pragma unroll
    for (int j = 0; j < 4; ++j) {
      u16 h0 = f2bf(v[2 * j]),     l0 = f2bf(v[2 * j]     - bf2f(f2bf(v[2 * j])));
      u16 h1 = f2bf(v[2 * j + 1]), l1 = f2bf(v[2 * j + 1] - bf2f(f2bf(v[2 * j + 1])));
      hw[j] = (unsigned)h0 | ((unsigned)h1 << 16);
      lw[j] = (unsigned)l0 | ((unsigned)l1 << 16);
    }
    int row = i >> kshift, k = i & (K - 1);
    size_t rb = (size_t)row * 2 * K + k;
    *(uint4*)&out[rb]     = uint4{hw[0], hw[1], hw[2], hw[3]};
    *(uint4*)&out[rb + K] = uint4{lw[0], lw[1], lw[2], lw[3]};
  }
}

// ---------------- W (KxN, raw dtype) -> B2t (N x 2K bf16) transpose+split ----------------
__global__ __launch_bounds__(256) void wsplit_kernel(const void* __restrict__ W,
    const int* __restrict__ flag, u16* __restrict__ B2t, int K, int N)
{
  int bf = *flag;
  __shared__ float T[64][65];
  int n0 = blockIdx.x * 64, k0 = blockIdx.y * 64;
  int tid = threadIdx.x;
#pragma unroll
  for (int j = 0; j < 16; ++j) {
    int idx = tid + 256 * j;
    int kl = idx >> 6, nl = idx & 63;
    size_t gi = (size_t)(k0 + kl) * N + n0 + nl;
    T[kl][nl] = bf ? bf2f(((const u16*)W)[gi]) : ((const float*)W)[gi];
  }
  __syncthreads();
#pragma unroll
  for (int j = 0; j < 16; ++j) {
    int idx = tid + 256 * j;
    int nl = idx >> 6, kl = idx & 63;
    float v = T[kl][nl];
    u16 hi = f2bf(v);
    u16 lo = f2bf(v - bf2f(hi));
    size_t rb = (size_t)(n0 + nl) * 2 * K + k0 + kl;
    B2t[rb]     = hi;
    B2t[rb + K] = lo;
  }
}

// ---------------- MFMA GEMM: C[M,N] = A2[M,2K] @ B2t[N,2K]^T ----------------
// 2-term split operands [hi|lo]; per k-step issues Ah*Bh + Ah*Bl + Al*Bh.
// Bijective XCD swizzle. OUTMODE 0: fp32 C (+bias)(+res)(relu). OUTMODE 1: split
// [hi|lo] bf16 out (row 2N). OUTMODE 2: raw fp32 partial (split-K).
template<int BM, int BN, int SPLITK, int OUTMODE, bool RELU, bool ADD_RES>
__global__ __launch_bounds__(256) void gemm_mfma(
    const u16* __restrict__ A2, const u16* __restrict__ B2t,
    const float* __restrict__ bias, const float* __restrict__ res,
    float* __restrict__ Cf, u16* __restrict__ C2,
    int N, int K)
{
  constexpr int WM = BM / 2, WN = BN / 2, FM = WM / 16, FN = WN / 16;
  __shared__ u16 Ash[BM][32], Asl[BM][32];
  __shared__ u16 Bsh[BN][32], Bsl[BN][32];
  const int tid = threadIdx.x;
  const int lane = tid & 63, wid = tid >> 6;
  const int wr = wid >> 1, wc = wid & 1;
  const int gx = gridDim.x, gy = gridDim.y;
  const int nwg = gx * gy * gridDim.z;
  const int flat = (blockIdx.z * gy + blockIdx.y) * gx + blockIdx.x;
  const int v = (flat & 7) * (nwg >> 3) + (flat >> 3);
  const int bx = v % gx;
  const int rest = v / gx;
  const int by = rest % gy;
  const int bz = rest / gy;
  const int row0 = by * BM, col0 = bx * BN;
  const int Mtot = gy * BM;
  const int sr = lane >> 2, sk = (lane & 3) * 8;
  const int ar = lane & 15, kb = (lane >> 4) * 8;
  const size_t strA = (size_t)2 * K;

  ffrag4 acc[FM][FN];
#pragma unroll
  for (int m = 0; m < FM; ++m)
#pragma unroll
    for (int n = 0; n < FN; ++n) acc[m][n] = ffrag4{0.f, 0.f, 0.f, 0.f};

  const int Kseg = K / SPLITK;
  const int kbeg = bz * Kseg;
  for (int k0 = kbeg; k0 < kbeg + Kseg; k0 += 32) {
    for (int r = wid; r < BM / 16; r += 4) {
      gload16(&A2[(size_t)(row0 + r * 16 + sr) * strA + k0 + sk],     &Ash[r * 16][0]);
      gload16(&A2[(size_t)(row0 + r * 16 + sr) * strA + K + k0 + sk], &Asl[r * 16][0]);
    }
    for (int r = wid; r < BN / 16; r += 4) {
      gload16(&B2t[(size_t)(col0 + r * 16 + sr) * strA + k0 + sk],     &Bsh[r * 16][0]);
      gload16(&B2t[(size_t)(col0 + r * 16 + sr) * strA + K + k0 + sk], &Bsl[r * 16][0]);
    }
    __syncthreads();

    bfrag8 afh[FM], afl[FM], bwh[FN], bwl[FN];
#pragma unroll
    for (int m = 0; m < FM; ++m) {
      afh[m] = *(const bfrag8*)&Ash[wr * WM + m * 16 + ar][kb];
      afl[m] = *(const bfrag8*)&Asl[wr * WM + m * 16 + ar][kb];
    }
#pragma unroll
    for (int n = 0; n < FN; ++n) {
      bwh[n] = *(const bfrag8*)&Bsh[wc * WN + n * 16 + ar][kb];
      bwl[n] = *(const bfrag8*)&Bsl[wc * WN + n * 16 + ar][kb];
    }
#pragma unroll
    for (int m = 0; m < FM; ++m)
#pragma unroll
      for (int n = 0; n < FN; ++n) {
        acc[m][n] = __builtin_amdgcn_mfma_f32_16x16x32_bf16(afh[m], bwh[n], acc[m][n], 0, 0, 0);
        acc[m][n] = __builtin_amdgcn_mfma_f32_16x16x32_bf16(afh[m], bwl[n], acc[m][n], 0, 0, 0);
        acc[m][n] = __builtin_amdgcn_mfma_f32_16x16x32_bf16(afl[m], bwh[n], acc[m][n], 0, 0, 0);
      }
    __syncthreads();
  }

#pragma unroll
  for (int m = 0; m < FM; ++m) {
    int rbase = row0 + wr * WM + m * 16 + (lane >> 4) * 4;
#pragma unroll
    for (int n = 0; n < FN; ++n) {
      int col = col0 + wc * WN + n * 16 + ar;
#pragma unroll
      for (int u = 0; u < 4; ++u) {
        int row = rbase + u;
        float val = acc[m][n][u];
        if constexpr (OUTMODE == 2) {
          Cf[((size_t)bz * Mtot + row) * N + col] = val;
        } else {
          val += bias[col];
          if (ADD_RES) val += res[(size_t)row * N + col];
          if (RELU) val = fmaxf(val, 0.f);
          if constexpr (OUTMODE == 0) {
            Cf[(size_t)row * N + col] = val;
          } else {
            u16 hi = f2bf(val);
            u16 lo = f2bf(val - bf2f(hi));
            size_t rb = (size_t)row * 2 * N;
            C2[rb + col]     = hi;
            C2[rb + N + col] = lo;
          }
        }
      }
    }
  }
}

// ---------------- split-K reduce for ff2: out = part0+part1 + bias + res ----------
__global__ __launch_bounds__(256) void reduce2(const float* __restrict__ part,
    const float* __restrict__ bias, const float* __restrict__ res,
    float* __restrict__ out)
{
  size_t i = ((size_t)blockIdx.x * 256 + threadIdx.x) * 4;
  float4 a = *(const float4*)&part[i];
  float4 b = *(const float4*)&part[(size_t)2097152 + i];   // 4096*512
  float4 r = *(const float4*)&res[i];
  int col = (int)(i & 511);
  float4 o;
  o.x = a.x + b.x + r.x + bias[col];
  o.y = a.y + b.y + r.y + bias[col + 1];
  o.z = a.z + b.z + r.z + bias[col + 2];
  o.w = a.w + b.w + r.w + bias[col + 3];
  *(float4*)&out[i] = o;
}

// ---------------- layernorm over last dim (512), optional residual ----------------
// OUTSPLIT: also emit [hi|lo] bf16 split rows (len 1024) for the next GEMM's A.
template<bool HAS_RES, bool FINAL, bool OUTSPLIT>
__global__ __launch_bounds__(256) void ln_kernel(
    const float* __restrict__ in, const float* __restrict__ res,
    const float* __restrict__ g, const float* __restrict__ b,
    void* __restrict__ out, u16* __restrict__ out2, const int* __restrict__ flag)
{
  int row = blockIdx.x, tid = threadIdx.x;
  size_t base = (size_t)row * DIMc;
  float x0 = in[base + tid], x1 = in[base + tid + 256];
  if (HAS_RES) { x0 += res[base + tid]; x1 += res[base + tid + 256]; }
  float s1 = x0 + x1, s2 = x0 * x0 + x1 * x1;
#pragma unroll
  for (int off = 1; off < 64; off <<= 1) { s1 += __shfl_xor(s1, off); s2 += __shfl_xor(s2, off); }
  __shared__ float p1[4], p2[4], stat[2];
  if ((tid & 63) == 0) { p1[tid >> 6] = s1; p2[tid >> 6] = s2; }
  __syncthreads();
  if (tid == 0) {
    float t1 = p1[0] + p1[1] + p1[2] + p1[3];
    float t2 = p2[0] + p2[1] + p2[2] + p2[3];
    float mu = t1 / DIMc;
    float var = t2 / DIMc - mu * mu;
    stat[0] = mu; stat[1] = rsqrtf(var + LN_EPS);
  }
  __syncthreads();
  float mu = stat[0], rv = stat[1];
  float y0 = (x0 - mu) * rv * g[tid] + b[tid];
  float y1 = (x1 - mu) * rv * g[tid + 256] + b[tid + 256];
  if (FINAL) {
    if (*flag) {
      __hip_bfloat16* o = (__hip_bfloat16*)out;
      o[base + tid] = __float2bfloat16(y0);
      o[base + tid + 256] = __float2bfloat16(y1);
    } else {
      float* o = (float*)out;
      o[base + tid] = y0;
      o[base + tid + 256] = y1;
    }
  } else {
    float* o = (float*)out;
    o[base + tid] = y0;
    o[base + tid + 256] = y1;
  }
  if (OUTSPLIT) {
    size_t rb = (size_t)row * 1024;
    u16 h0 = f2bf(y0);
    out2[rb + tid] = h0;
    out2[rb + 512 + tid] = f2bf(y0 - bf2f(h0));
    u16 h1 = f2bf(y1);
    out2[rb + tid + 256] = h1;
    out2[rb + 512 + tid + 256] = f2bf(y1 - bf2f(h1));
  }
}

// ---------------- causal linear attention, pass A: per-chunk KV sums ----------------
// Writes chunkKV TRANSPOSED: chunkKVT[e][d] = sum_t ks[t][d]*vs[t][e]
__global__ __launch_bounds__(256) void causalA(const float* __restrict__ qvk,
    float* __restrict__ chunkKVT, float* __restrict__ chunkKs)
{
  int c = blockIdx.x, bh = blockIdx.y;
  int b = bh >> 3, h = bh & 7;
  __shared__ float ks[CT][Ec];
  __shared__ float vs[CT][Ec];
  int tid = threadIdx.x;
#pragma unroll
  for (int j = 0; j < 16; ++j) {
    int i = tid + 256 * j;
    int t = i >> 6, d = i & 63;
    size_t rowbase = ((size_t)b * Nc + c * CT + t) * (3 * DIMc);
    ks[t][d] = __expf(qvk[rowbase + 2 * DIMc + h * Ec + d]);
    vs[t][d] = qvk[rowbase + DIMc + h * Ec + d];
  }
  __syncthreads();
  int e = tid & 63, d0 = tid >> 6;
  float acc[16] = {};
  for (int t = 0; t < CT; ++t) {
    float ve = vs[t][e];
#pragma unroll
    for (int j = 0; j < 16; ++j) acc[j] += ks[t][d0 + 4 * j] * ve;
  }
  size_t obase = ((size_t)bh * NCc + c) * (Ec * Ec);
#pragma unroll
  for (int j = 0; j < 16; ++j) chunkKVT[obase + (size_t)e * Ec + (d0 + 4 * j)] = acc[j];
  if (tid < Ec) {
    float s = 0;
    for (int t = 0; t < CT; ++t) s += ks[t][tid];
    chunkKs[((size_t)bh * NCc + c) * Ec + tid] = s;
  }
}

// ---------------- pass B: exclusive prefix over chunks (parallelized) ----------------
__global__ __launch_bounds__(256) void causalB(float* __restrict__ chunkKV,
                                               float* __restrict__ chunkKs)
{
  int bh = blockIdx.x, grp = blockIdx.y, tid = threadIdx.x;
  if (grp < 16) {
    int idx = grp * 256 + tid;
    float run = 0;
    size_t base = (size_t)bh * NCc * Ec * Ec + idx;
#pragma unroll
    for (int c = 0; c < NCc; ++c) {
      float t = chunkKV[base + (size_t)c * Ec * Ec];
      chunkKV[base + (size_t)c * Ec * Ec] = run;
      run += t;
    }
  } else if (tid < Ec) {
    float run = 0;
    size_t base = (size_t)bh * NCc * Ec + tid;
#pragma unroll
    for (int c = 0; c < NCc; ++c) {
      float t = chunkKs[base + (size_t)c * Ec];
      chunkKs[base + (size_t)c * Ec] = run;
      run += t;
    }
  }
}

// ---------------- pass C: per-token outputs via MFMA ----------------
__global__ __launch_bounds__(256) void causalC(const float* __restrict__ qvk,
    const float* __restrict__ chunkKVT, const float* __restrict__ chunkKs,
    float* __restrict__ attn_out)
{
  int c = blockIdx.x, bh = blockIdx.y;
  int b = bh >> 3, h = bh & 7;
  __shared__ u16 qsh[64 * 64], qsl[64 * 64];   // A: qs[t][d]
  __shared__ u16 ksPh[64 * 64], ksPl[64 * 64]; // B: ks[tau][d]  ->  A: Pm[t][tau]
  __shared__ u16 STh[64 * 64], STl[64 * 64];   // B: S^T[e][d]
  __shared__ u16 VTh[64 * 72], VTl[64 * 72];   // B: V^T[e][tau], pad 72
  __shared__ float kpre[Ec], r0[CT], dinv[CT];
  int tid = threadIdx.x;
  int lane = tid & 63, w = tid >> 6;
  const int ar = lane & 15, kb = (lane >> 4) * 8;
  size_t kvb = (size_t)bh * NCc + c;

  if (tid < Ec) kpre[tid] = chunkKs[kvb * Ec + tid] + ATTN_EPS;

  float qreg[16];
#pragma unroll
  for (int j = 0; j < 16; ++j) {
    int t = w * 16 + j, d = lane;
    size_t rowbase = ((size_t)b * Nc + c * CT + t) * (3 * DIMc);
    qreg[j] = qvk[rowbase + h * Ec + d];
    float kv = __expf(qvk[rowbase + 2 * DIMc + h * Ec + d]);
    u16 hi = f2bf(kv);
    ksPh[SW(t, d)] = hi; ksPl[SW(t, d)] = f2bf(kv - bf2f(hi));
    float vv = qvk[rowbase + DIMc + h * Ec + d];
    hi = f2bf(vv);
    VTh[d * 72 + t] = hi; VTl[d * 72 + t] = f2bf(vv - bf2f(hi));
    float sv = chunkKVT[kvb * (Ec * Ec) + (size_t)t * Ec + d];  // row e=t of S^T
    hi = f2bf(sv);
    STh[SW(t, d)] = hi; STl[SW(t, d)] = f2bf(sv - bf2f(hi));
  }
  __syncthreads();

  for (int ti = 0; ti < 16; ++ti) {
    int t = w * 16 + ti;
    float qv = qreg[ti];
    float mx = qv;
#pragma unroll
    for (int off = 1; off < 64; off <<= 1) mx = fmaxf(mx, __shfl_xor(mx, off));
    float ex = __expf(qv - mx);
    float ssum = ex;
#pragma unroll
    for (int off = 1; off < 64; off <<= 1) ssum += __shfl_xor(ssum, off);
    float qs = ex / ssum * 0.125f;
    float qk = qs * kpre[lane];
#pragma unroll
    for (int off = 1; off < 64; off <<= 1) qk += __shfl_xor(qk, off);
    if (lane == 0) r0[t] = qk;
    u16 hi = f2bf(qs);
    qsh[SW(t, lane)] = hi; qsl[SW(t, lane)] = f2bf(qs - bf2f(hi));
  }
  __syncthreads();

  ffrag4 pacc[4];
#pragma unroll
  for (int ct = 0; ct < 4; ++ct) pacc[ct] = ffrag4{0.f, 0.f, 0.f, 0.f};
#pragma unroll
  for (int ct = 0; ct < 4; ++ct)
#pragma unroll
    for (int k2 = 0; k2 < 64; k2 += 32) {
      bfrag8 ah = *(const bfrag8*)&qsh[SW(w * 16 + ar, k2 + kb)];
      bfrag8 al = *(const bfrag8*)&qsl[SW(w * 16 + ar, k2 + kb)];
      bfrag8 bh_ = *(const bfrag8*)&ksPh[SW(ct * 16 + ar, k2 + kb)];
      bfrag8 bl_ = *(const bfrag8*)&ksPl[SW(ct * 16 + ar, k2 + kb)];
      pacc[ct] = __builtin_amdgcn_mfma_f32_16x16x32_bf16(ah, bh_, pacc[ct], 0, 0, 0);
      pacc[ct] = __builtin_amdgcn_mfma_f32_16x16x32_bf16(ah, bl_, pacc[ct], 0, 0, 0);
      pacc[ct] = __builtin_amdgcn_mfma_f32_16x16x32_bf16(al, bh_, pacc[ct], 0, 0, 0);
    }
  __syncthreads();

  float rs[4] = {0.f, 0.f, 0.f, 0.f};
#pragma unroll
  for (int ct = 0; ct < 4; ++ct) {
    int tau = ct * 16 + ar;
#pragma unroll
    for (int u = 0; u < 4; ++u) {
      int t = w * 16 + (lane >> 4) * 4 + u;
      float pv = (tau <= t) ? pacc[ct][u] : 0.f;
      rs[u] += pv;
      u16 hi = f2bf(pv);
      ksPh[SW(t, tau)] = hi; ksPl[SW(t, tau)] = f2bf(pv - bf2f(hi));
    }
  }
#pragma unroll
  for (int u = 0; u < 4; ++u) {
    float vv = rs[u];
    vv += __shfl_xor(vv, 1); vv += __shfl_xor(vv, 2);
    vv += __shfl_xor(vv, 4); vv += __shfl_xor(vv, 8);
    if (ar == 0) {
      int t = w * 16 + (lane >> 4) * 4 + u;
      dinv[t] = 1.f / (r0[t] + vv);
    }
  }
  __syncthreads();

#pragma unroll
  for (int et = 0; et < 4; ++et) {
    ffrag4 oacc = ffrag4{0.f, 0.f, 0.f, 0.f};
#pragma unroll
    for (int k2 = 0; k2 < 64; k2 += 32) {
      bfrag8 ah = *(const bfrag8*)&qsh[SW(w * 16 + ar, k2 + kb)];
      bfrag8 al = *(const bfrag8*)&qsl[SW(w * 16 + ar, k2 + kb)];
      bfrag8 bh_ = *(const bfrag8*)&STh[SW(et * 16 + ar, k2 + kb)];
      bfrag8 bl_ = *(const bfrag8*)&STl[SW(et * 16 + ar, k2 + kb)];
      oacc = __builtin_amdgcn_mfma_f32_16x16x32_bf16(ah, bh_, oacc, 0, 0, 0);
      oacc = __builtin_amdgcn_mfma_f32_16x16x32_bf16(ah, bl_, oacc, 0, 0, 0);
      oacc = __builtin_amdgcn_mfma_f32_16x16x32_bf16(al, bh_, oacc, 0, 0, 0);
      bfrag8 ph = *(const bfrag8*)&ksPh[SW(w * 16 + ar, k2 + kb)];
      bfrag8 pl = *(const bfrag8*)&ksPl[SW(w * 16 + ar, k2 + kb)];
      bfrag8 vh = *(const bfrag8*)&VTh[(et * 16 + ar) * 72 + k2 + kb];
      bfrag8 vl = *(const bfrag8*)&VTl[(et * 16 + ar) * 72 + k2 + kb];
      oacc = __builtin_amdgcn_mfma_f32_16x16x32_bf16(ph, vh, oacc, 0, 0, 0);
      oacc = __builtin_amdgcn_mfma_f32_16x16x32_bf16(ph, vl, oacc, 0, 0, 0);
      oacc = __builtin_amdgcn_mfma_f32_16x16x32_bf16(pl, vh, oacc, 0, 0, 0);
    }
    int e = et * 16 + ar;
#pragma unroll
    for (int u = 0; u < 4; ++u) {
      int t = w * 16 + (lane >> 4) * 4 + u;
      attn_out[((size_t)b * Nc + c * CT + t) * DIMc + h * Ec + e] = oacc[u] * dinv[t];
    }
  }
}

// ---------------- cross-attn: ctxT[e][d] += sum_m exp(k2)[m,d] * v2[m,e]  (+colsum) ----
// Accumulates the context TRANSPOSED so it feeds attn2's MFMA B-operand directly.
__global__ __launch_bounds__(256) void ctx_kernel(const float* __restrict__ kvbuf,
    float* __restrict__ colsum, float* __restrict__ ctxT)
{
  int slab = blockIdx.x, bh = blockIdx.y;
  int b = bh >> 3, h = bh & 7;
  __shared__ float ks[64][Ec];
  __shared__ float vs[64][Ec];
  int tid = threadIdx.x;
#pragma unroll
  for (int j = 0; j < 16; ++j) {
    int i = tid + 256 * j;
    int m = i >> 6, d = i & 63;
    size_t rowbase = ((size_t)b * Mc + slab * 64 + m) * (2 * DIMc);
    ks[m][d] = __expf(kvbuf[rowbase + h * Ec + d]);
    vs[m][d] = kvbuf[rowbase + DIMc + h * Ec + d];
  }
  __syncthreads();
  int d = tid & 63, e0 = tid >> 6;   // lane owns column d; wave owns e-band
  float acc[16] = {};
  for (int m = 0; m < 64; ++m) {
    float kd = ks[m][d];
#pragma unroll
    for (int j = 0; j < 16; ++j) acc[j] += kd * vs[m][e0 + 4 * j];
  }
  size_t obase = (size_t)bh * Ec * Ec;
#pragma unroll
  for (int j = 0; j < 16; ++j)
    atomicAdd(&ctxT[obase + (size_t)(e0 + 4 * j) * Ec + d], acc[j]);  // coalesced over d
  int w = tid >> 6, lane = tid & 63;
  float s = 0;
#pragma unroll
  for (int m = 0; m < 16; ++m) s += ks[w * 16 + m][lane];
  __shared__ float p[4][Ec];
  p[w][lane] = s;
  __syncthreads();
  if (tid < Ec)
    atomicAdd(&colsum[(size_t)bh * Ec + tid], p[0][tid] + p[1][tid] + p[2][tid] + p[3][tid]);
}

// ---------------- cross-attn via MFMA: out[t,e] = (softmax(q2[t])*E^-.5) @ ctx ----
// Block = (64-token tile, bh). Normalization by colsum fused into ctxT staging.
__global__ __launch_bounds__(256) void attn2_kernel(const float* __restrict__ q2,
    const float* __restrict__ ctxT, const float* __restrict__ colsum,
    float* __restrict__ out)
{
  int tc = blockIdx.x, bh = blockIdx.y;
  int b = bh >> 3, h = bh & 7;
  __shared__ u16 qsh[64 * 64], qsl[64 * 64];   // A: qs[t][d]
  __shared__ u16 cth[64 * 64], ctl[64 * 64];   // B: ctxT[e][d] (normalized)
  int tid = threadIdx.x;
  int lane = tid & 63, w = tid >> 6;
  const int ar = lane & 15, kb = (lane >> 4) * 8;

  // stage normalized ctxT split into LDS
#pragma unroll
  for (int j = 0; j < 16; ++j) {
    int i = tid + 256 * j;
    int r = i >> 6, d = i & 63;
    float v = ctxT[(size_t)bh * Ec * Ec + i] / colsum[(size_t)bh * Ec + d];
    u16 hi = f2bf(v);
    cth[SW(r, d)] = hi; ctl[SW(r, d)] = f2bf(v - bf2f(hi));
  }
  // softmax for this wave's 16 tokens; write qs split
  for (int ti = 0; ti < 16; ++ti) {
    int t = tc * 64 + w * 16 + ti;
    float qv = q2[((size_t)b * Nc + t) * DIMc + h * Ec + lane];
    float mx = qv;
#pragma unroll
    for (int off = 1; off < 64; off <<= 1) mx = fmaxf(mx, __shfl_xor(mx, off));
    float ex = __expf(qv - mx);
    float ssum = ex;
#pragma unroll
    for (int off = 1; off < 64; off <<= 1) ssum += __shfl_xor(ssum, off);
    float qs = ex / ssum * 0.125f;
    u16 hi = f2bf(qs);
    qsh[SW(w * 16 + ti, lane)] = hi; qsl[SW(w * 16 + ti, lane)] = f2bf(qs - bf2f(hi));
  }
  __syncthreads();

#pragma unroll
  for (int et = 0; et < 4; ++et) {
    ffrag4 oacc = ffrag4{0.f, 0.f, 0.f, 0.f};
#pragma unroll
    for (int k2 = 0; k2 < 64; k2 += 32) {
      bfrag8 ah = *(const bfrag8*)&qsh[SW(w * 16 + ar, k2 + kb)];
      bfrag8 al = *(const bfrag8*)&qsl[SW(w * 16 + ar, k2 + kb)];
      bfrag8 bh_ = *(const bfrag8*)&cth[SW(et * 16 + ar, k2 + kb)];
      bfrag8 bl_ = *(const bfrag8*)&ctl[SW(et * 16 + ar, k2 + kb)];
      oacc = __builtin_amdgcn_mfma_f32_16x16x32_bf16(ah, bh_, oacc, 0, 0, 0);
      oacc = __builtin_amdgcn_mfma_f32_16x16x32_bf16(ah, bl_, oacc, 0, 0, 0);
      oacc = __builtin_amdgcn_mfma_f32_16x16x32_bf16(al, bh_, oacc, 0, 0, 0);
    }
    int e = et * 16 + ar;
#pragma unroll
    for (int u = 0; u < 4; ++u) {
      int t = tc * 64 + w * 16 + (lane >> 4) * 4 + u;
      out[((size_t)b * Nc + t) * DIMc + h * Ec + e] = oacc[u];
    }
  }
}

extern "C" void kernel_launch(void* const* d_in, const int* in_sizes, int n_in,
                              void* d_out, int out_size, void* d_ws, size_t ws_size,
                              hipStream_t stream)
{
  float* ws = (float*)d_ws;
  int* flag = (int*)ws;
  float* conv = ws + 64;

  float* cin[18];
  size_t off = 0;
  for (int i = 0; i < 18; ++i) { cin[i] = conv + off; off += (size_t)in_sizes[i]; }
  float* pipe = conv + off;

  const size_t SZ_ROW = (size_t)Bc * Nc * DIMc;            // 2,097,152
  const size_t SZ_KV  = (size_t)Bc * Mc * 2 * DIMc;        // 4,194,304
  const size_t SZ_R0  = 12582912;                          // region0 span (f-eq)

  float* region0 = pipe;
  float* qvk     = region0;                   // live: gemm1 .. causalC
  float* kvbuf   = region0;                   // live: kvGEMM .. ctx_kernel
  float* q2      = region0 + SZ_KV;           // live: q2GEMM .. attn2
  u16*   O2ff    = (u16*)region0;             // live: ff1 .. ff2 ([hi|lo], 8.39M f-eq)
  float* partials= region0 + 8388608;         // ff2 split-K partials (2 x 2.10M f)
  float* out1    = region0 + SZ_R0;           // live: LN1 .. LN2
  float* attn_o  = out1 + SZ_ROW;             // attn_o -> attn2_o -> ybuf
  float* r3      = attn_o + SZ_ROW;           // chunkKV -> pre3
  float* chunkKV = r3;
  float* pre3    = r3;
  float* chunkKs = r3 + SZ_ROW;                                   // 32768
  float* colsum  = chunkKs + (size_t)Bc * Hc * NCc * Ec;          // 1024
  float* ctx2    = colsum + (size_t)Bc * Hc * Ec;                 // 65536 (transposed)
  float* ybuf    = attn_o;
  float* attn2_o = attn_o;

  u16* B2_qvk = (u16*)(ctx2 + (size_t)Bc * Hc * Ec * Ec);
  u16* B2_kv  = B2_qvk + (size_t)(3 * DIMc) * (2 * DIMc);   // 1536 x 1024
  u16* B2_q   = B2_kv  + (size_t)(2 * DIMc) * (2 * DIMc);   // 1024 x 1024
  u16* B2_ff1 = B2_q   + (size_t)DIMc * (2 * DIMc);         // 512 x 1024
  u16* B2_ff2 = B2_ff1 + (size_t)FFc  * (2 * DIMc);         // 2048 x 1024
  u16* A2slotA = B2_ff2 + (size_t)DIMc * (2 * FFc);         // 4096 x 1024 (x / memory / ybuf)
  u16* A2slotB = A2slotA + (size_t)4096 * 1024;             // 4096 x 1024 (out1)
  (void)ws_size; (void)n_in; (void)out_size;

  dim3 blk(256);
  const int MR = Bc * Nc;  // 4096 rows

  // 0. detect input dtype; ingest ONLY what is needed in fp32.
  detect_kernel<<<dim3(1), dim3(64), 0, stream>>>(d_in[0], flag);
  ConvJobs jobs;
  for (int i = 0; i < 18; ++i) { jobs.j[i].src = d_in[i]; jobs.j[i].dst = cin[i]; jobs.j[i].n = in_sizes[i]; }
  jobs.j[1].n = 0;   // memory  -> split_act_raw reads d_in[1]
  jobs.j[2].n = 0;   // W_qvk   -> wsplit reads d_in[2]
  jobs.j[4].n = 0;   // W_kv
  jobs.j[6].n = 0;   // W_q
  jobs.j[8].n = 0;   // W_ff1
  jobs.j[10].n = 0;  // W_ff2
  ingest_kernel<<<dim3(32, 18), blk, 0, stream>>>(jobs, flag);

  const float *x = cin[0], *b_qvk = cin[3], *b_kv = cin[5], *b_q = cin[7],
              *b_ff1 = cin[9], *b_ff2 = cin[11],
              *ln1_g = cin[12], *ln1_b = cin[13], *ln2_g = cin[14], *ln2_b = cin[15],
              *ln3_g = cin[16], *ln3_b = cin[17];

  // 0b. weight transpose+split straight from d_in (dtype-aware)
  wsplit_kernel<<<dim3(24, 8), blk, 0, stream>>>(d_in[2],  flag, B2_qvk, DIMc, 3 * DIMc);
  wsplit_kernel<<<dim3(16, 8), blk, 0, stream>>>(d_in[4],  flag, B2_kv,  DIMc, 2 * DIMc);
  wsplit_kernel<<<dim3(8, 8),  blk, 0, stream>>>(d_in[6],  flag, B2_q,   DIMc, DIMc);
  wsplit_kernel<<<dim3(32, 8), blk, 0, stream>>>(d_in[8],  flag, B2_ff1, DIMc, FFc);
  wsplit_kernel<<<dim3(8, 32), blk, 0, stream>>>(d_in[10], flag, B2_ff2, FFc,  DIMc);

  // 1. qvk = x @ W_qvk + b   (x split read raw from d_in[0])
  split_act_raw<<<dim3(1024), blk, 0, stream>>>(d_in[0], flag, A2slotA, 9, (int)SZ_ROW);
  gemm_mfma<128, 128, 1, 0, false, false><<<dim3(12, 32), blk, 0, stream>>>(
      A2slotA, B2_qvk, b_qvk, nullptr, qvk, nullptr, 3 * DIMc, DIMc);
  // 2. causal linear self-attention
  causalA<<<dim3(NCc, Bc * Hc), blk, 0, stream>>>(qvk, chunkKV, chunkKs);
  causalB<<<dim3(16, 17), blk, 0, stream>>>(chunkKV, chunkKs);
  causalC<<<dim3(NCc, Bc * Hc), blk, 0, stream>>>(qvk, chunkKV, chunkKs, attn_o);
  // 3. LN1(attn + x) -> out1 fp32 + split into slotB (q2 GEMM A)
  ln_kernel<true, false, true><<<dim3(MR), blk, 0, stream>>>(
      attn_o, x, ln1_g, ln1_b, out1, A2slotB, flag);
  // 4. kv = memory @ W_kv + b (memory split read raw); q2 = out1 @ W_q + b
  split_act_raw<<<dim3(1024), blk, 0, stream>>>(d_in[1], flag, A2slotA, 9, (int)SZ_ROW);
  gemm_mfma<128, 128, 1, 0, false, false><<<dim3(8, 32), blk, 0, stream>>>(
      A2slotA, B2_kv, b_kv, nullptr, kvbuf, nullptr, 2 * DIMc, DIMc);
  gemm_mfma<128, 64, 1, 0, false, false><<<dim3(8, 32), blk, 0, stream>>>(
      A2slotB, B2_q, b_q, nullptr, q2, nullptr, DIMc, DIMc);
  // 5. cross linear attention (ctx transposed; normalize fused into attn2 staging)
  hipMemsetAsync(colsum, 0,
      ((size_t)Bc * Hc * Ec + (size_t)Bc * Hc * Ec * Ec) * sizeof(float), stream);
  ctx_kernel<<<dim3(Mc / 64, Bc * Hc), blk, 0, stream>>>(kvbuf, colsum, ctx2);
  attn2_kernel<<<dim3(Nc / 64, Bc * Hc), blk, 0, stream>>>(q2, ctx2, colsum, attn2_o);
  // 6. LN2(attn2 + out1) in-place -> ybuf fp32 + split into slotA (ff1 A)
  ln_kernel<true, false, true><<<dim3(MR), blk, 0, stream>>>(
      attn2_o, out1, ln2_g, ln2_b, ybuf, A2slotA, flag);
  // 7. FF: ff1 writes [hi|lo] split directly; ff2 split-K=2 + reduce(bias+res)
  gemm_mfma<128, 128, 1, 1, true, false><<<dim3(16, 32), blk, 0, stream>>>(
      A2slotA, B2_ff1, b_ff1, nullptr, nullptr, O2ff, FFc, DIMc);
  gemm_mfma<128, 64, 2, 2, false, false><<<dim3(8, 32, 2), blk, 0, stream>>>(
      O2ff, B2_ff2, b_ff2, nullptr, partials, nullptr, DIMc, FFc);
  reduce2<<<dim3(2048), blk, 0, stream>>>(partials, b_ff2, ybuf, pre3);
  // 8. LN3 -> d_out (bf16 or fp32 per flag)
  ln_kernel<false, true, false><<<dim3(MR), blk, 0, stream>>>(
      pre3, nullptr, ln3_g, ln3_b, d_out, nullptr, flag);
}

// Round 7
// 367.822 us; speedup vs baseline: 3.3952x; 1.1159x over previous
//
#include <hip/hip_runtime.h>
#include <hip/hip_bf16.h>

#define DEV __device__ __forceinline__

constexpr int Bc = 2, Nc = 2048, Mc = 2048, DIMc = 512, Hc = 8, FFc = 2048, Ec = 64;
constexpr int CT = 64;            // causal chunk length (tokens)
constexpr int NCc = Nc / CT;      // 32 chunks per sequence
constexpr float LN_EPS = 1e-5f, ATTN_EPS = 1e-6f;

typedef __bf16 bfrag8 __attribute__((ext_vector_type(8)));
typedef float ffrag4 __attribute__((ext_vector_type(4)));
typedef unsigned short u16;

// ---------------- helpers ----------------
DEV u16 f2bf(float v) {
  __hip_bfloat16 h = __float2bfloat16(v);   // RTN-even
  return __builtin_bit_cast(unsigned short, h);
}
DEV float bf2f(u16 u) { return __uint_as_float(((unsigned)u) << 16); }

DEV void gload16(const void* g, void* l) {
  __builtin_amdgcn_global_load_lds(
      (const __attribute__((address_space(1))) void*)g,
      (__attribute__((address_space(3))) void*)l, 16, 0, 0);
}

// XOR swizzle for [64][64] u16 LDS tiles (row stride 128B).
DEV int SW(int r, int c) { return r * 64 + (c ^ ((r & 7) << 3)); }

// ---------------- dtype detection ----------------
__global__ __launch_bounds__(64) void detect_kernel(const void* x, int* flag) {
  const unsigned short* u = (const unsigned short*)x;
  int tid = threadIdx.x;
  int bad = 0;
#pragma unroll
  for (int i = 0; i < 8; ++i) {
    float v = __uint_as_float(((unsigned)u[tid * 8 + i]) << 16);
    if (!(fabsf(v) <= 1e4f)) bad = 1;   // catches NaN, Inf, garbage
  }
  unsigned long long m = __ballot(bad);
  if (tid == 0) *flag = (m == 0ull) ? 1 : 0;  // 1 = inputs are bf16
}

// ---------------- ingest (vectorized, only for arrays needed in fp32) ----------------
struct ConvJob { const void* src; float* dst; int n; };
struct ConvJobs { ConvJob j[18]; };

__global__ __launch_bounds__(256) void ingest_kernel(ConvJobs jobs, const int* flag) {
  int bf = *flag;
  ConvJob jb = jobs.j[blockIdx.y];
  int n8 = jb.n >> 3;
  int stride = gridDim.x * 256;
  for (int i = blockIdx.x * 256 + threadIdx.x; i < n8; i += stride) {
    float o[8];
    if (bf) {
      uint4 a = ((const uint4*)jb.src)[i];
      unsigned w[4] = {a.x, a.y, a.z, a.w};
#pragma unroll
      for (int j = 0; j < 4; ++j) {
        o[2 * j]     = bf2f((u16)(w[j] & 0xffff));
        o[2 * j + 1] = bf2f((u16)(w[j] >> 16));
      }
    } else {
      float4 a = ((const float4*)jb.src)[2 * i];
      float4 b = ((const float4*)jb.src)[2 * i + 1];
      o[0] = a.x; o[1] = a.y; o[2] = a.z; o[3] = a.w;
      o[4] = b.x; o[5] = b.y; o[6] = b.z; o[7] = b.w;
    }
    float4* d = (float4*)jb.dst;
    d[2 * i]     = float4{o[0], o[1], o[2], o[3]};
    d[2 * i + 1] = float4{o[4], o[5], o[6], o[7]};
  }
}

// ---------------- raw input -> 2-term bf16 split [hi|lo] (dtype-aware) ----------------
__global__ __launch_bounds__(256) void split_act_raw(const void* __restrict__ in,
    const int* __restrict__ flag, u16* __restrict__ out, int kshift, int total)
{
  int bf = *flag;
  const int K = 1 << kshift;
  int n8 = total >> 3;
  int stride = gridDim.x * 256;
  for (int ii = blockIdx.x * 256 + threadIdx.x; ii < n8; ii += stride) {
    int i = ii * 8;
    float v[8];
    if (bf) {
      uint4 a = ((const uint4*)in)[ii];
      unsigned w[4] = {a.x, a.y, a.z, a.w};
#pragma unroll
      for (int j = 0; j < 4; ++j) {
        v[2 * j]     = bf2f((u16)(w[j] & 0xffff));
        v[2 * j + 1] = bf2f((u16)(w[j] >> 16));
      }
    } else {
      float4 a = ((const float4*)in)[2 * ii];
      float4 b = ((const float4*)in)[2 * ii + 1];
      v[0] = a.x; v[1] = a.y; v[2] = a.z; v[3] = a.w;
      v[4] = b.x; v[5] = b.y; v[6] = b.z; v[7] = b.w;
    }
    unsigned hw[4], lw[4];
#pragma unroll
    for (int j = 0; j < 4; ++j) {
      u16 h0 = f2bf(v[2 * j]),     l0 = f2bf(v[2 * j]     - bf2f(f2bf(v[2 * j])));
      u16 h1 = f2bf(v[2 * j + 1]), l1 = f2bf(v[2 * j + 1] - bf2f(f2bf(v[2 * j + 1])));
      hw[j] = (unsigned)h0 | ((unsigned)h1 << 16);
      lw[j] = (unsigned)l0 | ((unsigned)l1 << 16);
    }
    int row = i >> kshift, k = i & (K - 1);
    size_t rb = (size_t)row * 2 * K + k;
    *(uint4*)&out[rb]     = uint4{hw[0], hw[1], hw[2], hw[3]};
    *(uint4*)&out[rb + K] = uint4{lw[0], lw[1], lw[2], lw[3]};
  }
}

// ---------------- batched W (KxN raw) -> B2t (N x 2K bf16) transpose+split ----------
struct WJob { const void* src; u16* dst; int K; int N; int tx; int base; };
struct WJobs { WJob j[5]; };

__global__ __launch_bounds__(256) void wsplit_batch(WJobs jobs, const int* flag) {
  int bf = *flag;
  int flat = blockIdx.x;
  int ji = 0;
#pragma unroll
  for (int t = 1; t < 5; ++t) if (flat >= jobs.j[t].base) ji = t;
  WJob jb = jobs.j[ji];
  int tti = flat - jb.base;
  int bx = tti % jb.tx, by = tti / jb.tx;
  const int K = jb.K, N = jb.N;
  const void* W = jb.src;
  u16* B2t = jb.dst;
  __shared__ float T[64][65];
  int n0 = bx * 64, k0 = by * 64;
  int tid = threadIdx.x;
#pragma unroll
  for (int j = 0; j < 16; ++j) {
    int idx = tid + 256 * j;
    int kl = idx >> 6, nl = idx & 63;
    size_t gi = (size_t)(k0 + kl) * N + n0 + nl;
    T[kl][nl] = bf ? bf2f(((const u16*)W)[gi]) : ((const float*)W)[gi];
  }
  __syncthreads();
#pragma unroll
  for (int j = 0; j < 16; ++j) {
    int idx = tid + 256 * j;
    int nl = idx >> 6, kl = idx & 63;
    float v = T[kl][nl];
    u16 hi = f2bf(v);
    u16 lo = f2bf(v - bf2f(hi));
    size_t rb = (size_t)(n0 + nl) * 2 * K + k0 + kl;
    B2t[rb]     = hi;
    B2t[rb + K] = lo;
  }
}

// ---------------- MFMA GEMM: C[M,N] = A2[M,2K] @ B2t[N,2K]^T ----------------
// 2-term split operands [hi|lo]; per k-step issues Ah*Bh + Ah*Bl + Al*Bh.
// Bijective XCD swizzle. OUTMODE 0: fp32 C (+bias)(+res)(relu). OUTMODE 1: split
// [hi|lo] bf16 out (row 2N). OUTMODE 2: raw fp32 partial (split-K).
template<int BM, int BN, int SPLITK, int OUTMODE, bool RELU, bool ADD_RES>
__global__ __launch_bounds__(256) void gemm_mfma(
    const u16* __restrict__ A2, const u16* __restrict__ B2t,
    const float* __restrict__ bias, const float* __restrict__ res,
    float* __restrict__ Cf, u16* __restrict__ C2,
    int N, int K)
{
  constexpr int WM = BM / 2, WN = BN / 2, FM = WM / 16, FN = WN / 16;
  __shared__ u16 Ash[BM][32], Asl[BM][32];
  __shared__ u16 Bsh[BN][32], Bsl[BN][32];
  const int tid = threadIdx.x;
  const int lane = tid & 63, wid = tid >> 6;
  const int wr = wid >> 1, wc = wid & 1;
  const int gx = gridDim.x, gy = gridDim.y;
  const int nwg = gx * gy * gridDim.z;
  const int flat = (blockIdx.z * gy + blockIdx.y) * gx + blockIdx.x;
  const int v = (flat & 7) * (nwg >> 3) + (flat >> 3);
  const int bx = v % gx;
  const int rest = v / gx;
  const int by = rest % gy;
  const int bz = rest / gy;
  const int row0 = by * BM, col0 = bx * BN;
  const int Mtot = gy * BM;
  const int sr = lane >> 2, sk = (lane & 3) * 8;
  const int ar = lane & 15, kb = (lane >> 4) * 8;
  const size_t strA = (size_t)2 * K;

  ffrag4 acc[FM][FN];
#pragma unroll
  for (int m = 0; m < FM; ++m)
#pragma unroll
    for (int n = 0; n < FN; ++n) acc[m][n] = ffrag4{0.f, 0.f, 0.f, 0.f};

  const int Kseg = K / SPLITK;
  const int kbeg = bz * Kseg;
  for (int k0 = kbeg; k0 < kbeg + Kseg; k0 += 32) {
    for (int r = wid; r < BM / 16; r += 4) {
      gload16(&A2[(size_t)(row0 + r * 16 + sr) * strA + k0 + sk],     &Ash[r * 16][0]);
      gload16(&A2[(size_t)(row0 + r * 16 + sr) * strA + K + k0 + sk], &Asl[r * 16][0]);
    }
    for (int r = wid; r < BN / 16; r += 4) {
      gload16(&B2t[(size_t)(col0 + r * 16 + sr) * strA + k0 + sk],     &Bsh[r * 16][0]);
      gload16(&B2t[(size_t)(col0 + r * 16 + sr) * strA + K + k0 + sk], &Bsl[r * 16][0]);
    }
    __syncthreads();

    bfrag8 afh[FM], afl[FM], bwh[FN], bwl[FN];
#pragma unroll
    for (int m = 0; m < FM; ++m) {
      afh[m] = *(const bfrag8*)&Ash[wr * WM + m * 16 + ar][kb];
      afl[m] = *(const bfrag8*)&Asl[wr * WM + m * 16 + ar][kb];
    }
#pragma unroll
    for (int n = 0; n < FN; ++n) {
      bwh[n] = *(const bfrag8*)&Bsh[wc * WN + n * 16 + ar][kb];
      bwl[n] = *(const bfrag8*)&Bsl[wc * WN + n * 16 + ar][kb];
    }
#pragma unroll
    for (int m = 0; m < FM; ++m)
#pragma unroll
      for (int n = 0; n < FN; ++n) {
        acc[m][n] = __builtin_amdgcn_mfma_f32_16x16x32_bf16(afh[m], bwh[n], acc[m][n], 0, 0, 0);
        acc[m][n] = __builtin_amdgcn_mfma_f32_16x16x32_bf16(afh[m], bwl[n], acc[m][n], 0, 0, 0);
        acc[m][n] = __builtin_amdgcn_mfma_f32_16x16x32_bf16(afl[m], bwh[n], acc[m][n], 0, 0, 0);
      }
    __syncthreads();
  }

#pragma unroll
  for (int m = 0; m < FM; ++m) {
    int rbase = row0 + wr * WM + m * 16 + (lane >> 4) * 4;
#pragma unroll
    for (int n = 0; n < FN; ++n) {
      int col = col0 + wc * WN + n * 16 + ar;
#pragma unroll
      for (int u = 0; u < 4; ++u) {
        int row = rbase + u;
        float val = acc[m][n][u];
        if constexpr (OUTMODE == 2) {
          Cf[((size_t)bz * Mtot + row) * N + col] = val;
        } else {
          val += bias[col];
          if (ADD_RES) val += res[(size_t)row * N + col];
          if (RELU) val = fmaxf(val, 0.f);
          if constexpr (OUTMODE == 0) {
            Cf[(size_t)row * N + col] = val;
          } else {
            u16 hi = f2bf(val);
            u16 lo = f2bf(val - bf2f(hi));
            size_t rb = (size_t)row * 2 * N;
            C2[rb + col]     = hi;
            C2[rb + N + col] = lo;
          }
        }
      }
    }
  }
}

// ---------------- split-K reduce: out = sum_p part[p] + bias (+res) --------------
// Shapes here are always M*N = 2,097,152 with N = 512.
template<int P, bool ADD_RES>
__global__ __launch_bounds__(256) void reduceK(const float* __restrict__ part,
    const float* __restrict__ bias, const float* __restrict__ res,
    float* __restrict__ out)
{
  size_t i = ((size_t)blockIdx.x * 256 + threadIdx.x) * 4;
  float4 o = *(const float4*)&part[i];
#pragma unroll
  for (int p = 1; p < P; ++p) {
    float4 a = *(const float4*)&part[(size_t)p * 2097152 + i];
    o.x += a.x; o.y += a.y; o.z += a.z; o.w += a.w;
  }
  int col = (int)(i & 511);
  o.x += bias[col]; o.y += bias[col + 1]; o.z += bias[col + 2]; o.w += bias[col + 3];
  if (ADD_RES) {
    float4 r = *(const float4*)&res[i];
    o.x += r.x; o.y += r.y; o.z += r.z; o.w += r.w;
  }
  *(float4*)&out[i] = o;
}

// ---------------- layernorm over last dim (512), optional residual ----------------
// OUTSPLIT: also emit [hi|lo] bf16 split rows (len 1024) for the next GEMM's A.
template<bool HAS_RES, bool FINAL, bool OUTSPLIT>
__global__ __launch_bounds__(256) void ln_kernel(
    const float* __restrict__ in, const float* __restrict__ res,
    const float* __restrict__ g, const float* __restrict__ b,
    void* __restrict__ out, u16* __restrict__ out2, const int* __restrict__ flag)
{
  int row = blockIdx.x, tid = threadIdx.x;
  size_t base = (size_t)row * DIMc;
  float x0 = in[base + tid], x1 = in[base + tid + 256];
  if (HAS_RES) { x0 += res[base + tid]; x1 += res[base + tid + 256]; }
  float s1 = x0 + x1, s2 = x0 * x0 + x1 * x1;
#pragma unroll
  for (int off = 1; off < 64; off <<= 1) { s1 += __shfl_xor(s1, off); s2 += __shfl_xor(s2, off); }
  __shared__ float p1[4], p2[4], stat[2];
  if ((tid & 63) == 0) { p1[tid >> 6] = s1; p2[tid >> 6] = s2; }
  __syncthreads();
  if (tid == 0) {
    float t1 = p1[0] + p1[1] + p1[2] + p1[3];
    float t2 = p2[0] + p2[1] + p2[2] + p2[3];
    float mu = t1 / DIMc;
    float var = t2 / DIMc - mu * mu;
    stat[0] = mu; stat[1] = rsqrtf(var + LN_EPS);
  }
  __syncthreads();
  float mu = stat[0], rv = stat[1];
  float y0 = (x0 - mu) * rv * g[tid] + b[tid];
  float y1 = (x1 - mu) * rv * g[tid + 256] + b[tid + 256];
  if (FINAL) {
    if (*flag) {
      __hip_bfloat16* o = (__hip_bfloat16*)out;
      o[base + tid] = __float2bfloat16(y0);
      o[base + tid + 256] = __float2bfloat16(y1);
    } else {
      float* o = (float*)out;
      o[base + tid] = y0;
      o[base + tid + 256] = y1;
    }
  } else {
    float* o = (float*)out;
    o[base + tid] = y0;
    o[base + tid + 256] = y1;
  }
  if (OUTSPLIT) {
    size_t rb = (size_t)row * 1024;
    u16 h0 = f2bf(y0);
    out2[rb + tid] = h0;
    out2[rb + 512 + tid] = f2bf(y0 - bf2f(h0));
    u16 h1 = f2bf(y1);
    out2[rb + tid + 256] = h1;
    out2[rb + 512 + tid + 256] = f2bf(y1 - bf2f(h1));
  }
}

// ---------------- causal linear attention, pass A: per-chunk KV sums ----------------
// Writes chunkKV TRANSPOSED: chunkKVT[e][d] = sum_t ks[t][d]*vs[t][e]
__global__ __launch_bounds__(256) void causalA(const float* __restrict__ qvk,
    float* __restrict__ chunkKVT, float* __restrict__ chunkKs)
{
  int c = blockIdx.x, bh = blockIdx.y;
  int b = bh >> 3, h = bh & 7;
  __shared__ float ks[CT][Ec];
  __shared__ float vs[CT][Ec];
  int tid = threadIdx.x;
#pragma unroll
  for (int j = 0; j < 16; ++j) {
    int i = tid + 256 * j;
    int t = i >> 6, d = i & 63;
    size_t rowbase = ((size_t)b * Nc + c * CT + t) * (3 * DIMc);
    ks[t][d] = __expf(qvk[rowbase + 2 * DIMc + h * Ec + d]);
    vs[t][d] = qvk[rowbase + DIMc + h * Ec + d];
  }
  __syncthreads();
  int e = tid & 63, d0 = tid >> 6;
  float acc[16] = {};
  for (int t = 0; t < CT; ++t) {
    float ve = vs[t][e];
#pragma unroll
    for (int j = 0; j < 16; ++j) acc[j] += ks[t][d0 + 4 * j] * ve;
  }
  size_t obase = ((size_t)bh * NCc + c) * (Ec * Ec);
#pragma unroll
  for (int j = 0; j < 16; ++j) chunkKVT[obase + (size_t)e * Ec + (d0 + 4 * j)] = acc[j];
  if (tid < Ec) {
    float s = 0;
    for (int t = 0; t < CT; ++t) s += ks[t][tid];
    chunkKs[((size_t)bh * NCc + c) * Ec + tid] = s;
  }
}

// ---------------- pass B: exclusive prefix over chunks (parallelized) ----------------
__global__ __launch_bounds__(256) void causalB(float* __restrict__ chunkKV,
                                               float* __restrict__ chunkKs)
{
  int bh = blockIdx.x, grp = blockIdx.y, tid = threadIdx.x;
  if (grp < 16) {
    int idx = grp * 256 + tid;
    float run = 0;
    size_t base = (size_t)bh * NCc * Ec * Ec + idx;
#pragma unroll
    for (int c = 0; c < NCc; ++c) {
      float t = chunkKV[base + (size_t)c * Ec * Ec];
      chunkKV[base + (size_t)c * Ec * Ec] = run;
      run += t;
    }
  } else if (tid < Ec) {
    float run = 0;
    size_t base = (size_t)bh * NCc * Ec + tid;
#pragma unroll
    for (int c = 0; c < NCc; ++c) {
      float t = chunkKs[base + (size_t)c * Ec];
      chunkKs[base + (size_t)c * Ec] = run;
      run += t;
    }
  }
}

// ---------------- pass C: per-token outputs via MFMA ----------------
__global__ __launch_bounds__(256) void causalC(const float* __restrict__ qvk,
    const float* __restrict__ chunkKVT, const float* __restrict__ chunkKs,
    float* __restrict__ attn_out)
{
  int c = blockIdx.x, bh = blockIdx.y;
  int b = bh >> 3, h = bh & 7;
  __shared__ u16 qsh[64 * 64], qsl[64 * 64];   // A: qs[t][d]
  __shared__ u16 ksPh[64 * 64], ksPl[64 * 64]; // B: ks[tau][d]  ->  A: Pm[t][tau]
  __shared__ u16 STh[64 * 64], STl[64 * 64];   // B: S^T[e][d]
  __shared__ u16 VTh[64 * 72], VTl[64 * 72];   // B: V^T[e][tau], pad 72
  __shared__ float kpre[Ec], r0[CT], dinv[CT];
  int tid = threadIdx.x;
  int lane = tid & 63, w = tid >> 6;
  const int ar = lane & 15, kb = (lane >> 4) * 8;
  size_t kvb = (size_t)bh * NCc + c;

  if (tid < Ec) kpre[tid] = chunkKs[kvb * Ec + tid] + ATTN_EPS;

  float qreg[16];
#pragma unroll
  for (int j = 0; j < 16; ++j) {
    int t = w * 16 + j, d = lane;
    size_t rowbase = ((size_t)b * Nc + c * CT + t) * (3 * DIMc);
    qreg[j] = qvk[rowbase + h * Ec + d];
    float kv = __expf(qvk[rowbase + 2 * DIMc + h * Ec + d]);
    u16 hi = f2bf(kv);
    ksPh[SW(t, d)] = hi; ksPl[SW(t, d)] = f2bf(kv - bf2f(hi));
    float vv = qvk[rowbase + DIMc + h * Ec + d];
    hi = f2bf(vv);
    VTh[d * 72 + t] = hi; VTl[d * 72 + t] = f2bf(vv - bf2f(hi));
    float sv = chunkKVT[kvb * (Ec * Ec) + (size_t)t * Ec + d];  // row e=t of S^T
    hi = f2bf(sv);
    STh[SW(t, d)] = hi; STl[SW(t, d)] = f2bf(sv - bf2f(hi));
  }
  __syncthreads();

  for (int ti = 0; ti < 16; ++ti) {
    int t = w * 16 + ti;
    float qv = qreg[ti];
    float mx = qv;
#pragma unroll
    for (int off = 1; off < 64; off <<= 1) mx = fmaxf(mx, __shfl_xor(mx, off));
    float ex = __expf(qv - mx);
    float ssum = ex;
#pragma unroll
    for (int off = 1; off < 64; off <<= 1) ssum += __shfl_xor(ssum, off);
    float qs = ex / ssum * 0.125f;
    float qk = qs * kpre[lane];
#pragma unroll
    for (int off = 1; off < 64; off <<= 1) qk += __shfl_xor(qk, off);
    if (lane == 0) r0[t] = qk;
    u16 hi = f2bf(qs);
    qsh[SW(t, lane)] = hi; qsl[SW(t, lane)] = f2bf(qs - bf2f(hi));
  }
  __syncthreads();

  ffrag4 pacc[4];
#pragma unroll
  for (int ct = 0; ct < 4; ++ct) pacc[ct] = ffrag4{0.f, 0.f, 0.f, 0.f};
#pragma unroll
  for (int ct = 0; ct < 4; ++ct)
#pragma unroll
    for (int k2 = 0; k2 < 64; k2 += 32) {
      bfrag8 ah = *(const bfrag8*)&qsh[SW(w * 16 + ar, k2 + kb)];
      bfrag8 al = *(const bfrag8*)&qsl[SW(w * 16 + ar, k2 + kb)];
      bfrag8 bh_ = *(const bfrag8*)&ksPh[SW(ct * 16 + ar, k2 + kb)];
      bfrag8 bl_ = *(const bfrag8*)&ksPl[SW(ct * 16 + ar, k2 + kb)];
      pacc[ct] = __builtin_amdgcn_mfma_f32_16x16x32_bf16(ah, bh_, pacc[ct], 0, 0, 0);
      pacc[ct] = __builtin_amdgcn_mfma_f32_16x16x32_bf16(ah, bl_, pacc[ct], 0, 0, 0);
      pacc[ct] = __builtin_amdgcn_mfma_f32_16x16x32_bf16(al, bh_, pacc[ct], 0, 0, 0);
    }
  __syncthreads();

  float rs[4] = {0.f, 0.f, 0.f, 0.f};
#pragma unroll
  for (int ct = 0; ct < 4; ++ct) {
    int tau = ct * 16 + ar;
#pragma unroll
    for (int u = 0; u < 4; ++u) {
      int t = w * 16 + (lane >> 4) * 4 + u;
      float pv = (tau <= t) ? pacc[ct][u] : 0.f;
      rs[u] += pv;
      u16 hi = f2bf(pv);
      ksPh[SW(t, tau)] = hi; ksPl[SW(t, tau)] = f2bf(pv - bf2f(hi));
    }
  }
#pragma unroll
  for (int u = 0; u < 4; ++u) {
    float vv = rs[u];
    vv += __shfl_xor(vv, 1); vv += __shfl_xor(vv, 2);
    vv += __shfl_xor(vv, 4); vv += __shfl_xor(vv, 8);
    if (ar == 0) {
      int t = w * 16 + (lane >> 4) * 4 + u;
      dinv[t] = 1.f / (r0[t] + vv);
    }
  }
  __syncthreads();

#pragma unroll
  for (int et = 0; et < 4; ++et) {
    ffrag4 oacc = ffrag4{0.f, 0.f, 0.f, 0.f};
#pragma unroll
    for (int k2 = 0; k2 < 64; k2 += 32) {
      bfrag8 ah = *(const bfrag8*)&qsh[SW(w * 16 + ar, k2 + kb)];
      bfrag8 al = *(const bfrag8*)&qsl[SW(w * 16 + ar, k2 + kb)];
      bfrag8 bh_ = *(const bfrag8*)&STh[SW(et * 16 + ar, k2 + kb)];
      bfrag8 bl_ = *(const bfrag8*)&STl[SW(et * 16 + ar, k2 + kb)];
      oacc = __builtin_amdgcn_mfma_f32_16x16x32_bf16(ah, bh_, oacc, 0, 0, 0);
      oacc = __builtin_amdgcn_mfma_f32_16x16x32_bf16(ah, bl_, oacc, 0, 0, 0);
      oacc = __builtin_amdgcn_mfma_f32_16x16x32_bf16(al, bh_, oacc, 0, 0, 0);
      bfrag8 ph = *(const bfrag8*)&ksPh[SW(w * 16 + ar, k2 + kb)];
      bfrag8 pl = *(const bfrag8*)&ksPl[SW(w * 16 + ar, k2 + kb)];
      bfrag8 vh = *(const bfrag8*)&VTh[(et * 16 + ar) * 72 + k2 + kb];
      bfrag8 vl = *(const bfrag8*)&VTl[(et * 16 + ar) * 72 + k2 + kb];
      oacc = __builtin_amdgcn_mfma_f32_16x16x32_bf16(ph, vh, oacc, 0, 0, 0);
      oacc = __builtin_amdgcn_mfma_f32_16x16x32_bf16(ph, vl, oacc, 0, 0, 0);
      oacc = __builtin_amdgcn_mfma_f32_16x16x32_bf16(pl, vh, oacc, 0, 0, 0);
    }
    int e = et * 16 + ar;
#pragma unroll
    for (int u = 0; u < 4; ++u) {
      int t = w * 16 + (lane >> 4) * 4 + u;
      attn_out[((size_t)b * Nc + c * CT + t) * DIMc + h * Ec + e] = oacc[u] * dinv[t];
    }
  }
}

// ---------------- cross-attn: ctxT[e][d] += sum_m exp(k2)[m,d] * v2[m,e]  (+colsum) ----
__global__ __launch_bounds__(256) void ctx_kernel(const float* __restrict__ kvbuf,
    float* __restrict__ colsum, float* __restrict__ ctxT)
{
  int slab = blockIdx.x, bh = blockIdx.y;
  int b = bh >> 3, h = bh & 7;
  __shared__ float ks[64][Ec];
  __shared__ float vs[64][Ec];
  int tid = threadIdx.x;
#pragma unroll
  for (int j = 0; j < 16; ++j) {
    int i = tid + 256 * j;
    int m = i >> 6, d = i & 63;
    size_t rowbase = ((size_t)b * Mc + slab * 64 + m) * (2 * DIMc);
    ks[m][d] = __expf(kvbuf[rowbase + h * Ec + d]);
    vs[m][d] = kvbuf[rowbase + DIMc + h * Ec + d];
  }
  __syncthreads();
  int d = tid & 63, e0 = tid >> 6;   // lane owns column d; wave owns e-band
  float acc[16] = {};
  for (int m = 0; m < 64; ++m) {
    float kd = ks[m][d];
#pragma unroll
    for (int j = 0; j < 16; ++j) acc[j] += kd * vs[m][e0 + 4 * j];
  }
  size_t obase = (size_t)bh * Ec * Ec;
#pragma unroll
  for (int j = 0; j < 16; ++j)
    atomicAdd(&ctxT[obase + (size_t)(e0 + 4 * j) * Ec + d], acc[j]);  // coalesced over d
  int w = tid >> 6, lane = tid & 63;
  float s = 0;
#pragma unroll
  for (int m = 0; m < 16; ++m) s += ks[w * 16 + m][lane];
  __shared__ float p[4][Ec];
  p[w][lane] = s;
  __syncthreads();
  if (tid < Ec)
    atomicAdd(&colsum[(size_t)bh * Ec + tid], p[0][tid] + p[1][tid] + p[2][tid] + p[3][tid]);
}

// ---------------- cross-attn via MFMA: out[t,e] = (softmax(q2[t])*E^-.5) @ ctx ----
__global__ __launch_bounds__(256) void attn2_kernel(const float* __restrict__ q2,
    const float* __restrict__ ctxT, const float* __restrict__ colsum,
    float* __restrict__ out)
{
  int tc = blockIdx.x, bh = blockIdx.y;
  int b = bh >> 3, h = bh & 7;
  __shared__ u16 qsh[64 * 64], qsl[64 * 64];   // A: qs[t][d]
  __shared__ u16 cth[64 * 64], ctl[64 * 64];   // B: ctxT[e][d] (normalized)
  int tid = threadIdx.x;
  int lane = tid & 63, w = tid >> 6;
  const int ar = lane & 15, kb = (lane >> 4) * 8;

  // stage normalized ctxT split into LDS
#pragma unroll
  for (int j = 0; j < 16; ++j) {
    int i = tid + 256 * j;
    int r = i >> 6, d = i & 63;
    float v = ctxT[(size_t)bh * Ec * Ec + i] / colsum[(size_t)bh * Ec + d];
    u16 hi = f2bf(v);
    cth[SW(r, d)] = hi; ctl[SW(r, d)] = f2bf(v - bf2f(hi));
  }
  // softmax for this wave's 16 tokens; write qs split
  for (int ti = 0; ti < 16; ++ti) {
    int t = tc * 64 + w * 16 + ti;
    float qv = q2[((size_t)b * Nc + t) * DIMc + h * Ec + lane];
    float mx = qv;
#pragma unroll
    for (int off = 1; off < 64; off <<= 1) mx = fmaxf(mx, __shfl_xor(mx, off));
    float ex = __expf(qv - mx);
    float ssum = ex;
#pragma unroll
    for (int off = 1; off < 64; off <<= 1) ssum += __shfl_xor(ssum, off);
    float qs = ex / ssum * 0.125f;
    u16 hi = f2bf(qs);
    qsh[SW(w * 16 + ti, lane)] = hi; qsl[SW(w * 16 + ti, lane)] = f2bf(qs - bf2f(hi));
  }
  __syncthreads();

#pragma unroll
  for (int et = 0; et < 4; ++et) {
    ffrag4 oacc = ffrag4{0.f, 0.f, 0.f, 0.f};
#pragma unroll
    for (int k2 = 0; k2 < 64; k2 += 32) {
      bfrag8 ah = *(const bfrag8*)&qsh[SW(w * 16 + ar, k2 + kb)];
      bfrag8 al = *(const bfrag8*)&qsl[SW(w * 16 + ar, k2 + kb)];
      bfrag8 bh_ = *(const bfrag8*)&cth[SW(et * 16 + ar, k2 + kb)];
      bfrag8 bl_ = *(const bfrag8*)&ctl[SW(et * 16 + ar, k2 + kb)];
      oacc = __builtin_amdgcn_mfma_f32_16x16x32_bf16(ah, bh_, oacc, 0, 0, 0);
      oacc = __builtin_amdgcn_mfma_f32_16x16x32_bf16(ah, bl_, oacc, 0, 0, 0);
      oacc = __builtin_amdgcn_mfma_f32_16x16x32_bf16(al, bh_, oacc, 0, 0, 0);
    }
    int e = et * 16 + ar;
#pragma unroll
    for (int u = 0; u < 4; ++u) {
      int t = tc * 64 + w * 16 + (lane >> 4) * 4 + u;
      out[((size_t)b * Nc + t) * DIMc + h * Ec + e] = oacc[u];
    }
  }
}

extern "C" void kernel_launch(void* const* d_in, const int* in_sizes, int n_in,
                              void* d_out, int out_size, void* d_ws, size_t ws_size,
                              hipStream_t stream)
{
  float* ws = (float*)d_ws;
  int* flag = (int*)ws;
  float* conv = ws + 64;

  float* cin[18];
  size_t off = 0;
  for (int i = 0; i < 18; ++i) { cin[i] = conv + off; off += (size_t)in_sizes[i]; }
  float* pipe = conv + off;

  const size_t SZ_ROW = (size_t)Bc * Nc * DIMc;            // 2,097,152
  const size_t SZ_KV  = (size_t)Bc * Mc * 2 * DIMc;        // 4,194,304
  const size_t SZ_R0  = 12582912;                          // region0 span (f-eq)

  float* region0 = pipe;
  float* qvk     = region0;                   // live: gemm1 .. causalC
  float* kvbuf   = region0;                   // live: kvGEMM .. ctx_kernel
  float* q2      = region0 + SZ_KV;           // live: q2 reduce .. attn2
  u16*   O2ff    = (u16*)region0;             // live: ff1 .. ff2 ([hi|lo], 8.39M f-eq)
  float* out1    = region0 + SZ_R0;           // live: LN1 .. LN2
  float* attn_o  = out1 + SZ_ROW;             // attn_o -> attn2_o -> ybuf
  float* r3      = attn_o + SZ_ROW;           // chunkKV -> pre3
  float* chunkKV = r3;
  float* pre3    = r3;
  float* chunkKs = r3 + SZ_ROW;                                   // 32768
  float* colsum  = chunkKs + (size_t)Bc * Hc * NCc * Ec;          // 1024
  float* ctx2    = colsum + (size_t)Bc * Hc * Ec;                 // 65536 (transposed)
  float* ybuf    = attn_o;
  float* attn2_o = attn_o;

  u16* B2_qvk = (u16*)(ctx2 + (size_t)Bc * Hc * Ec * Ec);
  u16* B2_kv  = B2_qvk + (size_t)(3 * DIMc) * (2 * DIMc);   // 1536 x 1024
  u16* B2_q   = B2_kv  + (size_t)(2 * DIMc) * (2 * DIMc);   // 1024 x 1024
  u16* B2_ff1 = B2_q   + (size_t)DIMc * (2 * DIMc);         // 512 x 1024
  u16* B2_ff2 = B2_ff1 + (size_t)FFc  * (2 * DIMc);         // 2048 x 1024
  u16* A2slotA = B2_ff2 + (size_t)DIMc * (2 * FFc);         // 4096 x 1024 (x -> ybuf)
  u16* A2slotB = A2slotA + (size_t)4096 * 1024;             // 4096 x 1024 (out1)
  u16* A2slotC = A2slotB + (size_t)4096 * 1024;             // 4096 x 1024 (memory)
  float* partials = (float*)(A2slotC + (size_t)4096 * 1024);// 4 x 2,097,152 fp32
  (void)ws_size; (void)n_in; (void)out_size;

  dim3 blk(256);
  const int MR = Bc * Nc;  // 4096 rows

  // 0. detect input dtype; ingest ONLY what is needed in fp32.
  detect_kernel<<<dim3(1), dim3(64), 0, stream>>>(d_in[0], flag);
  ConvJobs jobs;
  for (int i = 0; i < 18; ++i) { jobs.j[i].src = d_in[i]; jobs.j[i].dst = cin[i]; jobs.j[i].n = in_sizes[i]; }
  jobs.j[1].n = 0;   // memory  -> split_act_raw reads d_in[1]
  jobs.j[2].n = 0;   // W_qvk   -> wsplit reads d_in[2]
  jobs.j[4].n = 0;   // W_kv
  jobs.j[6].n = 0;   // W_q
  jobs.j[8].n = 0;   // W_ff1
  jobs.j[10].n = 0;  // W_ff2
  ingest_kernel<<<dim3(32, 18), blk, 0, stream>>>(jobs, flag);

  const float *x = cin[0], *b_qvk = cin[3], *b_kv = cin[5], *b_q = cin[7],
              *b_ff1 = cin[9], *b_ff2 = cin[11],
              *ln1_g = cin[12], *ln1_b = cin[13], *ln2_g = cin[14], *ln2_b = cin[15],
              *ln3_g = cin[16], *ln3_b = cin[17];

  // 0b. all weight transpose+splits in ONE batched launch (896 tile-blocks)
  WJobs wj;
  wj.j[0] = WJob{d_in[2],  B2_qvk, DIMc, 3 * DIMc, 24, 0};    // 24x8  = 192
  wj.j[1] = WJob{d_in[4],  B2_kv,  DIMc, 2 * DIMc, 16, 192};  // 16x8  = 128
  wj.j[2] = WJob{d_in[6],  B2_q,   DIMc, DIMc,      8, 320};  // 8x8   = 64
  wj.j[3] = WJob{d_in[8],  B2_ff1, DIMc, FFc,      32, 384};  // 32x8  = 256
  wj.j[4] = WJob{d_in[10], B2_ff2, FFc,  DIMc,      8, 640};  // 8x32  = 256 -> 896
  wsplit_batch<<<dim3(896), blk, 0, stream>>>(wj, flag);
  // both activation splits up front (x -> slotA, memory -> slotC)
  split_act_raw<<<dim3(1024), blk, 0, stream>>>(d_in[0], flag, A2slotA, 9, (int)SZ_ROW);
  split_act_raw<<<dim3(1024), blk, 0, stream>>>(d_in[1], flag, A2slotC, 9, (int)SZ_ROW);

  // 1. qvk = x @ W_qvk + b  (BN=64, 768 blocks -> 3 blocks/CU)
  gemm_mfma<128, 64, 1, 0, false, false><<<dim3(24, 32), blk, 0, stream>>>(
      A2slotA, B2_qvk, b_qvk, nullptr, qvk, nullptr, 3 * DIMc, DIMc);
  // 2. causal linear self-attention
  causalA<<<dim3(NCc, Bc * Hc), blk, 0, stream>>>(qvk, chunkKV, chunkKs);
  causalB<<<dim3(16, 17), blk, 0, stream>>>(chunkKV, chunkKs);
  causalC<<<dim3(NCc, Bc * Hc), blk, 0, stream>>>(qvk, chunkKV, chunkKs, attn_o);
  // 3. LN1(attn + x) -> out1 fp32 + split into slotB (q2 GEMM A)
  ln_kernel<true, false, true><<<dim3(MR), blk, 0, stream>>>(
      attn_o, x, ln1_g, ln1_b, out1, A2slotB, flag);
  // 4. kv = memory @ W_kv + b ; q2 = out1 @ W_q + b (split-K=2 + reduce)
  gemm_mfma<128, 64, 1, 0, false, false><<<dim3(16, 32), blk, 0, stream>>>(
      A2slotC, B2_kv, b_kv, nullptr, kvbuf, nullptr, 2 * DIMc, DIMc);
  gemm_mfma<128, 64, 2, 2, false, false><<<dim3(8, 32, 2), blk, 0, stream>>>(
      A2slotB, B2_q, nullptr, nullptr, partials, nullptr, DIMc, DIMc);
  reduceK<2, false><<<dim3(2048), blk, 0, stream>>>(partials, b_q, nullptr, q2);
  // 5. cross linear attention (ctx transposed; normalize fused into attn2 staging)
  hipMemsetAsync(colsum, 0,
      ((size_t)Bc * Hc * Ec + (size_t)Bc * Hc * Ec * Ec) * sizeof(float), stream);
  ctx_kernel<<<dim3(Mc / 64, Bc * Hc), blk, 0, stream>>>(kvbuf, colsum, ctx2);
  attn2_kernel<<<dim3(Nc / 64, Bc * Hc), blk, 0, stream>>>(q2, ctx2, colsum, attn2_o);
  // 6. LN2(attn2 + out1) in-place -> ybuf fp32 + split into slotA (ff1 A)
  ln_kernel<true, false, true><<<dim3(MR), blk, 0, stream>>>(
      attn2_o, out1, ln2_g, ln2_b, ybuf, A2slotA, flag);
  // 7. FF: ff1 (1024 blocks) writes [hi|lo] split; ff2 split-K=4 + reduce(bias+res)
  gemm_mfma<128, 64, 1, 1, true, false><<<dim3(32, 32), blk, 0, stream>>>(
      A2slotA, B2_ff1, b_ff1, nullptr, nullptr, O2ff, FFc, DIMc);
  gemm_mfma<128, 64, 4, 2, false, false><<<dim3(8, 32, 4), blk, 0, stream>>>(
      O2ff, B2_ff2, nullptr, nullptr, partials, nullptr, DIMc, FFc);
  reduceK<4, true><<<dim3(2048), blk, 0, stream>>>(partials, b_ff2, ybuf, pre3);
  // 8. LN3 -> d_out (bf16 or fp32 per flag)
  ln_kernel<false, true, false><<<dim3(MR), blk, 0, stream>>>(
      pre3, nullptr, ln3_g, ln3_b, d_out, nullptr, flag);
}